// Round 1
// baseline (1658.594 us; speedup 1.0000x reference)
//
#include <hip/hip_runtime.h>
#include <stdint.h>

typedef __attribute__((ext_vector_type(8))) short bf16x8;
typedef __attribute__((ext_vector_type(4))) float f32x4;

__device__ __forceinline__ float b2f(short s) {
  union { unsigned u; float f; } a; a.u = ((unsigned)(unsigned short)s) << 16; return a.f;
}
__device__ __forceinline__ short f2b(float f) {
  union { float f; unsigned u; } a; a.f = f;
  unsigned r = a.u + 0x7fffu + ((a.u >> 16) & 1u);
  return (short)(r >> 16);
}
__device__ __forceinline__ void gload16(const void* g, void* l) {
  __builtin_amdgcn_global_load_lds((__attribute__((address_space(1))) void*)g,
                                   (__attribute__((address_space(3))) void*)l, 16, 0, 0);
}

// ---------------- permute kernels: x (b,c,25,48,48) f32 -> Qbf (4,Mp,Kp) bf16 ----------------

// SF: m=(c,h) M=3072, k=(w,u,v) K=1200 Kp=1280.  k = w*25 + u*5 + v; n=uv=k%25.
__global__ __launch_bounds__(256) void permute_sf_k(const float* __restrict__ x, short* __restrict__ Q) {
  __shared__ float buf[4][1200];
  int wave = threadIdx.x >> 6, lane = threadIdx.x & 63;
  int gr = blockIdx.x * 4 + wave;          // 0..12287 over (b, m)
  int b = gr / 3072, m = gr - b * 3072;
  int c = m / 48, hh = m - c * 48;
  const float* xb = x + (long)(b * 64 + c) * 57600 + hh * 48;
  for (int uv = 0; uv < 25; ++uv)
    if (lane < 48) buf[wave][uv * 48 + lane] = xb[uv * 2304 + lane];
  __syncthreads();
  short* Qr = Q + (long)gr * 1280;
  for (int k = lane; k < 1280; k += 64) {
    float v = 0.f;
    if (k < 1200) { int wv = k / 25, uv = k - wv * 25; v = buf[wave][uv * 48 + wv]; }
    Qr[k] = f2b(v);
  }
}

// BR==1 AF: m=(c,u) M=320 Mp=384, k=(h,v,w) Kp=11520
// BR==2 SA: m=(h,u) M=240 Mp=256, k=(c,v,w) Kp=15360
template<int BR>
__global__ __launch_bounds__(256) void permute_k(const float* __restrict__ x, short* __restrict__ Q) {
  constexpr int M  = (BR == 1) ? 320 : 240;
  constexpr int Mp = (BR == 1) ? 384 : 256;
  constexpr int Kp = (BR == 1) ? 11520 : 15360;
  const int total = 4 * Mp * Kp;
  for (int idx = blockIdx.x * 256 + threadIdx.x; idx < total; idx += gridDim.x * 256) {
    int b = idx / (Mp * Kp);
    int rem = idx - b * (Mp * Kp);
    int m = rem / Kp;
    int k = rem - m * Kp;
    float v = 0.f;
    if (m < M) {
      int q1 = k / 240, r2 = k - q1 * 240;
      int v5 = r2 / 48, wv = r2 - v5 * 48;
      int a1 = m / 5, u = m - a1 * 5;
      long xi;
      if (BR == 1) xi = ((long)(b * 64 + a1) * 25 + u * 5 + v5) * 2304 + q1 * 48 + wv;
      else         xi = ((long)(b * 64 + q1) * 25 + u * 5 + v5) * 2304 + a1 * 48 + wv;
      v = x[xi];
    }
    Q[idx] = f2b(v);
  }
}

// ---------------- bf16 2D transpose per batch: in (R x C) -> out (C x R) ----------------
__global__ __launch_bounds__(256) void transpose_k(const short* __restrict__ in, short* __restrict__ out,
                                                   int R, int C) {
  __shared__ short t[32][33];
  long base = (long)blockIdx.z * R * C;
  int c0 = blockIdx.x * 32, r0 = blockIdx.y * 32;
  int tx = threadIdx.x & 31, ty = threadIdx.x >> 5;   // ty 0..7
  #pragma unroll
  for (int i = 0; i < 32; i += 8)
    t[ty + i][tx] = in[base + (long)(r0 + ty + i) * C + c0 + tx];
  __syncthreads();
  #pragma unroll
  for (int i = 0; i < 32; i += 8)
    out[base + (long)(c0 + ty + i) * R + r0 + tx] = t[tx][ty + i];
}

// ---------------- row inv-norms ----------------
__global__ __launch_bounds__(256) void invnorm_k(const short* __restrict__ Q, long sQ, int Kp,
                                                 int Mvalid, int Mp, float* __restrict__ inv) {
  __shared__ float red[256];
  int m = blockIdx.x, b = blockIdx.y, tid = threadIdx.x;
  float acc = 0.f;
  if (m < Mvalid) {
    const short* row = Q + (long)b * sQ + (long)m * Kp;
    for (int k = tid * 8; k < Kp; k += 2048) {
      bf16x8 v = *(const bf16x8*)&row[k];
      #pragma unroll
      for (int j = 0; j < 8; ++j) { float f = b2f(v[j]); acc += f * f; }
    }
  }
  red[tid] = acc; __syncthreads();
  #pragma unroll
  for (int s2 = 128; s2 > 0; s2 >>= 1) {
    if (tid < s2) red[tid] += red[tid + s2];
    __syncthreads();
  }
  if (tid == 0)
    inv[(long)b * Mp + m] = (m < Mvalid) ? 1.0f / fmaxf(sqrtf(red[0]), 1e-12f) : 1.0f;
}

// ---------------- GEMM: 128x128 tile, 4 waves, 16x16x32 bf16 MFMA, global_load_lds staging -----
// EPI 0: store raw f32 dot (optionally atomic, split-K) into Sf
// EPI 1/2/3: scatter O + x into F (bf16) for sf/af/sa
template<int EPI>
__global__ __launch_bounds__(256) void gemm_k(
    const short* __restrict__ A, const short* __restrict__ B,
    long sA, long sB, int lda, int ldb,
    int ktotal, int ksper, int SK,
    int atomicF, float* __restrict__ Sf, long sS, int ldc,
    short* __restrict__ F, const float* __restrict__ x,
    int Mvalid, int Kvalid, int batch0)
{
  __shared__ short As[128 * 64];
  __shared__ short Bs[128 * 64];
  int tid = threadIdx.x;
  int wave = tid >> 6, lane = tid & 63;
  int la = lane & 15, lb = lane >> 4;
  int bz = blockIdx.z;
  int bat = bz / SK, kc = bz - bat * SK;
  int row0 = blockIdx.y * 128, col0 = blockIdx.x * 128;
  const short* Ab = A + (long)bat * sA;
  const short* Bb = B + (long)bat * sB;
  int kb = kc * ksper, ke = min(ktotal, kb + ksper);
  f32x4 acc[4][4] = {};
  int wr = wave >> 1, wc = wave & 1;

  for (int kt = kb; kt < ke; ++kt) {
    int k0 = kt * 64;
    #pragma unroll
    for (int p = 0; p < 4; ++p) {
      int e = p * 2048 + wave * 512 + lane * 8;
      int row = e >> 6, col = e & 63;
      gload16(Ab + (long)(row0 + row) * lda + k0 + col, (void*)(As + p * 2048 + wave * 512));
      gload16(Bb + (long)(col0 + row) * ldb + k0 + col, (void*)(Bs + p * 2048 + wave * 512));
    }
    __syncthreads();
    #pragma unroll
    for (int kk = 0; kk < 64; kk += 32) {
      bf16x8 av[4], bv[4];
      #pragma unroll
      for (int m = 0; m < 4; ++m)
        av[m] = *(const bf16x8*)&As[(wr * 64 + m * 16 + la) * 64 + kk + lb * 8];
      #pragma unroll
      for (int nn = 0; nn < 4; ++nn)
        bv[nn] = *(const bf16x8*)&Bs[(wc * 64 + nn * 16 + la) * 64 + kk + lb * 8];
      #pragma unroll
      for (int m = 0; m < 4; ++m)
        #pragma unroll
        for (int nn = 0; nn < 4; ++nn)
          acc[m][nn] = __builtin_amdgcn_mfma_f32_16x16x32_bf16(av[m], bv[nn], acc[m][nn], 0, 0, 0);
    }
    __syncthreads();
  }

  int bglob = batch0 + bat;
  if (EPI == 0) {
    float* Sb = Sf + (long)bat * sS;
    #pragma unroll
    for (int m = 0; m < 4; ++m) {
      int gr0 = row0 + wr * 64 + m * 16 + lb * 4;
      #pragma unroll
      for (int nn = 0; nn < 4; ++nn) {
        int gc = col0 + wc * 64 + nn * 16 + la;
        #pragma unroll
        for (int j = 0; j < 4; ++j) {
          float v = acc[m][nn][j];
          if (atomicF) atomicAdd(&Sb[(long)(gr0 + j) * ldc + gc], v);
          else Sb[(long)(gr0 + j) * ldc + gc] = v;
        }
      }
    }
  } else {
    #pragma unroll
    for (int m = 0; m < 4; ++m) {
      int gr0 = row0 + wr * 64 + m * 16 + lb * 4;
      #pragma unroll
      for (int nn = 0; nn < 4; ++nn) {
        int gc = col0 + wc * 64 + nn * 16 + la;
        if (gc < Kvalid) {
          #pragma unroll
          for (int j = 0; j < 4; ++j) {
            int gr = gr0 + j;
            if (gr < Mvalid) {
              int cch, hh, wv, nidx;
              if (EPI == 1) { cch = gr / 48; hh = gr - cch * 48; wv = gc / 25; nidx = gc - wv * 25; }
              else if (EPI == 2) {
                cch = gr / 5; int u = gr - cch * 5;
                hh = gc / 240; int r2 = gc - hh * 240; int v5 = r2 / 48; wv = r2 - v5 * 48;
                nidx = u * 5 + v5;
              } else {
                hh = gr / 5; int u = gr - hh * 5;
                cch = gc / 240; int r2 = gc - cch * 240; int v5 = r2 / 48; wv = r2 - v5 * 48;
                nidx = u * 5 + v5;
              }
              long xi = ((long)(bglob * 64 + cch) * 25 + nidx) * 2304 + hh * 48 + wv;
              long fi = (((long)(bglob * 48 + hh) * 48 + wv) * 25 + nidx) * 192 + (EPI - 1) * 64 + cch;
              F[fi] = f2b(acc[m][nn][j] + x[xi]);
            }
          }
        }
      }
    }
  }
}

// ---------------- row softmax with cosine scaling: Sf (f32 raw dots) -> att (bf16) ----------------
__global__ __launch_bounds__(256) void softmax_k(const float* __restrict__ Sf, long sS,
                                                 const float* __restrict__ inv,
                                                 int Mvalid, int Mp,
                                                 short* __restrict__ att, long sAtt) {
  __shared__ float srow[3072];
  __shared__ float red[256];
  int row = blockIdx.x, b = blockIdx.y, tid = threadIdx.x;
  const float* Sr = Sf + (long)b * sS + (long)row * Mp;
  const float* invb = inv + (long)b * Mp;
  float inv_i = invb[row];
  for (int j = tid; j < Mvalid; j += 256) srow[j] = Sr[j] * inv_i * invb[j];
  __syncthreads();
  float mx = -1e30f;
  for (int j = tid; j < Mvalid; j += 256) mx = fmaxf(mx, srow[j]);
  red[tid] = mx; __syncthreads();
  #pragma unroll
  for (int s2 = 128; s2 > 0; s2 >>= 1) {
    if (tid < s2) red[tid] = fmaxf(red[tid], red[tid + s2]);
    __syncthreads();
  }
  mx = red[0]; __syncthreads();
  float sum = 0.f;
  for (int j = tid; j < Mvalid; j += 256) {
    float e = __expf(srow[j] - mx);
    srow[j] = e; sum += e;
  }
  red[tid] = sum; __syncthreads();
  #pragma unroll
  for (int s2 = 128; s2 > 0; s2 >>= 1) {
    if (tid < s2) red[tid] += red[tid + s2];
    __syncthreads();
  }
  float rden = 1.0f / red[0];
  short* ar = att + (long)b * sAtt + (long)row * Mp;
  for (int j = tid; j < Mp; j += 256)
    ar[j] = (j < Mvalid) ? f2b(srow[j] * rden) : (short)0;
}

// ---------------- fused LayerNorm + MLP + residual ----------------
// block = (n, h, b); handles 48 w-rows of 192 features each
__global__ __launch_bounds__(256) void ln_mlp_k(
    const short* __restrict__ F, const float* __restrict__ x,
    const float* __restrict__ gamma, const float* __restrict__ beta,
    const float* __restrict__ w1, const float* __restrict__ w2,
    float* __restrict__ out)
{
  int n = blockIdx.x, hh = blockIdx.y, b = blockIdx.z;
  __shared__ float fr[48][196];
  __shared__ float y1[48][68];
  __shared__ float y2[48][65];
  int tid = threadIdx.x;
  long Fb0 = ((long)(b * 48 + hh) * 1200 + n) * 192;
  #pragma unroll
  for (int i = 0; i < 36; ++i) {
    int e = tid + 256 * i;
    int wv = e / 192, ch = e - wv * 192;
    fr[wv][ch] = b2f(F[Fb0 + (long)wv * 4800 + ch]);
  }
  __syncthreads();
  int wave = tid >> 6, lane = tid & 63;
  for (int r = wave; r < 48; r += 4) {
    float v0 = fr[r][lane], v1 = fr[r][lane + 64], v2 = fr[r][lane + 128];
    float s = v0 + v1 + v2;
    #pragma unroll
    for (int o = 32; o >= 1; o >>= 1) s += __shfl_xor(s, o, 64);
    float mu = s * (1.f / 192.f);
    float d0 = v0 - mu, d1 = v1 - mu, d2 = v2 - mu;
    float q = d0 * d0 + d1 * d1 + d2 * d2;
    #pragma unroll
    for (int o = 32; o >= 1; o >>= 1) q += __shfl_xor(q, o, 64);
    float rs = rsqrtf(q * (1.f / 192.f) + 1e-5f);
    fr[r][lane]       = d0 * rs * gamma[lane]       + beta[lane];
    fr[r][lane + 64]  = d1 * rs * gamma[lane + 64]  + beta[lane + 64];
    fr[r][lane + 128] = d2 * rs * gamma[lane + 128] + beta[lane + 128];
  }
  __syncthreads();
  {
    int j0 = (tid & 15) * 4, rg = tid >> 4;
    float a1[3][4] = {};
    const float4* w1v = reinterpret_cast<const float4*>(w1);
    for (int i = 0; i < 192; ++i) {
      float4 wv = w1v[i * 16 + (j0 >> 2)];
      float f0 = fr[rg][i], f1 = fr[rg + 16][i], f2 = fr[rg + 32][i];
      a1[0][0] += f0 * wv.x; a1[0][1] += f0 * wv.y; a1[0][2] += f0 * wv.z; a1[0][3] += f0 * wv.w;
      a1[1][0] += f1 * wv.x; a1[1][1] += f1 * wv.y; a1[1][2] += f1 * wv.z; a1[1][3] += f1 * wv.w;
      a1[2][0] += f2 * wv.x; a1[2][1] += f2 * wv.y; a1[2][2] += f2 * wv.z; a1[2][3] += f2 * wv.w;
    }
    #pragma unroll
    for (int q = 0; q < 4; ++q) {
      y1[rg][j0 + q]      = fmaxf(a1[0][q], 0.f);
      y1[rg + 16][j0 + q] = fmaxf(a1[1][q], 0.f);
      y1[rg + 32][j0 + q] = fmaxf(a1[2][q], 0.f);
    }
  }
  __syncthreads();
  {
    int j0 = (tid & 15) * 4, rg = tid >> 4;
    float a2[3][4] = {};
    const float4* w2v = reinterpret_cast<const float4*>(w2);
    for (int i = 0; i < 64; ++i) {
      float4 wv = w2v[i * 16 + (j0 >> 2)];
      float f0 = y1[rg][i], f1 = y1[rg + 16][i], f2 = y1[rg + 32][i];
      a2[0][0] += f0 * wv.x; a2[0][1] += f0 * wv.y; a2[0][2] += f0 * wv.z; a2[0][3] += f0 * wv.w;
      a2[1][0] += f1 * wv.x; a2[1][1] += f1 * wv.y; a2[1][2] += f1 * wv.z; a2[1][3] += f1 * wv.w;
      a2[2][0] += f2 * wv.x; a2[2][1] += f2 * wv.y; a2[2][2] += f2 * wv.z; a2[2][3] += f2 * wv.w;
    }
    #pragma unroll
    for (int q = 0; q < 4; ++q) {
      y2[rg][j0 + q]      = a2[0][q];
      y2[rg + 16][j0 + q] = a2[1][q];
      y2[rg + 32][j0 + q] = a2[2][q];
    }
  }
  __syncthreads();
  long xb = (long)b * 3686400 + (long)n * 2304 + hh * 48;
  #pragma unroll
  for (int i = 0; i < 12; ++i) {
    int e = tid + 256 * i;
    int cc = e / 48, wv = e - cc * 48;
    long xi = xb + (long)cc * 57600 + wv;
    out[xi] = y2[wv][cc] + x[xi];
  }
}

// ---------------- host launcher ----------------
extern "C" void kernel_launch(void* const* d_in, const int* in_sizes, int n_in,
                              void* d_out, int out_size, void* d_ws, size_t ws_size,
                              hipStream_t stream) {
  (void)in_sizes; (void)n_in; (void)out_size;
  const float* x     = (const float*)d_in[0];
  const float* gamma = (const float*)d_in[1];
  const float* beta  = (const float*)d_in[2];
  const float* w1    = (const float*)d_in[3];
  const float* w2    = (const float*)d_in[4];
  float* out = (float*)d_out;

  // workspace layout (bytes, 256-aligned)
  const size_t OFF_F    = 0;                    // 88,473,600  bf16 F (b,h,w,n,192)
  const size_t OFF_QBF  = 88473600;             // 35,389,440  bf16 Qbf
  const size_t OFF_QBFT = 123863040;            // 35,389,440  bf16 QbfT
  const size_t OFF_S    = 159252480;            // 37,748,736  f32 S
  const size_t OFF_ATT  = 197001216;            // 18,874,368  bf16 att
  const size_t OFF_INV  = 215875584;            // 49,152      f32 inv norms
  const size_t NEED     = 215924736;
  if (ws_size < NEED) return;

  char* ws = (char*)d_ws;
  short* F     = (short*)(ws + OFF_F);
  short* Qbf   = (short*)(ws + OFF_QBF);
  short* QbfT  = (short*)(ws + OFF_QBFT);
  float* Sf    = (float*)(ws + OFF_S);
  short* att   = (short*)(ws + OFF_ATT);
  float* invn  = (float*)(ws + OFF_INV);

  // ================= SF branch: M=3072 Mp=3072, K=1200 Kp=1280 =================
  permute_sf_k<<<3072, 256, 0, stream>>>(x, Qbf);
  transpose_k<<<dim3(40, 96, 4), 256, 0, stream>>>(Qbf, QbfT, 3072, 1280);
  invnorm_k<<<dim3(3072, 4), 256, 0, stream>>>(Qbf, 3932160L, 1280, 3072, 3072, invn);
  for (int b = 0; b < 4; ++b) {
    long qoff = (long)b * 3072 * 1280;
    gemm_k<0><<<dim3(24, 24, 1), 256, 0, stream>>>(
        Qbf + qoff, Qbf + qoff, 0, 0, 1280, 1280,
        20, 20, 1, 0, Sf, 0, 3072, nullptr, nullptr, 0, 0, 0);
    softmax_k<<<dim3(3072, 1), 256, 0, stream>>>(Sf, 0, invn + (long)b * 3072, 3072, 3072, att, 0);
    gemm_k<1><<<dim3(10, 24, 1), 256, 0, stream>>>(
        att, QbfT + (long)b * 1280 * 3072, 0, 0, 3072, 3072,
        48, 48, 1, 0, nullptr, 0, 0, F, x, 3072, 1200, b);
  }

  // ================= AF branch: M=320 Mp=384, Kp=11520 =================
  permute_k<1><<<4096, 256, 0, stream>>>(x, Qbf);
  transpose_k<<<dim3(360, 12, 4), 256, 0, stream>>>(Qbf, QbfT, 384, 11520);
  invnorm_k<<<dim3(384, 4), 256, 0, stream>>>(Qbf, 4423680L, 11520, 320, 384, invn);
  hipMemsetAsync(Sf, 0, (size_t)4 * 384 * 384 * 4, stream);
  gemm_k<0><<<dim3(3, 3, 32), 256, 0, stream>>>(
      Qbf, Qbf, 4423680L, 4423680L, 11520, 11520,
      180, 23, 8, 1, Sf, 147456L, 384, nullptr, nullptr, 0, 0, 0);
  softmax_k<<<dim3(320, 4), 256, 0, stream>>>(Sf, 147456L, invn, 320, 384, att, 147456L);
  gemm_k<2><<<dim3(90, 3, 4), 256, 0, stream>>>(
      att, QbfT, 147456L, 4423680L, 384, 384,
      6, 6, 1, 0, nullptr, 0, 0, F, x, 320, 11520, 0);

  // ================= SA branch: M=240 Mp=256, Kp=15360 =================
  permute_k<2><<<4096, 256, 0, stream>>>(x, Qbf);
  transpose_k<<<dim3(480, 8, 4), 256, 0, stream>>>(Qbf, QbfT, 256, 15360);
  invnorm_k<<<dim3(256, 4), 256, 0, stream>>>(Qbf, 3932160L, 15360, 240, 256, invn);
  hipMemsetAsync(Sf, 0, (size_t)4 * 256 * 256 * 4, stream);
  gemm_k<0><<<dim3(2, 2, 64), 256, 0, stream>>>(
      Qbf, Qbf, 3932160L, 3932160L, 15360, 15360,
      240, 15, 16, 1, Sf, 65536L, 256, nullptr, nullptr, 0, 0, 0);
  softmax_k<<<dim3(240, 4), 256, 0, stream>>>(Sf, 65536L, invn, 240, 256, att, 65536L);
  gemm_k<3><<<dim3(120, 2, 4), 256, 0, stream>>>(
      att, QbfT, 65536L, 3932160L, 256, 256,
      4, 4, 1, 0, nullptr, 0, 0, F, x, 240, 15360, 0);

  // ================= LayerNorm + MLP + residual =================
  ln_mlp_k<<<dim3(25, 48, 4), 256, 0, stream>>>(F, x, gamma, beta, w1, w2, out);
}

// Round 2
// 1358.920 us; speedup vs baseline: 1.2205x; 1.2205x over previous
//
#include <hip/hip_runtime.h>
#include <stdint.h>

typedef __attribute__((ext_vector_type(8))) short bf16x8;
typedef __attribute__((ext_vector_type(4))) float f32x4;

__device__ __forceinline__ float b2f(short s) {
  union { unsigned u; float f; } a; a.u = ((unsigned)(unsigned short)s) << 16; return a.f;
}
__device__ __forceinline__ short f2b(float f) {
  union { float f; unsigned u; } a; a.f = f;
  unsigned r = a.u + 0x7fffu + ((a.u >> 16) & 1u);
  return (short)(r >> 16);
}
__device__ __forceinline__ void gload16(const void* g, void* l) {
  __builtin_amdgcn_global_load_lds((__attribute__((address_space(1))) void*)g,
                                   (__attribute__((address_space(3))) void*)l, 16, 0, 0);
}

// ---------------- permute kernels: x (b,c,25,48,48) f32 -> Qbf (4,Mp,Kp) bf16 ----------------

// SF: m=(c,h) M=3072, k=(w,u,v) K=1200 Kp=1280.
__global__ __launch_bounds__(256) void permute_sf_k(const float* __restrict__ x, short* __restrict__ Q) {
  __shared__ float buf[4][1200];
  int wave = threadIdx.x >> 6, lane = threadIdx.x & 63;
  int gr = blockIdx.x * 4 + wave;
  int b = gr / 3072, m = gr - b * 3072;
  int c = m / 48, hh = m - c * 48;
  const float* xb = x + (long)(b * 64 + c) * 57600 + hh * 48;
  for (int uv = 0; uv < 25; ++uv)
    if (lane < 48) buf[wave][uv * 48 + lane] = xb[uv * 2304 + lane];
  __syncthreads();
  short* Qr = Q + (long)gr * 1280;
  for (int k = lane; k < 1280; k += 64) {
    float v = 0.f;
    if (k < 1200) { int wv = k / 25, uv = k - wv * 25; v = buf[wave][uv * 48 + wv]; }
    Qr[k] = f2b(v);
  }
}

// BR==1 AF: m=(c,u) M=320 Mp=384, k=(h,v,w) Kp=11520
// BR==2 SA: m=(h,u) M=240 Mp=256, k=(c,v,w) Kp=15360
template<int BR>
__global__ __launch_bounds__(256) void permute_k(const float* __restrict__ x, short* __restrict__ Q) {
  constexpr int M  = (BR == 1) ? 320 : 240;
  constexpr int Mp = (BR == 1) ? 384 : 256;
  constexpr int Kp = (BR == 1) ? 11520 : 15360;
  const int total = 4 * Mp * Kp;
  for (int idx = blockIdx.x * 256 + threadIdx.x; idx < total; idx += gridDim.x * 256) {
    int b = idx / (Mp * Kp);
    int rem = idx - b * (Mp * Kp);
    int m = rem / Kp;
    int k = rem - m * Kp;
    float v = 0.f;
    if (m < M) {
      int q1 = k / 240, r2 = k - q1 * 240;
      int v5 = r2 / 48, wv = r2 - v5 * 48;
      int a1 = m / 5, u = m - a1 * 5;
      long xi;
      if (BR == 1) xi = ((long)(b * 64 + a1) * 25 + u * 5 + v5) * 2304 + q1 * 48 + wv;
      else         xi = ((long)(b * 64 + q1) * 25 + u * 5 + v5) * 2304 + a1 * 48 + wv;
      v = x[xi];
    }
    Q[idx] = f2b(v);
  }
}

// ---------------- bf16 2D transpose per batch ----------------
__global__ __launch_bounds__(256) void transpose_k(const short* __restrict__ in, short* __restrict__ out,
                                                   int R, int C) {
  __shared__ short t[32][33];
  long base = (long)blockIdx.z * R * C;
  int c0 = blockIdx.x * 32, r0 = blockIdx.y * 32;
  int tx = threadIdx.x & 31, ty = threadIdx.x >> 5;
  #pragma unroll
  for (int i = 0; i < 32; i += 8)
    t[ty + i][tx] = in[base + (long)(r0 + ty + i) * C + c0 + tx];
  __syncthreads();
  #pragma unroll
  for (int i = 0; i < 32; i += 8)
    out[base + (long)(c0 + ty + i) * R + r0 + tx] = t[tx][ty + i];
}

// ---------------- row inv-norms ----------------
__global__ __launch_bounds__(256) void invnorm_k(const short* __restrict__ Q, long sQ, int Kp,
                                                 int Mvalid, int Mp, float* __restrict__ inv) {
  __shared__ float red[256];
  int m = blockIdx.x, b = blockIdx.y, tid = threadIdx.x;
  float acc = 0.f;
  if (m < Mvalid) {
    const short* row = Q + (long)b * sQ + (long)m * Kp;
    for (int k = tid * 8; k < Kp; k += 2048) {
      bf16x8 v = *(const bf16x8*)&row[k];
      #pragma unroll
      for (int j = 0; j < 8; ++j) { float f = b2f(v[j]); acc += f * f; }
    }
  }
  red[tid] = acc; __syncthreads();
  #pragma unroll
  for (int s2 = 128; s2 > 0; s2 >>= 1) {
    if (tid < s2) red[tid] += red[tid + s2];
    __syncthreads();
  }
  if (tid == 0)
    inv[(long)b * Mp + m] = (m < Mvalid) ? 1.0f / fmaxf(sqrtf(red[0]), 1e-12f) : 1.0f;
}

// ---------------- GEMM: 128x128 tile, 4 waves, 16x16x32 bf16 MFMA -----
// EPI 0: store raw f32 dot (optionally atomic, split-K) into Sf
// EPI 4: store bf16 cosine-scaled S directly: F=att out, sS=att batch stride,
//        ldc, x=inv ptr, Mvalid=inv batch stride
// EPI 1/2/3: scatter O + x into F (bf16) for sf/af/sa
template<int EPI>
__global__ __launch_bounds__(256) void gemm_k(
    const short* __restrict__ A, const short* __restrict__ B,
    long sA, long sB, int lda, int ldb,
    int ktotal, int ksper, int SK,
    int atomicF, float* __restrict__ Sf, long sS, int ldc,
    short* __restrict__ F, const float* __restrict__ x,
    int Mvalid, int Kvalid, int batch0)
{
  __shared__ short As[128 * 64];
  __shared__ short Bs[128 * 64];
  int tid = threadIdx.x;
  int wave = tid >> 6, lane = tid & 63;
  int la = lane & 15, lb = lane >> 4;
  int bz = blockIdx.z;
  int bat = bz / SK, kc = bz - bat * SK;
  int row0 = blockIdx.y * 128, col0 = blockIdx.x * 128;
  const short* Ab = A + (long)bat * sA;
  const short* Bb = B + (long)bat * sB;
  int kb = kc * ksper, ke = min(ktotal, kb + ksper);
  f32x4 acc[4][4] = {};
  int wr = wave >> 1, wc = wave & 1;

  for (int kt = kb; kt < ke; ++kt) {
    int k0 = kt * 64;
    #pragma unroll
    for (int p = 0; p < 4; ++p) {
      int e = p * 2048 + wave * 512 + lane * 8;
      int row = e >> 6, col = e & 63;
      gload16(Ab + (long)(row0 + row) * lda + k0 + col, (void*)(As + p * 2048 + wave * 512));
      gload16(Bb + (long)(col0 + row) * ldb + k0 + col, (void*)(Bs + p * 2048 + wave * 512));
    }
    __syncthreads();
    #pragma unroll
    for (int kk = 0; kk < 64; kk += 32) {
      bf16x8 av[4], bv[4];
      #pragma unroll
      for (int m = 0; m < 4; ++m)
        av[m] = *(const bf16x8*)&As[(wr * 64 + m * 16 + la) * 64 + kk + lb * 8];
      #pragma unroll
      for (int nn = 0; nn < 4; ++nn)
        bv[nn] = *(const bf16x8*)&Bs[(wc * 64 + nn * 16 + la) * 64 + kk + lb * 8];
      #pragma unroll
      for (int m = 0; m < 4; ++m)
        #pragma unroll
        for (int nn = 0; nn < 4; ++nn)
          acc[m][nn] = __builtin_amdgcn_mfma_f32_16x16x32_bf16(av[m], bv[nn], acc[m][nn], 0, 0, 0);
    }
    __syncthreads();
  }

  int bglob = batch0 + bat;
  if (EPI == 0) {
    float* Sb = Sf + (long)bat * sS;
    #pragma unroll
    for (int m = 0; m < 4; ++m) {
      int gr0 = row0 + wr * 64 + m * 16 + lb * 4;
      #pragma unroll
      for (int nn = 0; nn < 4; ++nn) {
        int gc = col0 + wc * 64 + nn * 16 + la;
        #pragma unroll
        for (int j = 0; j < 4; ++j) {
          float v = acc[m][nn][j];
          if (atomicF) atomicAdd(&Sb[(long)(gr0 + j) * ldc + gc], v);
          else Sb[(long)(gr0 + j) * ldc + gc] = v;
        }
      }
    }
  } else if (EPI == 4) {
    const float* invb = x + (long)bat * Mvalid;
    short* Ob = F + (long)bat * sS;
    #pragma unroll
    for (int m = 0; m < 4; ++m) {
      int gr0 = row0 + wr * 64 + m * 16 + lb * 4;
      #pragma unroll
      for (int nn = 0; nn < 4; ++nn) {
        int gc = col0 + wc * 64 + nn * 16 + la;
        float ic = invb[gc];
        #pragma unroll
        for (int j = 0; j < 4; ++j)
          Ob[(long)(gr0 + j) * ldc + gc] = f2b(acc[m][nn][j] * invb[gr0 + j] * ic);
      }
    }
  } else {
    #pragma unroll
    for (int m = 0; m < 4; ++m) {
      int gr0 = row0 + wr * 64 + m * 16 + lb * 4;
      #pragma unroll
      for (int nn = 0; nn < 4; ++nn) {
        int gc = col0 + wc * 64 + nn * 16 + la;
        if (gc < Kvalid) {
          #pragma unroll
          for (int j = 0; j < 4; ++j) {
            int gr = gr0 + j;
            if (gr < Mvalid) {
              int cch, hh, wv, nidx;
              if (EPI == 1) { cch = gr / 48; hh = gr - cch * 48; wv = gc / 25; nidx = gc - wv * 25; }
              else if (EPI == 2) {
                cch = gr / 5; int u = gr - cch * 5;
                hh = gc / 240; int r2 = gc - hh * 240; int v5 = r2 / 48; wv = r2 - v5 * 48;
                nidx = u * 5 + v5;
              } else {
                hh = gr / 5; int u = gr - hh * 5;
                cch = gc / 240; int r2 = gc - cch * 240; int v5 = r2 / 48; wv = r2 - v5 * 48;
                nidx = u * 5 + v5;
              }
              long xi = ((long)(bglob * 64 + cch) * 25 + nidx) * 2304 + hh * 48 + wv;
              long fi = (((long)(bglob * 48 + hh) * 48 + wv) * 25 + nidx) * 192 + (EPI - 1) * 64 + cch;
              F[fi] = f2b(acc[m][nn][j] + x[xi]);
            }
          }
        }
      }
    }
  }
}

// ---------------- softmax over f32 raw dots (af/sa path) ----------------
__global__ __launch_bounds__(256) void softmax_k(const float* __restrict__ Sf, long sS,
                                                 const float* __restrict__ inv,
                                                 int Mvalid, int Mp,
                                                 short* __restrict__ att, long sAtt) {
  __shared__ float srow[3072];
  __shared__ float red[256];
  int row = blockIdx.x, b = blockIdx.y, tid = threadIdx.x;
  const float* Sr = Sf + (long)b * sS + (long)row * Mp;
  const float* invb = inv + (long)b * Mp;
  float inv_i = invb[row];
  for (int j = tid; j < Mvalid; j += 256) srow[j] = Sr[j] * inv_i * invb[j];
  __syncthreads();
  float mx = -1e30f;
  for (int j = tid; j < Mvalid; j += 256) mx = fmaxf(mx, srow[j]);
  red[tid] = mx; __syncthreads();
  #pragma unroll
  for (int s2 = 128; s2 > 0; s2 >>= 1) {
    if (tid < s2) red[tid] = fmaxf(red[tid], red[tid + s2]);
    __syncthreads();
  }
  mx = red[0]; __syncthreads();
  float sum = 0.f;
  for (int j = tid; j < Mvalid; j += 256) {
    float e = __expf(srow[j] - mx);
    srow[j] = e; sum += e;
  }
  red[tid] = sum; __syncthreads();
  #pragma unroll
  for (int s2 = 128; s2 > 0; s2 >>= 1) {
    if (tid < s2) red[tid] += red[tid + s2];
    __syncthreads();
  }
  float rden = 1.0f / red[0];
  short* ar = att + (long)b * sAtt + (long)row * Mp;
  for (int j = tid; j < Mp; j += 256)
    ar[j] = (j < Mvalid) ? f2b(srow[j] * rden) : (short)0;
}

// ---------------- in-place softmax over bf16 scaled S (sf path) ----------------
__global__ __launch_bounds__(256) void softmax_bf16_k(short* __restrict__ att, long sAtt, int M) {
  __shared__ float srow[3072];
  __shared__ float red[256];
  int row = blockIdx.x, b = blockIdx.y, tid = threadIdx.x;
  short* ar = att + (long)b * sAtt + (long)row * M;
  float mx = -1e30f;
  for (int j = tid * 8; j < M; j += 2048) {
    bf16x8 v = *(const bf16x8*)&ar[j];
    #pragma unroll
    for (int jj = 0; jj < 8; ++jj) { float f = b2f(v[jj]); srow[j + jj] = f; mx = fmaxf(mx, f); }
  }
  red[tid] = mx; __syncthreads();
  #pragma unroll
  for (int s2 = 128; s2 > 0; s2 >>= 1) {
    if (tid < s2) red[tid] = fmaxf(red[tid], red[tid + s2]);
    __syncthreads();
  }
  mx = red[0]; __syncthreads();
  float sum = 0.f;
  for (int j = tid; j < M; j += 256) {
    float e = __expf(srow[j] - mx);
    srow[j] = e; sum += e;
  }
  red[tid] = sum; __syncthreads();
  #pragma unroll
  for (int s2 = 128; s2 > 0; s2 >>= 1) {
    if (tid < s2) red[tid] += red[tid + s2];
    __syncthreads();
  }
  float rden = 1.0f / red[0];
  for (int j = tid * 8; j < M; j += 2048) {
    bf16x8 o;
    #pragma unroll
    for (int jj = 0; jj < 8; ++jj) o[jj] = f2b(srow[j + jj] * rden);
    *(bf16x8*)&ar[j] = o;
  }
}

// ---------------- weight prep: w1 (192,64) f32 -> w1t (64,192) bf16; w2 (64,64) -> w2t ----------------
__global__ __launch_bounds__(256) void prep_w_k(const float* __restrict__ w1, const float* __restrict__ w2,
                                                short* __restrict__ w1t, short* __restrict__ w2t) {
  int idx = blockIdx.x * 256 + threadIdx.x;
  if (idx < 12288) {
    int i = idx / 64, j = idx - i * 64;
    w1t[j * 192 + i] = f2b(w1[idx]);
  } else if (idx < 16384) {
    int k = idx - 12288;
    int i = k / 64, j = k - i * 64;
    w2t[j * 64 + i] = f2b(w2[k]);
  }
}

// ---------------- fused LayerNorm + MFMA MLP + residual ----------------
// grid (25, 48, 4); 4 waves; each block: 48 w-rows x 192 feats
__global__ __launch_bounds__(256) void ln_mlp_mfma_k(
    const short* __restrict__ F, const float* __restrict__ x,
    const float* __restrict__ gamma, const float* __restrict__ beta,
    const short* __restrict__ w1t, const short* __restrict__ w2t,
    float* __restrict__ out)
{
  int n = blockIdx.x, hh = blockIdx.y, b = blockIdx.z;
  __shared__ short A1[48 * 200];   // LN output bf16, pitch 200 (bank-spread, 16B-aligned rows)
  __shared__ short Y1[48 * 72];    // relu(f@w1) bf16, pitch 72
  __shared__ float Y2[48 * 66];    // final f32, pitch 66
  int tid = threadIdx.x, wave = tid >> 6, lane = tid & 63;
  int la = lane & 15, lb = lane >> 4;
  long Fb0 = ((long)(b * 48 + hh) * 1200 + n) * 192;

  float g0 = gamma[lane], g1 = gamma[lane + 64], g2 = gamma[lane + 128];
  float bt0 = beta[lane], bt1 = beta[lane + 64], bt2 = beta[lane + 128];
  for (int r = wave; r < 48; r += 4) {
    const short* Fr = F + Fb0 + (long)r * 4800;
    float v0 = b2f(Fr[lane]), v1 = b2f(Fr[lane + 64]), v2 = b2f(Fr[lane + 128]);
    float s = v0 + v1 + v2;
    #pragma unroll
    for (int o = 32; o >= 1; o >>= 1) s += __shfl_xor(s, o, 64);
    float mu = s * (1.f / 192.f);
    float d0 = v0 - mu, d1 = v1 - mu, d2 = v2 - mu;
    float q = d0 * d0 + d1 * d1 + d2 * d2;
    #pragma unroll
    for (int o = 32; o >= 1; o >>= 1) q += __shfl_xor(q, o, 64);
    float rs = rsqrtf(q * (1.f / 192.f) + 1e-5f);
    A1[r * 200 + lane]       = f2b(d0 * rs * g0 + bt0);
    A1[r * 200 + lane + 64]  = f2b(d1 * rs * g1 + bt1);
    A1[r * 200 + lane + 128] = f2b(d2 * rs * g2 + bt2);
  }
  __syncthreads();

  // GEMM1: (48 x 192) @ w1t^T -> (48 x 64); wave handles cols wave*16..+15
  f32x4 acc1[3] = {};
  #pragma unroll
  for (int ks = 0; ks < 6; ++ks) {
    bf16x8 bv = *(const bf16x8*)&w1t[(wave * 16 + la) * 192 + ks * 32 + lb * 8];
    #pragma unroll
    for (int m = 0; m < 3; ++m) {
      bf16x8 av = *(const bf16x8*)&A1[(m * 16 + la) * 200 + ks * 32 + lb * 8];
      acc1[m] = __builtin_amdgcn_mfma_f32_16x16x32_bf16(av, bv, acc1[m], 0, 0, 0);
    }
  }
  #pragma unroll
  for (int m = 0; m < 3; ++m)
    #pragma unroll
    for (int j = 0; j < 4; ++j)
      Y1[(m * 16 + lb * 4 + j) * 72 + wave * 16 + la] = f2b(fmaxf(acc1[m][j], 0.f));
  __syncthreads();

  // GEMM2: (48 x 64) @ w2t^T -> (48 x 64)
  f32x4 acc2[3] = {};
  #pragma unroll
  for (int ks = 0; ks < 2; ++ks) {
    bf16x8 bv = *(const bf16x8*)&w2t[(wave * 16 + la) * 64 + ks * 32 + lb * 8];
    #pragma unroll
    for (int m = 0; m < 3; ++m) {
      bf16x8 av = *(const bf16x8*)&Y1[(m * 16 + la) * 72 + ks * 32 + lb * 8];
      acc2[m] = __builtin_amdgcn_mfma_f32_16x16x32_bf16(av, bv, acc2[m], 0, 0, 0);
    }
  }
  #pragma unroll
  for (int m = 0; m < 3; ++m)
    #pragma unroll
    for (int j = 0; j < 4; ++j)
      Y2[(m * 16 + lb * 4 + j) * 66 + wave * 16 + la] = acc2[m][j];
  __syncthreads();

  long xb = (long)b * 3686400 + (long)n * 2304 + hh * 48;
  #pragma unroll
  for (int i = 0; i < 12; ++i) {
    int e = tid + 256 * i;
    int cc = e / 48, wv = e - cc * 48;
    long xi = xb + (long)cc * 57600 + wv;
    out[xi] = Y2[wv * 66 + cc] + x[xi];
  }
}

// ---------------- host launcher ----------------
extern "C" void kernel_launch(void* const* d_in, const int* in_sizes, int n_in,
                              void* d_out, int out_size, void* d_ws, size_t ws_size,
                              hipStream_t stream) {
  (void)in_sizes; (void)n_in; (void)out_size;
  const float* x     = (const float*)d_in[0];
  const float* gamma = (const float*)d_in[1];
  const float* beta  = (const float*)d_in[2];
  const float* w1    = (const float*)d_in[3];
  const float* w2    = (const float*)d_in[4];
  float* out = (float*)d_out;

  // workspace layout
  const size_t ATT_BIG   = 75497472;   // 4 x 3072 x 3072 bf16
  const size_t ATT_SMALL = 18874368;   // 1 x 3072 x 3072 bf16
  const size_t FIXED_TAIL = 35389440UL + 35389440UL + 2359296UL + 49152UL + 24576UL + 8192UL;
  const size_t NEED_BATCHED = 88473600UL + ATT_BIG + FIXED_TAIL;    // 237,191,168
  const size_t NEED_SERIAL  = 88473600UL + ATT_SMALL + FIXED_TAIL;  // 180,568,064
  bool batched = (ws_size >= NEED_BATCHED);
  if (ws_size < NEED_SERIAL) return;
  size_t attBytes = batched ? ATT_BIG : ATT_SMALL;

  char* ws = (char*)d_ws;
  short* F     = (short*)(ws);
  short* att   = (short*)(ws + 88473600UL);
  short* Qbf   = (short*)(ws + 88473600UL + attBytes);
  short* QbfT  = (short*)(ws + 88473600UL + attBytes + 35389440UL);
  float* Sf    = (float*)(ws + 88473600UL + attBytes + 70778880UL);
  float* invn  = (float*)(ws + 88473600UL + attBytes + 70778880UL + 2359296UL);
  short* w1t   = (short*)(ws + 88473600UL + attBytes + 70778880UL + 2359296UL + 49152UL);
  short* w2t   = (short*)(ws + 88473600UL + attBytes + 70778880UL + 2359296UL + 49152UL + 24576UL);

  prep_w_k<<<64, 256, 0, stream>>>(w1, w2, w1t, w2t);

  // ================= SF branch: M=3072, K=1200 Kp=1280 =================
  permute_sf_k<<<3072, 256, 0, stream>>>(x, Qbf);
  transpose_k<<<dim3(40, 96, 4), 256, 0, stream>>>(Qbf, QbfT, 3072, 1280);
  invnorm_k<<<dim3(3072, 4), 256, 0, stream>>>(Qbf, 3932160L, 1280, 3072, 3072, invn);
  if (batched) {
    gemm_k<4><<<dim3(24, 24, 4), 256, 0, stream>>>(
        Qbf, Qbf, 3932160L, 3932160L, 1280, 1280,
        20, 20, 1, 0, nullptr, 9437184L, 3072, att, invn, 3072, 0, 0);
    softmax_bf16_k<<<dim3(3072, 4), 256, 0, stream>>>(att, 9437184L, 3072);
    gemm_k<1><<<dim3(10, 24, 4), 256, 0, stream>>>(
        att, QbfT, 9437184L, 3932160L, 3072, 3072,
        48, 48, 1, 0, nullptr, 0, 0, F, x, 3072, 1200, 0);
  } else {
    for (int b = 0; b < 4; ++b) {
      long qoff = (long)b * 3932160L;
      gemm_k<4><<<dim3(24, 24, 1), 256, 0, stream>>>(
          Qbf + qoff, Qbf + qoff, 0, 0, 1280, 1280,
          20, 20, 1, 0, nullptr, 0, 3072, att, invn + (long)b * 3072, 3072, 0, 0);
      softmax_bf16_k<<<dim3(3072, 1), 256, 0, stream>>>(att, 0, 3072);
      gemm_k<1><<<dim3(10, 24, 1), 256, 0, stream>>>(
          att, QbfT + qoff, 0, 0, 3072, 3072,
          48, 48, 1, 0, nullptr, 0, 0, F, x, 3072, 1200, b);
    }
  }

  // ================= AF branch: M=320 Mp=384, Kp=11520 =================
  permute_k<1><<<4096, 256, 0, stream>>>(x, Qbf);
  transpose_k<<<dim3(360, 12, 4), 256, 0, stream>>>(Qbf, QbfT, 384, 11520);
  invnorm_k<<<dim3(384, 4), 256, 0, stream>>>(Qbf, 4423680L, 11520, 320, 384, invn);
  hipMemsetAsync(Sf, 0, (size_t)4 * 384 * 384 * 4, stream);
  gemm_k<0><<<dim3(3, 3, 32), 256, 0, stream>>>(
      Qbf, Qbf, 4423680L, 4423680L, 11520, 11520,
      180, 23, 8, 1, Sf, 147456L, 384, nullptr, nullptr, 0, 0, 0);
  softmax_k<<<dim3(320, 4), 256, 0, stream>>>(Sf, 147456L, invn, 320, 384, att, 147456L);
  gemm_k<2><<<dim3(90, 3, 4), 256, 0, stream>>>(
      att, QbfT, 147456L, 4423680L, 384, 384,
      6, 6, 1, 0, nullptr, 0, 0, F, x, 320, 11520, 0);

  // ================= SA branch: M=240 Mp=256, Kp=15360 =================
  permute_k<2><<<4096, 256, 0, stream>>>(x, Qbf);
  transpose_k<<<dim3(480, 8, 4), 256, 0, stream>>>(Qbf, QbfT, 256, 15360);
  invnorm_k<<<dim3(256, 4), 256, 0, stream>>>(Qbf, 3932160L, 15360, 240, 256, invn);
  hipMemsetAsync(Sf, 0, (size_t)4 * 256 * 256 * 4, stream);
  gemm_k<0><<<dim3(2, 2, 64), 256, 0, stream>>>(
      Qbf, Qbf, 3932160L, 3932160L, 15360, 15360,
      240, 15, 16, 1, Sf, 65536L, 256, nullptr, nullptr, 0, 0, 0);
  softmax_k<<<dim3(240, 4), 256, 0, stream>>>(Sf, 65536L, invn, 240, 256, att, 65536L);
  gemm_k<3><<<dim3(120, 2, 4), 256, 0, stream>>>(
      att, QbfT, 65536L, 3932160L, 256, 256,
      4, 4, 1, 0, nullptr, 0, 0, F, x, 240, 15360, 0);

  // ================= LayerNorm + MFMA MLP + residual =================
  ln_mlp_mfma_k<<<dim3(25, 48, 4), 256, 0, stream>>>(F, x, gamma, beta, w1t, w2t, out);
}

// Round 3
// 677.162 us; speedup vs baseline: 2.4493x; 2.0068x over previous
//
#include <hip/hip_runtime.h>
#include <stdint.h>

typedef __attribute__((ext_vector_type(8))) short bf16x8;
typedef __attribute__((ext_vector_type(4))) float f32x4;

__device__ __forceinline__ float b2f(short s) {
  union { unsigned u; float f; } a; a.u = ((unsigned)(unsigned short)s) << 16; return a.f;
}
__device__ __forceinline__ short f2b(float f) {
  union { float f; unsigned u; } a; a.f = f;
  unsigned r = a.u + 0x7fffu + ((a.u >> 16) & 1u);
  return (short)(r >> 16);
}
__device__ __forceinline__ void gload16(const void* g, void* l) {
  __builtin_amdgcn_global_load_lds((__attribute__((address_space(1))) void*)g,
                                   (__attribute__((address_space(3))) void*)l, 16, 0, 0);
}

// ---------------- permute kernels: x (b,c,25,48,48) f32 -> Qbf bf16 ----------------

// SF: m=(c,h) M=3072, k=(w,u,v) K=1200 Kp=1280.
__global__ __launch_bounds__(256) void permute_sf_k(const float* __restrict__ x, short* __restrict__ Q) {
  __shared__ float buf[4][1200];
  int wave = threadIdx.x >> 6, lane = threadIdx.x & 63;
  int gr = blockIdx.x * 4 + wave;
  int b = gr / 3072, m = gr - b * 3072;
  int c = m / 48, hh = m - c * 48;
  const float* xb = x + (long)(b * 64 + c) * 57600 + hh * 48;
  for (int uv = 0; uv < 25; ++uv)
    if (lane < 48) buf[wave][uv * 48 + lane] = xb[uv * 2304 + lane];
  __syncthreads();
  short* Qr = Q + (long)gr * 1280;
  for (int k = lane; k < 1280; k += 64) {
    float v = 0.f;
    if (k < 1200) { int wv = k / 25, uv = k - wv * 25; v = buf[wave][uv * 48 + wv]; }
    Qr[k] = f2b(v);
  }
}

// BR==1 AF: m=(c,u) M=320 Mp=384, k=(h,v,w) Kp=11520
// BR==2 SA: m=(h,u) M=240 Mp=256, k=(c,v,w) Kp=15360
template<int BR>
__global__ __launch_bounds__(256) void permute_k(const float* __restrict__ x, short* __restrict__ Q) {
  constexpr int M  = (BR == 1) ? 320 : 240;
  constexpr int Mp = (BR == 1) ? 384 : 256;
  constexpr int Kp = (BR == 1) ? 11520 : 15360;
  const int total = 4 * Mp * Kp;
  for (int idx = blockIdx.x * 256 + threadIdx.x; idx < total; idx += gridDim.x * 256) {
    int b = idx / (Mp * Kp);
    int rem = idx - b * (Mp * Kp);
    int m = rem / Kp;
    int k = rem - m * Kp;
    float v = 0.f;
    if (m < M) {
      int q1 = k / 240, r2 = k - q1 * 240;
      int v5 = r2 / 48, wv = r2 - v5 * 48;
      int a1 = m / 5, u = m - a1 * 5;
      long xi;
      if (BR == 1) xi = ((long)(b * 64 + a1) * 25 + u * 5 + v5) * 2304 + q1 * 48 + wv;
      else         xi = ((long)(b * 64 + q1) * 25 + u * 5 + v5) * 2304 + a1 * 48 + wv;
      v = x[xi];
    }
    Q[idx] = f2b(v);
  }
}

// ---------------- bf16 2D transpose per batch ----------------
__global__ __launch_bounds__(256) void transpose_k(const short* __restrict__ in, short* __restrict__ out,
                                                   int R, int C) {
  __shared__ short t[32][33];
  long base = (long)blockIdx.z * R * C;
  int c0 = blockIdx.x * 32, r0 = blockIdx.y * 32;
  int tx = threadIdx.x & 31, ty = threadIdx.x >> 5;
  #pragma unroll
  for (int i = 0; i < 32; i += 8)
    t[ty + i][tx] = in[base + (long)(r0 + ty + i) * C + c0 + tx];
  __syncthreads();
  #pragma unroll
  for (int i = 0; i < 32; i += 8)
    out[base + (long)(c0 + ty + i) * R + r0 + tx] = t[tx][ty + i];
}

// ---------------- row inv-norms ----------------
__global__ __launch_bounds__(256) void invnorm_k(const short* __restrict__ Q, long sQ, int Kp,
                                                 int Mvalid, int Mp, float* __restrict__ inv) {
  __shared__ float red[256];
  int m = blockIdx.x, b = blockIdx.y, tid = threadIdx.x;
  float acc = 0.f;
  if (m < Mvalid) {
    const short* row = Q + (long)b * sQ + (long)m * Kp;
    for (int k = tid * 8; k < Kp; k += 2048) {
      bf16x8 v = *(const bf16x8*)&row[k];
      #pragma unroll
      for (int j = 0; j < 8; ++j) { float f = b2f(v[j]); acc += f * f; }
    }
  }
  red[tid] = acc; __syncthreads();
  #pragma unroll
  for (int s2 = 128; s2 > 0; s2 >>= 1) {
    if (tid < s2) red[tid] += red[tid + s2];
    __syncthreads();
  }
  if (tid == 0)
    inv[(long)b * Mp + m] = (m < Mvalid) ? 1.0f / fmaxf(sqrtf(red[0]), 1e-12f) : 1.0f;
}

// ---------------- sf GEMM1: symmetric triangular, scaled bf16 S -> att (mirror write) -------
// grid (300, 1, 4); tile 128x128; Q (3072 x 1280)
__global__ __launch_bounds__(256) void gemm1_tri_k(const short* __restrict__ Q,
                                                   const float* __restrict__ invn,
                                                   short* __restrict__ att) {
  __shared__ short sm[17408];                 // As 8192 | Bs 8192; staged reuses all (128*136)
  short* As = sm;
  short* Bs = sm + 8192;
  int tid = threadIdx.x, wave = tid >> 6, lane = tid & 63;
  int la = lane & 15, lb = lane >> 4;
  int bat = blockIdx.z;
  int bx = blockIdx.x, yt = 0, rem = bx;
  while (rem >= 24 - yt) { rem -= 24 - yt; ++yt; }
  int xt = yt + rem;
  const short* Qb = Q + (long)bat * 3932160L;
  const float* inv = invn + (long)bat * 3072;
  int row0 = yt * 128, col0 = xt * 128;
  f32x4 acc[4][4] = {};
  int wr = wave >> 1, wc = wave & 1;

  for (int kt = 0; kt < 20; ++kt) {
    int k0 = kt * 64;
    #pragma unroll
    for (int p = 0; p < 4; ++p) {
      int e = p * 2048 + tid * 8;
      int r = e >> 6, c = e & 63;
      gload16(Qb + (long)(row0 + r) * 1280 + k0 + c, (void*)(As + e));
      gload16(Qb + (long)(col0 + r) * 1280 + k0 + c, (void*)(Bs + e));
    }
    __syncthreads();
    #pragma unroll
    for (int kk = 0; kk < 64; kk += 32) {
      bf16x8 av[4], bv[4];
      #pragma unroll
      for (int m = 0; m < 4; ++m)
        av[m] = *(const bf16x8*)&As[(wr * 64 + m * 16 + la) * 64 + kk + lb * 8];
      #pragma unroll
      for (int nn = 0; nn < 4; ++nn)
        bv[nn] = *(const bf16x8*)&Bs[(wc * 64 + nn * 16 + la) * 64 + kk + lb * 8];
      #pragma unroll
      for (int m = 0; m < 4; ++m)
        #pragma unroll
        for (int nn = 0; nn < 4; ++nn)
          acc[m][nn] = __builtin_amdgcn_mfma_f32_16x16x32_bf16(av[m], bv[nn], acc[m][nn], 0, 0, 0);
    }
    __syncthreads();
  }

  // scale by inv_i * inv_j and stage bf16 tile: staged[r*136 + c]
  short* staged = sm;
  #pragma unroll
  for (int m = 0; m < 4; ++m) {
    #pragma unroll
    for (int nn = 0; nn < 4; ++nn) {
      int cl = wc * 64 + nn * 16 + la;
      float ic = inv[col0 + cl];
      #pragma unroll
      for (int j = 0; j < 4; ++j) {
        int rl = wr * 64 + m * 16 + lb * 4 + j;
        staged[rl * 136 + cl] = f2b(acc[m][nn][j] * inv[row0 + rl] * ic);
      }
    }
  }
  __syncthreads();
  short* attb = att + (long)bat * 9437184L;
  {
    int r = tid >> 1, half = tid & 1;
    short* dst = attb + (long)(row0 + r) * 3072 + col0 + half * 64;
    const short* src = &staged[r * 136 + half * 64];
    #pragma unroll
    for (int q = 0; q < 8; ++q)
      *(bf16x8*)&dst[q * 8] = *(const bf16x8*)&src[q * 8];
  }
  if (xt != yt) {
    int c = tid >> 1, half = tid & 1;
    short* dst = attb + (long)(col0 + c) * 3072 + row0 + half * 64;
    #pragma unroll
    for (int q = 0; q < 8; ++q) {
      bf16x8 o;
      #pragma unroll
      for (int jj = 0; jj < 8; ++jj)
        o[jj] = staged[(half * 64 + q * 8 + jj) * 136 + c];
      *(bf16x8*)&dst[q * 8] = o;
    }
  }
}

// ---------------- af/sa GEMM1: raw f32 S, split-K atomics (A==B symmetric input) -------
__global__ __launch_bounds__(256) void gemm_s_k(
    const short* __restrict__ A, long sA, int lda,
    int ktotal, int ksper, int SK,
    float* __restrict__ Sf, long sS, int ldc)
{
  __shared__ short As[128 * 64];
  __shared__ short Bs[128 * 64];
  int tid = threadIdx.x;
  int wave = tid >> 6, lane = tid & 63;
  int la = lane & 15, lb = lane >> 4;
  int bz = blockIdx.z;
  int bat = bz / SK, kc = bz - bat * SK;
  int row0 = blockIdx.y * 128, col0 = blockIdx.x * 128;
  const short* Ab = A + (long)bat * sA;
  int kb = kc * ksper, ke = min(ktotal, kb + ksper);
  f32x4 acc[4][4] = {};
  int wr = wave >> 1, wc = wave & 1;

  for (int kt = kb; kt < ke; ++kt) {
    int k0 = kt * 64;
    #pragma unroll
    for (int p = 0; p < 4; ++p) {
      int e = p * 2048 + tid * 8;
      int row = e >> 6, col = e & 63;
      gload16(Ab + (long)(row0 + row) * lda + k0 + col, (void*)(As + e));
      gload16(Ab + (long)(col0 + row) * lda + k0 + col, (void*)(Bs + e));
    }
    __syncthreads();
    #pragma unroll
    for (int kk = 0; kk < 64; kk += 32) {
      bf16x8 av[4], bv[4];
      #pragma unroll
      for (int m = 0; m < 4; ++m)
        av[m] = *(const bf16x8*)&As[(wr * 64 + m * 16 + la) * 64 + kk + lb * 8];
      #pragma unroll
      for (int nn = 0; nn < 4; ++nn)
        bv[nn] = *(const bf16x8*)&Bs[(wc * 64 + nn * 16 + la) * 64 + kk + lb * 8];
      #pragma unroll
      for (int m = 0; m < 4; ++m)
        #pragma unroll
        for (int nn = 0; nn < 4; ++nn)
          acc[m][nn] = __builtin_amdgcn_mfma_f32_16x16x32_bf16(av[m], bv[nn], acc[m][nn], 0, 0, 0);
    }
    __syncthreads();
  }

  float* Sb = Sf + (long)bat * sS;
  #pragma unroll
  for (int m = 0; m < 4; ++m) {
    int gr0 = row0 + wr * 64 + m * 16 + lb * 4;
    #pragma unroll
    for (int nn = 0; nn < 4; ++nn) {
      int gc = col0 + wc * 64 + nn * 16 + la;
      #pragma unroll
      for (int j = 0; j < 4; ++j)
        atomicAdd(&Sb[(long)(gr0 + j) * ldc + gc], acc[m][nn][j]);
    }
  }
}

// ---------------- softmax over f32 raw dots (af/sa) ----------------
__global__ __launch_bounds__(256) void softmax_k(const float* __restrict__ Sf, long sS,
                                                 const float* __restrict__ inv,
                                                 int Mvalid, int Mp,
                                                 short* __restrict__ att, long sAtt) {
  __shared__ float srow[3072];
  __shared__ float red[256];
  int row = blockIdx.x, b = blockIdx.y, tid = threadIdx.x;
  const float* Sr = Sf + (long)b * sS + (long)row * Mp;
  const float* invb = inv + (long)b * Mp;
  float inv_i = invb[row];
  for (int j = tid; j < Mvalid; j += 256) srow[j] = Sr[j] * inv_i * invb[j];
  __syncthreads();
  float mx = -1e30f;
  for (int j = tid; j < Mvalid; j += 256) mx = fmaxf(mx, srow[j]);
  red[tid] = mx; __syncthreads();
  #pragma unroll
  for (int s2 = 128; s2 > 0; s2 >>= 1) {
    if (tid < s2) red[tid] = fmaxf(red[tid], red[tid + s2]);
    __syncthreads();
  }
  mx = red[0]; __syncthreads();
  float sum = 0.f;
  for (int j = tid; j < Mvalid; j += 256) {
    float e = __expf(srow[j] - mx);
    srow[j] = e; sum += e;
  }
  red[tid] = sum; __syncthreads();
  #pragma unroll
  for (int s2 = 128; s2 > 0; s2 >>= 1) {
    if (tid < s2) red[tid] += red[tid + s2];
    __syncthreads();
  }
  float rden = 1.0f / red[0];
  short* ar = att + (long)b * sAtt + (long)row * Mp;
  for (int j = tid; j < Mp; j += 256)
    ar[j] = (j < Mvalid) ? f2b(srow[j] * rden) : (short)0;
}

// ---------------- in-place softmax over bf16 scaled S (sf) ----------------
__global__ __launch_bounds__(256) void softmax_bf16_k(short* __restrict__ att, long sAtt, int M) {
  __shared__ float srow[3072];
  __shared__ float red[256];
  int row = blockIdx.x, b = blockIdx.y, tid = threadIdx.x;
  short* ar = att + (long)b * sAtt + (long)row * M;
  float mx = -1e30f;
  for (int j = tid * 8; j < M; j += 2048) {
    bf16x8 v = *(const bf16x8*)&ar[j];
    #pragma unroll
    for (int jj = 0; jj < 8; ++jj) { float f = b2f(v[jj]); srow[j + jj] = f; mx = fmaxf(mx, f); }
  }
  red[tid] = mx; __syncthreads();
  #pragma unroll
  for (int s2 = 128; s2 > 0; s2 >>= 1) {
    if (tid < s2) red[tid] = fmaxf(red[tid], red[tid + s2]);
    __syncthreads();
  }
  mx = red[0]; __syncthreads();
  float sum = 0.f;
  for (int j = tid; j < M; j += 256) {
    float e = __expf(srow[j] - mx);
    srow[j] = e; sum += e;
  }
  red[tid] = sum; __syncthreads();
  #pragma unroll
  for (int s2 = 128; s2 > 0; s2 >>= 1) {
    if (tid < s2) red[tid] += red[tid + s2];
    __syncthreads();
  }
  float rden = 1.0f / red[0];
  for (int j = tid * 8; j < M; j += 2048) {
    bf16x8 o;
    #pragma unroll
    for (int jj = 0; jj < 8; ++jj) o[jj] = f2b(srow[j + jj] * rden);
    *(bf16x8*)&ar[j] = o;
  }
}

// ---------------- GEMM2 (att @ QbfT^T), gather-row tiles, coalesced F scatter ----------------
// BR=1 sf, BR=2 af, BR=3 sa. Tile 64 rows x 256 cols, 4 waves. F gets RAW o (no +x).
template<int BR>
__global__ __launch_bounds__(256) void gemm2_k(const short* __restrict__ A,
                                               const short* __restrict__ B,
                                               short* __restrict__ F) {
  constexpr int NX  = (BR == 1) ? 5 : (BR == 2) ? 45 : 60;
  constexpr int NY  = (BR == 1) ? 48 : (BR == 2) ? 5 : 4;
  constexpr int NWG = NX * NY * 4;
  constexpr int LDA = (BR == 1) ? 3072 : (BR == 2) ? 384 : 256;
  constexpr long SA = (BR == 1) ? 9437184L : (BR == 2) ? 147456L : 65536L;
  constexpr long SB = (BR == 1) ? 3932160L : (BR == 2) ? 4423680L : 3932160L;
  constexpr int KST = (BR == 1) ? 48 : (BR == 2) ? 6 : 4;

  __shared__ short sm[20480];     // As 4096 | Bs 16384; staged (256*72=18432) reuses
  short* As = sm;
  short* Bs = sm + 4096;
  int tid = threadIdx.x, wave = tid >> 6, lane = tid & 63;
  int la = lane & 15, lb = lane >> 4;

  // bijective XCD swizzle (m204), yt-fastest ordering for B-panel L2 reuse
  int wk;
  { constexpr int q = NWG / 8, r = NWG % 8;
    int xcd = blockIdx.x & 7, j = blockIdx.x >> 3;
    wk = (xcd < r) ? xcd * (q + 1) + j : r * (q + 1) + (xcd - r) * q + j; }
  int yt = wk % NY, rem = wk / NY;
  int xt = rem % NX, bat = rem / NX;

  const short* Ab = A + (long)bat * SA;
  const short* Bb = B + (long)bat * SB;
  f32x4 acc[4][4] = {};

  for (int kt = 0; kt < KST; ++kt) {
    int k0 = kt * 64;
    #pragma unroll
    for (int p = 0; p < 2; ++p) {
      int e = p * 2048 + tid * 8;
      int r = e >> 6, col = e & 63;
      int rowg;
      if (BR == 1) rowg = r * 48 + yt;
      else if (BR == 2) rowg = r * 5 + yt;
      else rowg = yt * 64 + r;
      gload16(Ab + (long)rowg * LDA + k0 + col, (void*)(As + e));
    }
    #pragma unroll
    for (int p = 0; p < 8; ++p) {
      int e = p * 2048 + tid * 8;
      int rb = e >> 6, col = e & 63;
      int rowg;
      if (BR == 3) { int c = rb & 63, g = rb >> 6; rowg = c * 240 + xt * 4 + g; }
      else rowg = xt * 256 + rb;
      gload16(Bb + (long)rowg * LDA + k0 + col, (void*)(Bs + e));
    }
    __syncthreads();
    #pragma unroll
    for (int kk = 0; kk < 64; kk += 32) {
      bf16x8 av[4], bv[4];
      #pragma unroll
      for (int m = 0; m < 4; ++m)
        av[m] = *(const bf16x8*)&As[(m * 16 + la) * 64 + kk + lb * 8];
      #pragma unroll
      for (int nn = 0; nn < 4; ++nn)
        bv[nn] = *(const bf16x8*)&Bs[(wave * 64 + nn * 16 + la) * 64 + kk + lb * 8];
      #pragma unroll
      for (int m = 0; m < 4; ++m)
        #pragma unroll
        for (int nn = 0; nn < 4; ++nn)
          acc[m][nn] = __builtin_amdgcn_mfma_f32_16x16x32_bf16(av[m], bv[nn], acc[m][nn], 0, 0, 0);
    }
    __syncthreads();
  }

  // stage bf16 C tile: sf/af: staged[col*72 + row]; sa: staged[(row*4+g)*72 + c]
  short* staged = sm;
  #pragma unroll
  for (int m = 0; m < 4; ++m) {
    #pragma unroll
    for (int nn = 0; nn < 4; ++nn) {
      if (BR == 3) {
        #pragma unroll
        for (int j = 0; j < 4; ++j)
          staged[((m * 16 + lb * 4 + j) * 4 + wave) * 72 + nn * 16 + la] = f2b(acc[m][nn][j]);
      } else {
        short4 o;
        o.x = f2b(acc[m][nn][0]); o.y = f2b(acc[m][nn][1]);
        o.z = f2b(acc[m][nn][2]); o.w = f2b(acc[m][nn][3]);
        *(short4*)&staged[(wave * 64 + nn * 16 + la) * 72 + m * 16 + lb * 4] = o;
      }
    }
  }
  __syncthreads();

  // write F: 256 chunks of 64 channels (128B), 8 rounds x (32 chunks x 8 threads)
  #pragma unroll
  for (int rd = 0; rd < 8; ++rd) {
    int chunk = rd * 32 + (tid >> 3);
    int part = tid & 7;
    bf16x8 v = *(const bf16x8*)&staged[chunk * 72 + part * 8];
    long base; bool ok = true;
    if (BR == 1) {
      int gc = xt * 256 + chunk; ok = (gc < 1200);
      int wv = gc / 25, nidx = gc - wv * 25;
      base = (((long)(bat * 48 + yt) * 48 + wv) * 25 + nidx) * 192 + part * 8;
    } else if (BR == 2) {
      int gc = xt * 256 + chunk;
      int hh = gc / 240, r2 = gc - hh * 240, v5 = r2 / 48, wv = r2 - v5 * 48;
      base = (((long)(bat * 48 + hh) * 48 + wv) * 25 + yt * 5 + v5) * 192 + 64 + part * 8;
    } else {
      int r = chunk >> 2, g = chunk & 3;
      int gr = yt * 64 + r; ok = (gr < 240);
      int hh = gr / 5, u = gr - hh * 5;
      int r2 = xt * 4 + g, v5 = r2 / 48, wv = r2 - v5 * 48;
      base = (((long)(bat * 48 + hh) * 48 + wv) * 25 + u * 5 + v5) * 192 + 128 + part * 8;
    }
    if (ok) *(bf16x8*)&F[base] = v;
  }
}

// ---------------- weight prep ----------------
__global__ __launch_bounds__(256) void prep_w_k(const float* __restrict__ w1, const float* __restrict__ w2,
                                                short* __restrict__ w1t, short* __restrict__ w2t) {
  int idx = blockIdx.x * 256 + threadIdx.x;
  if (idx < 12288) {
    int i = idx / 64, j = idx - i * 64;
    w1t[j * 192 + i] = f2b(w1[idx]);
  } else if (idx < 16384) {
    int k = idx - 12288;
    int i = k / 64, j = k - i * 64;
    w2t[j * 64 + i] = f2b(w2[k]);
  }
}

// ---------------- fused (+x) LayerNorm + MFMA MLP + residual ----------------
// grid (25, 48, 4); F holds raw o; x added here (LN input) and at the end (residual)
__global__ __launch_bounds__(256) void ln_mlp_mfma_k(
    const short* __restrict__ F, const float* __restrict__ x,
    const float* __restrict__ gamma, const float* __restrict__ beta,
    const short* __restrict__ w1t, const short* __restrict__ w2t,
    float* __restrict__ out)
{
  int n = blockIdx.x, hh = blockIdx.y, b = blockIdx.z;
  __shared__ short A1[48 * 200];
  __shared__ short Y1[48 * 72];
  __shared__ float Y2[48 * 66];
  __shared__ float xs[64 * 49];
  int tid = threadIdx.x, wave = tid >> 6, lane = tid & 63;
  int la = lane & 15, lb = lane >> 4;
  long Fb0 = ((long)(b * 48 + hh) * 1200 + n) * 192;
  long xb = (long)b * 3686400 + (long)n * 2304 + hh * 48;

  { // coalesced x tile: 64 ch x 48 w
    int ch = tid >> 2, qq = tid & 3;
    const float* xr = x + xb + (long)ch * 57600 + qq * 12;
    #pragma unroll
    for (int i = 0; i < 12; ++i) xs[ch * 49 + qq * 12 + i] = xr[i];
  }
  __syncthreads();

  float g0 = gamma[lane], g1 = gamma[lane + 64], g2 = gamma[lane + 128];
  float bt0 = beta[lane], bt1 = beta[lane + 64], bt2 = beta[lane + 128];
  for (int r = wave; r < 48; r += 4) {
    const short* Fr = F + Fb0 + (long)r * 4800;
    float xv = xs[lane * 49 + r];
    float v0 = b2f(Fr[lane]) + xv, v1 = b2f(Fr[lane + 64]) + xv, v2 = b2f(Fr[lane + 128]) + xv;
    float s = v0 + v1 + v2;
    #pragma unroll
    for (int o = 32; o >= 1; o >>= 1) s += __shfl_xor(s, o, 64);
    float mu = s * (1.f / 192.f);
    float d0 = v0 - mu, d1 = v1 - mu, d2 = v2 - mu;
    float q = d0 * d0 + d1 * d1 + d2 * d2;
    #pragma unroll
    for (int o = 32; o >= 1; o >>= 1) q += __shfl_xor(q, o, 64);
    float rs = rsqrtf(q * (1.f / 192.f) + 1e-5f);
    A1[r * 200 + lane]       = f2b(d0 * rs * g0 + bt0);
    A1[r * 200 + lane + 64]  = f2b(d1 * rs * g1 + bt1);
    A1[r * 200 + lane + 128] = f2b(d2 * rs * g2 + bt2);
  }
  __syncthreads();

  f32x4 acc1[3] = {};
  #pragma unroll
  for (int ks = 0; ks < 6; ++ks) {
    bf16x8 bv = *(const bf16x8*)&w1t[(wave * 16 + la) * 192 + ks * 32 + lb * 8];
    #pragma unroll
    for (int m = 0; m < 3; ++m) {
      bf16x8 av = *(const bf16x8*)&A1[(m * 16 + la) * 200 + ks * 32 + lb * 8];
      acc1[m] = __builtin_amdgcn_mfma_f32_16x16x32_bf16(av, bv, acc1[m], 0, 0, 0);
    }
  }
  #pragma unroll
  for (int m = 0; m < 3; ++m)
    #pragma unroll
    for (int j = 0; j < 4; ++j)
      Y1[(m * 16 + lb * 4 + j) * 72 + wave * 16 + la] = f2b(fmaxf(acc1[m][j], 0.f));
  __syncthreads();

  f32x4 acc2[3] = {};
  #pragma unroll
  for (int ks = 0; ks < 2; ++ks) {
    bf16x8 bv = *(const bf16x8*)&w2t[(wave * 16 + la) * 64 + ks * 32 + lb * 8];
    #pragma unroll
    for (int m = 0; m < 3; ++m) {
      bf16x8 av = *(const bf16x8*)&Y1[(m * 16 + la) * 72 + ks * 32 + lb * 8];
      acc2[m] = __builtin_amdgcn_mfma_f32_16x16x32_bf16(av, bv, acc2[m], 0, 0, 0);
    }
  }
  #pragma unroll
  for (int m = 0; m < 3; ++m)
    #pragma unroll
    for (int j = 0; j < 4; ++j)
      Y2[(m * 16 + lb * 4 + j) * 66 + wave * 16 + la] = acc2[m][j];
  __syncthreads();

  #pragma unroll
  for (int i = 0; i < 12; ++i) {
    int e = tid + 256 * i;
    int cc = e / 48, wv = e - cc * 48;
    out[xb + (long)cc * 57600 + wv] = Y2[wv * 66 + cc] + xs[cc * 49 + wv];
  }
}

// ---------------- host launcher ----------------
extern "C" void kernel_launch(void* const* d_in, const int* in_sizes, int n_in,
                              void* d_out, int out_size, void* d_ws, size_t ws_size,
                              hipStream_t stream) {
  (void)in_sizes; (void)n_in; (void)out_size;
  const float* x     = (const float*)d_in[0];
  const float* gamma = (const float*)d_in[1];
  const float* beta  = (const float*)d_in[2];
  const float* w1    = (const float*)d_in[3];
  const float* w2    = (const float*)d_in[4];
  float* out = (float*)d_out;

  const size_t NEED = 237191168UL;
  if (ws_size < NEED) return;
  char* ws = (char*)d_ws;
  short* F     = (short*)(ws);                           // 88,473,600
  short* att   = (short*)(ws + 88473600UL);              // 75,497,472 (4x3072x3072 bf16)
  short* Qbf   = (short*)(ws + 163971072UL);             // 35,389,440
  short* QbfT  = (short*)(ws + 199360512UL);             // 35,389,440
  float* Sf    = (float*)(ws + 234749952UL);             //  2,359,296
  float* invn  = (float*)(ws + 237109248UL);             //     49,152
  short* w1t   = (short*)(ws + 237158400UL);             //     24,576
  short* w2t   = (short*)(ws + 237182976UL);             //      8,192

  prep_w_k<<<64, 256, 0, stream>>>(w1, w2, w1t, w2t);

  // ================= SF: M=3072, K=1200 (Kp=1280) =================
  permute_sf_k<<<3072, 256, 0, stream>>>(x, Qbf);
  transpose_k<<<dim3(40, 96, 4), 256, 0, stream>>>(Qbf, QbfT, 3072, 1280);
  invnorm_k<<<dim3(3072, 4), 256, 0, stream>>>(Qbf, 3932160L, 1280, 3072, 3072, invn);
  gemm1_tri_k<<<dim3(300, 1, 4), 256, 0, stream>>>(Qbf, invn, att);
  softmax_bf16_k<<<dim3(3072, 4), 256, 0, stream>>>(att, 9437184L, 3072);
  gemm2_k<1><<<dim3(960), 256, 0, stream>>>(att, QbfT, F);

  // ================= AF: M=320 (Mp=384), Kp=11520 =================
  permute_k<1><<<4096, 256, 0, stream>>>(x, Qbf);
  transpose_k<<<dim3(360, 12, 4), 256, 0, stream>>>(Qbf, QbfT, 384, 11520);
  invnorm_k<<<dim3(384, 4), 256, 0, stream>>>(Qbf, 4423680L, 11520, 320, 384, invn);
  hipMemsetAsync(Sf, 0, (size_t)4 * 384 * 384 * 4, stream);
  gemm_s_k<<<dim3(3, 3, 32), 256, 0, stream>>>(Qbf, 4423680L, 11520, 180, 23, 8, Sf, 147456L, 384);
  softmax_k<<<dim3(320, 4), 256, 0, stream>>>(Sf, 147456L, invn, 320, 384, att, 147456L);
  gemm2_k<2><<<dim3(900), 256, 0, stream>>>(att, QbfT, F);

  // ================= SA: M=240 (Mp=256), Kp=15360 =================
  permute_k<2><<<4096, 256, 0, stream>>>(x, Qbf);
  transpose_k<<<dim3(480, 8, 4), 256, 0, stream>>>(Qbf, QbfT, 256, 15360);
  invnorm_k<<<dim3(256, 4), 256, 0, stream>>>(Qbf, 3932160L, 15360, 240, 256, invn);
  hipMemsetAsync(Sf, 0, (size_t)4 * 256 * 256 * 4, stream);
  gemm_s_k<<<dim3(2, 2, 64), 256, 0, stream>>>(Qbf, 3932160L, 15360, 240, 15, 16, Sf, 65536L, 256);
  softmax_k<<<dim3(240, 4), 256, 0, stream>>>(Sf, 65536L, invn, 240, 256, att, 65536L);
  gemm2_k<3><<<dim3(960), 256, 0, stream>>>(att, QbfT, F);

  // ================= LN + MLP + residual =================
  ln_mlp_mfma_k<<<dim3(25, 48, 4), 256, 0, stream>>>(F, x, gamma, beta, w1t, w2t, out);
}

// Round 4
// 628.599 us; speedup vs baseline: 2.6386x; 1.0773x over previous
//
#include <hip/hip_runtime.h>
#include <stdint.h>

typedef __attribute__((ext_vector_type(8))) short bf16x8;
typedef __attribute__((ext_vector_type(4))) float f32x4;

__device__ __forceinline__ float b2f(short s) {
  union { unsigned u; float f; } a; a.u = ((unsigned)(unsigned short)s) << 16; return a.f;
}
__device__ __forceinline__ short f2b(float f) {
  union { float f; unsigned u; } a; a.f = f;
  unsigned r = a.u + 0x7fffu + ((a.u >> 16) & 1u);
  return (short)(r >> 16);
}
__device__ __forceinline__ void gload16(const void* g, void* l) {
  __builtin_amdgcn_global_load_lds((__attribute__((address_space(1))) void*)g,
                                   (__attribute__((address_space(3))) void*)l, 16, 0, 0);
}

// ---------------- permute kernels ----------------

// SF: m=(c,h) M=3072, k=(w,u,v) K=1200 Kp=1280.
__global__ __launch_bounds__(256) void permute_sf_k(const float* __restrict__ x, short* __restrict__ Q) {
  __shared__ float buf[4][1200];
  int wave = threadIdx.x >> 6, lane = threadIdx.x & 63;
  int gr = blockIdx.x * 4 + wave;
  int b = gr / 3072, m = gr - b * 3072;
  int c = m / 48, hh = m - c * 48;
  const float* xb = x + (long)(b * 64 + c) * 57600 + hh * 48;
  for (int uv = 0; uv < 25; ++uv)
    if (lane < 48) buf[wave][uv * 48 + lane] = xb[uv * 2304 + lane];
  __syncthreads();
  short* Qr = Q + (long)gr * 1280;
  for (int k = lane; k < 1280; k += 64) {
    float v = 0.f;
    if (k < 1200) { int wv = k / 25, uv = k - wv * 25; v = buf[wave][uv * 48 + wv]; }
    Qr[k] = f2b(v);
  }
}

// fused permute + transpose for af/sa: writes Qbf (Mp x Kp) AND QbfT (Kp x Mp)
// BR==1 AF: m=(c,u) M=320 Mp=384, k=(h,v,w) Kp=11520
// BR==2 SA: m=(h,u) M=240 Mp=256, k=(c,v,w) Kp=15360
template<int BR>
__global__ __launch_bounds__(256) void permtr_k(const float* __restrict__ x,
                                                short* __restrict__ Q, short* __restrict__ QT) {
  constexpr int M  = (BR == 1) ? 320 : 240;
  constexpr int Mp = (BR == 1) ? 384 : 256;
  constexpr int Kp = (BR == 1) ? 11520 : 15360;
  __shared__ short t[32][33];
  int b = blockIdx.z;
  int k0 = blockIdx.x * 32, m0 = blockIdx.y * 32;
  int tx = threadIdx.x & 31, ty = threadIdx.x >> 5;
  const float* xb = x + (long)b * 3686400;
  #pragma unroll
  for (int i = 0; i < 32; i += 8) {
    int m = m0 + ty + i, k = k0 + tx;
    float v = 0.f;
    if (m < M) {
      int q1 = k / 240, r2 = k - q1 * 240;
      int v5 = r2 / 48, wv = r2 - v5 * 48;
      int a1 = m / 5, u = m - a1 * 5;
      long xi;
      if (BR == 1) xi = ((long)a1 * 25 + u * 5 + v5) * 2304 + q1 * 48 + wv;
      else         xi = ((long)q1 * 25 + u * 5 + v5) * 2304 + a1 * 48 + wv;
      v = xb[xi];
    }
    t[ty + i][tx] = f2b(v);
  }
  __syncthreads();
  long Qb = (long)b * Mp * Kp;
  #pragma unroll
  for (int i = 0; i < 32; i += 8)
    Q[Qb + (long)(m0 + ty + i) * Kp + k0 + tx] = t[ty + i][tx];
  #pragma unroll
  for (int i = 0; i < 32; i += 8)
    QT[Qb + (long)(k0 + ty + i) * Mp + m0 + tx] = t[tx][ty + i];
}

// ---------------- bf16 2D transpose (sf only) ----------------
__global__ __launch_bounds__(256) void transpose_k(const short* __restrict__ in, short* __restrict__ out,
                                                   int R, int C) {
  __shared__ short t[32][33];
  long base = (long)blockIdx.z * R * C;
  int c0 = blockIdx.x * 32, r0 = blockIdx.y * 32;
  int tx = threadIdx.x & 31, ty = threadIdx.x >> 5;
  #pragma unroll
  for (int i = 0; i < 32; i += 8)
    t[ty + i][tx] = in[base + (long)(r0 + ty + i) * C + c0 + tx];
  __syncthreads();
  #pragma unroll
  for (int i = 0; i < 32; i += 8)
    out[base + (long)(c0 + ty + i) * R + r0 + tx] = t[tx][ty + i];
}

// ---------------- row inv-norms ----------------
__global__ __launch_bounds__(256) void invnorm_k(const short* __restrict__ Q, long sQ, int Kp,
                                                 int Mvalid, int Mp, float* __restrict__ inv) {
  __shared__ float red[256];
  int m = blockIdx.x, b = blockIdx.y, tid = threadIdx.x;
  float acc = 0.f;
  if (m < Mvalid) {
    const short* row = Q + (long)b * sQ + (long)m * Kp;
    for (int k = tid * 8; k < Kp; k += 2048) {
      bf16x8 v = *(const bf16x8*)&row[k];
      #pragma unroll
      for (int j = 0; j < 8; ++j) { float f = b2f(v[j]); acc += f * f; }
    }
  }
  red[tid] = acc; __syncthreads();
  #pragma unroll
  for (int s2 = 128; s2 > 0; s2 >>= 1) {
    if (tid < s2) red[tid] += red[tid + s2];
    __syncthreads();
  }
  if (tid == 0)
    inv[(long)b * Mp + m] = (m < Mvalid) ? 1.0f / fmaxf(sqrtf(red[0]), 1e-12f) : 1.0f;
}

// LDS XOR swizzle (T2, rule-21 form): linear LDS dest, inverse-swizzled global src col,
// swizzled ds_read col. col in shorts within a 64-short (128B) row; involution.
#define SWZ(row, col) ((col) ^ (((row) & 7) << 3))

// ---------------- sf GEMM1: symmetric triangular, scaled bf16 S -> att (mirror write) -------
__global__ __launch_bounds__(256) void gemm1_tri_k(const short* __restrict__ Q,
                                                   const float* __restrict__ invn,
                                                   short* __restrict__ att) {
  __shared__ short sm[17408];
  short* As = sm;
  short* Bs = sm + 8192;
  int tid = threadIdx.x, wave = tid >> 6, lane = tid & 63;
  int la = lane & 15, lb = lane >> 4;
  int bat = blockIdx.z;
  int bx = blockIdx.x, yt = 0, rem = bx;
  while (rem >= 24 - yt) { rem -= 24 - yt; ++yt; }
  int xt = yt + rem;
  const short* Qb = Q + (long)bat * 3932160L;
  const float* inv = invn + (long)bat * 3072;
  int row0 = yt * 128, col0 = xt * 128;
  f32x4 acc[4][4] = {};
  int wr = wave >> 1, wc = wave & 1;
  int rloc = tid >> 3, cbase = (tid & 7) * 8;

  for (int kt = 0; kt < 20; ++kt) {
    int k0 = kt * 64;
    #pragma unroll
    for (int p = 0; p < 4; ++p) {
      int row = p * 32 + rloc;
      int sc = SWZ(row, cbase);
      int e = p * 2048 + tid * 8;
      gload16(Qb + (long)(row0 + row) * 1280 + k0 + sc, (void*)(As + e));
      gload16(Qb + (long)(col0 + row) * 1280 + k0 + sc, (void*)(Bs + e));
    }
    __syncthreads();
    #pragma unroll
    for (int kk = 0; kk < 64; kk += 32) {
      bf16x8 av[4], bv[4];
      #pragma unroll
      for (int m = 0; m < 4; ++m)
        av[m] = *(const bf16x8*)&As[(wr * 64 + m * 16 + la) * 64 + SWZ(la, kk + lb * 8)];
      #pragma unroll
      for (int nn = 0; nn < 4; ++nn)
        bv[nn] = *(const bf16x8*)&Bs[(wc * 64 + nn * 16 + la) * 64 + SWZ(la, kk + lb * 8)];
      #pragma unroll
      for (int m = 0; m < 4; ++m)
        #pragma unroll
        for (int nn = 0; nn < 4; ++nn)
          acc[m][nn] = __builtin_amdgcn_mfma_f32_16x16x32_bf16(av[m], bv[nn], acc[m][nn], 0, 0, 0);
    }
    __syncthreads();
  }

  short* staged = sm;
  #pragma unroll
  for (int m = 0; m < 4; ++m) {
    #pragma unroll
    for (int nn = 0; nn < 4; ++nn) {
      int cl = wc * 64 + nn * 16 + la;
      float ic = inv[col0 + cl];
      #pragma unroll
      for (int j = 0; j < 4; ++j) {
        int rl = wr * 64 + m * 16 + lb * 4 + j;
        staged[rl * 136 + cl] = f2b(acc[m][nn][j] * inv[row0 + rl] * ic);
      }
    }
  }
  __syncthreads();
  short* attb = att + (long)bat * 9437184L;
  {
    int r = tid >> 1, half = tid & 1;
    short* dst = attb + (long)(row0 + r) * 3072 + col0 + half * 64;
    const short* src = &staged[r * 136 + half * 64];
    #pragma unroll
    for (int q = 0; q < 8; ++q)
      *(bf16x8*)&dst[q * 8] = *(const bf16x8*)&src[q * 8];
  }
  if (xt != yt) {
    int c = tid >> 1, half = tid & 1;
    short* dst = attb + (long)(col0 + c) * 3072 + row0 + half * 64;
    #pragma unroll
    for (int q = 0; q < 8; ++q) {
      bf16x8 o;
      #pragma unroll
      for (int jj = 0; jj < 8; ++jj)
        o[jj] = staged[(half * 64 + q * 8 + jj) * 136 + c];
      *(bf16x8*)&dst[q * 8] = o;
    }
  }
}

// ---------------- af/sa GEMM1: raw f32 S, split-K atomics (A==B) -------
__global__ __launch_bounds__(256) void gemm_s_k(
    const short* __restrict__ A, long sA, int lda,
    int ktotal, int ksper, int SK,
    float* __restrict__ Sf, long sS, int ldc)
{
  __shared__ short As[128 * 64];
  __shared__ short Bs[128 * 64];
  int tid = threadIdx.x;
  int wave = tid >> 6, lane = tid & 63;
  int la = lane & 15, lb = lane >> 4;
  int bz = blockIdx.z;
  int bat = bz / SK, kc = bz - bat * SK;
  int row0 = blockIdx.y * 128, col0 = blockIdx.x * 128;
  const short* Ab = A + (long)bat * sA;
  int kb = kc * ksper, ke = min(ktotal, kb + ksper);
  f32x4 acc[4][4] = {};
  int wr = wave >> 1, wc = wave & 1;
  int rloc = tid >> 3, cbase = (tid & 7) * 8;

  for (int kt = kb; kt < ke; ++kt) {
    int k0 = kt * 64;
    #pragma unroll
    for (int p = 0; p < 4; ++p) {
      int row = p * 32 + rloc;
      int sc = SWZ(row, cbase);
      int e = p * 2048 + tid * 8;
      gload16(Ab + (long)(row0 + row) * lda + k0 + sc, (void*)(As + e));
      gload16(Ab + (long)(col0 + row) * lda + k0 + sc, (void*)(Bs + e));
    }
    __syncthreads();
    #pragma unroll
    for (int kk = 0; kk < 64; kk += 32) {
      bf16x8 av[4], bv[4];
      #pragma unroll
      for (int m = 0; m < 4; ++m)
        av[m] = *(const bf16x8*)&As[(wr * 64 + m * 16 + la) * 64 + SWZ(la, kk + lb * 8)];
      #pragma unroll
      for (int nn = 0; nn < 4; ++nn)
        bv[nn] = *(const bf16x8*)&Bs[(wc * 64 + nn * 16 + la) * 64 + SWZ(la, kk + lb * 8)];
      #pragma unroll
      for (int m = 0; m < 4; ++m)
        #pragma unroll
        for (int nn = 0; nn < 4; ++nn)
          acc[m][nn] = __builtin_amdgcn_mfma_f32_16x16x32_bf16(av[m], bv[nn], acc[m][nn], 0, 0, 0);
    }
    __syncthreads();
  }

  float* Sb = Sf + (long)bat * sS;
  #pragma unroll
  for (int m = 0; m < 4; ++m) {
    int gr0 = row0 + wr * 64 + m * 16 + lb * 4;
    #pragma unroll
    for (int nn = 0; nn < 4; ++nn) {
      int gc = col0 + wc * 64 + nn * 16 + la;
      #pragma unroll
      for (int j = 0; j < 4; ++j)
        atomicAdd(&Sb[(long)(gr0 + j) * ldc + gc], acc[m][nn][j]);
    }
  }
}

// ---------------- softmax over f32 raw dots (af/sa) ----------------
__global__ __launch_bounds__(256) void softmax_k(const float* __restrict__ Sf, long sS,
                                                 const float* __restrict__ inv,
                                                 int Mvalid, int Mp,
                                                 short* __restrict__ att, long sAtt) {
  __shared__ float srow[3072];
  __shared__ float red[256];
  int row = blockIdx.x, b = blockIdx.y, tid = threadIdx.x;
  const float* Sr = Sf + (long)b * sS + (long)row * Mp;
  const float* invb = inv + (long)b * Mp;
  float inv_i = invb[row];
  for (int j = tid; j < Mvalid; j += 256) srow[j] = Sr[j] * inv_i * invb[j];
  __syncthreads();
  float mx = -1e30f;
  for (int j = tid; j < Mvalid; j += 256) mx = fmaxf(mx, srow[j]);
  red[tid] = mx; __syncthreads();
  #pragma unroll
  for (int s2 = 128; s2 > 0; s2 >>= 1) {
    if (tid < s2) red[tid] = fmaxf(red[tid], red[tid + s2]);
    __syncthreads();
  }
  mx = red[0]; __syncthreads();
  float sum = 0.f;
  for (int j = tid; j < Mvalid; j += 256) {
    float e = __expf(srow[j] - mx);
    srow[j] = e; sum += e;
  }
  red[tid] = sum; __syncthreads();
  #pragma unroll
  for (int s2 = 128; s2 > 0; s2 >>= 1) {
    if (tid < s2) red[tid] += red[tid + s2];
    __syncthreads();
  }
  float rden = 1.0f / red[0];
  short* ar = att + (long)b * sAtt + (long)row * Mp;
  for (int j = tid; j < Mp; j += 256)
    ar[j] = (j < Mvalid) ? f2b(srow[j] * rden) : (short)0;
}

// ---------------- in-place softmax over bf16 scaled S (sf) ----------------
__global__ __launch_bounds__(256) void softmax_bf16_k(short* __restrict__ att, long sAtt, int M) {
  __shared__ float srow[3072];
  __shared__ float red[256];
  int row = blockIdx.x, b = blockIdx.y, tid = threadIdx.x;
  short* ar = att + (long)b * sAtt + (long)row * M;
  float mx = -1e30f;
  for (int j = tid * 8; j < M; j += 2048) {
    bf16x8 v = *(const bf16x8*)&ar[j];
    #pragma unroll
    for (int jj = 0; jj < 8; ++jj) { float f = b2f(v[jj]); srow[j + jj] = f; mx = fmaxf(mx, f); }
  }
  red[tid] = mx; __syncthreads();
  #pragma unroll
  for (int s2 = 128; s2 > 0; s2 >>= 1) {
    if (tid < s2) red[tid] = fmaxf(red[tid], red[tid + s2]);
    __syncthreads();
  }
  mx = red[0]; __syncthreads();
  float sum = 0.f;
  for (int j = tid; j < M; j += 256) {
    float e = __expf(srow[j] - mx);
    srow[j] = e; sum += e;
  }
  red[tid] = sum; __syncthreads();
  #pragma unroll
  for (int s2 = 128; s2 > 0; s2 >>= 1) {
    if (tid < s2) red[tid] += red[tid + s2];
    __syncthreads();
  }
  float rden = 1.0f / red[0];
  for (int j = tid * 8; j < M; j += 2048) {
    bf16x8 o;
    #pragma unroll
    for (int jj = 0; jj < 8; ++jj) o[jj] = f2b(srow[j + jj] * rden);
    *(bf16x8*)&ar[j] = o;
  }
}

// ---------------- GEMM2 (att @ QbfT^T), gather-row tiles, coalesced F scatter ----------------
template<int BR>
__global__ __launch_bounds__(256) void gemm2_k(const short* __restrict__ A,
                                               const short* __restrict__ B,
                                               short* __restrict__ F) {
  constexpr int NX  = (BR == 1) ? 5 : (BR == 2) ? 45 : 60;
  constexpr int NY  = (BR == 1) ? 48 : (BR == 2) ? 5 : 4;
  constexpr int NWG = NX * NY * 4;
  constexpr int LDA = (BR == 1) ? 3072 : (BR == 2) ? 384 : 256;
  constexpr long SA = (BR == 1) ? 9437184L : (BR == 2) ? 147456L : 65536L;
  constexpr long SB = (BR == 1) ? 3932160L : (BR == 2) ? 4423680L : 3932160L;
  constexpr int KST = (BR == 1) ? 48 : (BR == 2) ? 6 : 4;

  __shared__ short sm[20480];
  short* As = sm;
  short* Bs = sm + 4096;
  int tid = threadIdx.x, wave = tid >> 6, lane = tid & 63;
  int la = lane & 15, lb = lane >> 4;

  int wk;
  { constexpr int q = NWG / 8, r = NWG % 8;
    int xcd = blockIdx.x & 7, j = blockIdx.x >> 3;
    wk = (xcd < r) ? xcd * (q + 1) + j : r * (q + 1) + (xcd - r) * q + j; }
  int yt = wk % NY, rem = wk / NY;
  int xt = rem % NX, bat = rem / NX;

  const short* Ab = A + (long)bat * SA;
  const short* Bb = B + (long)bat * SB;
  f32x4 acc[4][4] = {};
  int rloc = tid >> 3, cbase = (tid & 7) * 8;

  for (int kt = 0; kt < KST; ++kt) {
    int k0 = kt * 64;
    #pragma unroll
    for (int p = 0; p < 2; ++p) {
      int r = p * 32 + rloc;
      int sc = SWZ(r, cbase);
      int e = p * 2048 + tid * 8;
      int rowg;
      if (BR == 1) rowg = r * 48 + yt;
      else if (BR == 2) rowg = r * 5 + yt;
      else rowg = yt * 64 + r;
      gload16(Ab + (long)rowg * LDA + k0 + sc, (void*)(As + e));
    }
    #pragma unroll
    for (int p = 0; p < 8; ++p) {
      int rb = p * 32 + rloc;
      int sc = SWZ(rb, cbase);
      int e = p * 2048 + tid * 8;
      int rowg;
      if (BR == 3) { int c = rb & 63, g = rb >> 6; rowg = c * 240 + xt * 4 + g; }
      else rowg = xt * 256 + rb;
      gload16(Bb + (long)rowg * LDA + k0 + sc, (void*)(Bs + e));
    }
    __syncthreads();
    #pragma unroll
    for (int kk = 0; kk < 64; kk += 32) {
      bf16x8 av[4], bv[4];
      #pragma unroll
      for (int m = 0; m < 4; ++m)
        av[m] = *(const bf16x8*)&As[(m * 16 + la) * 64 + SWZ(la, kk + lb * 8)];
      #pragma unroll
      for (int nn = 0; nn < 4; ++nn)
        bv[nn] = *(const bf16x8*)&Bs[(wave * 64 + nn * 16 + la) * 64 + SWZ(la, kk + lb * 8)];
      #pragma unroll
      for (int m = 0; m < 4; ++m)
        #pragma unroll
        for (int nn = 0; nn < 4; ++nn)
          acc[m][nn] = __builtin_amdgcn_mfma_f32_16x16x32_bf16(av[m], bv[nn], acc[m][nn], 0, 0, 0);
    }
    __syncthreads();
  }

  short* staged = sm;
  #pragma unroll
  for (int m = 0; m < 4; ++m) {
    #pragma unroll
    for (int nn = 0; nn < 4; ++nn) {
      if (BR == 3) {
        #pragma unroll
        for (int j = 0; j < 4; ++j)
          staged[((m * 16 + lb * 4 + j) * 4 + wave) * 72 + nn * 16 + la] = f2b(acc[m][nn][j]);
      } else {
        short4 o;
        o.x = f2b(acc[m][nn][0]); o.y = f2b(acc[m][nn][1]);
        o.z = f2b(acc[m][nn][2]); o.w = f2b(acc[m][nn][3]);
        *(short4*)&staged[(wave * 64 + nn * 16 + la) * 72 + m * 16 + lb * 4] = o;
      }
    }
  }
  __syncthreads();

  #pragma unroll
  for (int rd = 0; rd < 8; ++rd) {
    int chunk = rd * 32 + (tid >> 3);
    int part = tid & 7;
    bf16x8 v = *(const bf16x8*)&staged[chunk * 72 + part * 8];
    long base; bool ok = true;
    if (BR == 1) {
      int gc = xt * 256 + chunk; ok = (gc < 1200);
      int wv = gc / 25, nidx = gc - wv * 25;
      base = (((long)(bat * 48 + yt) * 48 + wv) * 25 + nidx) * 192 + part * 8;
    } else if (BR == 2) {
      int gc = xt * 256 + chunk;
      int hh = gc / 240, r2 = gc - hh * 240, v5 = r2 / 48, wv = r2 - v5 * 48;
      base = (((long)(bat * 48 + hh) * 48 + wv) * 25 + yt * 5 + v5) * 192 + 64 + part * 8;
    } else {
      int r = chunk >> 2, g = chunk & 3;
      int gr = yt * 64 + r; ok = (gr < 240);
      int hh = gr / 5, u = gr - hh * 5;
      int r2 = xt * 4 + g, v5 = r2 / 48, wv = r2 - v5 * 48;
      base = (((long)(bat * 48 + hh) * 48 + wv) * 25 + u * 5 + v5) * 192 + 128 + part * 8;
    }
    if (ok) *(bf16x8*)&F[base] = v;
  }
}

// ---------------- weight prep ----------------
__global__ __launch_bounds__(256) void prep_w_k(const float* __restrict__ w1, const float* __restrict__ w2,
                                                short* __restrict__ w1t, short* __restrict__ w2t) {
  int idx = blockIdx.x * 256 + threadIdx.x;
  if (idx < 12288) {
    int i = idx / 64, j = idx - i * 64;
    w1t[j * 192 + i] = f2b(w1[idx]);
  } else if (idx < 16384) {
    int k = idx - 12288;
    int i = k / 64, j = k - i * 64;
    w2t[j * 64 + i] = f2b(w2[k]);
  }
}

// ---------------- fused (+x) LayerNorm + MFMA MLP + residual ----------------
__global__ __launch_bounds__(256) void ln_mlp_mfma_k(
    const short* __restrict__ F, const float* __restrict__ x,
    const float* __restrict__ gamma, const float* __restrict__ beta,
    const short* __restrict__ w1t, const short* __restrict__ w2t,
    float* __restrict__ out)
{
  int n = blockIdx.x, hh = blockIdx.y, b = blockIdx.z;
  __shared__ short A1[48 * 200];
  __shared__ short Y1[48 * 72];
  __shared__ float Y2[48 * 66];
  __shared__ float xs[64 * 49];
  int tid = threadIdx.x, wave = tid >> 6, lane = tid & 63;
  int la = lane & 15, lb = lane >> 4;
  long Fb0 = ((long)(b * 48 + hh) * 1200 + n) * 192;
  long xb = (long)b * 3686400 + (long)n * 2304 + hh * 48;

  {
    int ch = tid >> 2, qq = tid & 3;
    const float* xr = x + xb + (long)ch * 57600 + qq * 12;
    #pragma unroll
    for (int i = 0; i < 12; ++i) xs[ch * 49 + qq * 12 + i] = xr[i];
  }
  __syncthreads();

  float g0 = gamma[lane], g1 = gamma[lane + 64], g2 = gamma[lane + 128];
  float bt0 = beta[lane], bt1 = beta[lane + 64], bt2 = beta[lane + 128];
  for (int r = wave; r < 48; r += 4) {
    const short* Fr = F + Fb0 + (long)r * 4800;
    float xv = xs[lane * 49 + r];
    float v0 = b2f(Fr[lane]) + xv, v1 = b2f(Fr[lane + 64]) + xv, v2 = b2f(Fr[lane + 128]) + xv;
    float s = v0 + v1 + v2;
    #pragma unroll
    for (int o = 32; o >= 1; o >>= 1) s += __shfl_xor(s, o, 64);
    float mu = s * (1.f / 192.f);
    float d0 = v0 - mu, d1 = v1 - mu, d2 = v2 - mu;
    float q = d0 * d0 + d1 * d1 + d2 * d2;
    #pragma unroll
    for (int o = 32; o >= 1; o >>= 1) q += __shfl_xor(q, o, 64);
    float rs = rsqrtf(q * (1.f / 192.f) + 1e-5f);
    A1[r * 200 + lane]       = f2b(d0 * rs * g0 + bt0);
    A1[r * 200 + lane + 64]  = f2b(d1 * rs * g1 + bt1);
    A1[r * 200 + lane + 128] = f2b(d2 * rs * g2 + bt2);
  }
  __syncthreads();

  f32x4 acc1[3] = {};
  #pragma unroll
  for (int ks = 0; ks < 6; ++ks) {
    bf16x8 bv = *(const bf16x8*)&w1t[(wave * 16 + la) * 192 + ks * 32 + lb * 8];
    #pragma unroll
    for (int m = 0; m < 3; ++m) {
      bf16x8 av = *(const bf16x8*)&A1[(m * 16 + la) * 200 + ks * 32 + lb * 8];
      acc1[m] = __builtin_amdgcn_mfma_f32_16x16x32_bf16(av, bv, acc1[m], 0, 0, 0);
    }
  }
  #pragma unroll
  for (int m = 0; m < 3; ++m)
    #pragma unroll
    for (int j = 0; j < 4; ++j)
      Y1[(m * 16 + lb * 4 + j) * 72 + wave * 16 + la] = f2b(fmaxf(acc1[m][j], 0.f));
  __syncthreads();

  f32x4 acc2[3] = {};
  #pragma unroll
  for (int ks = 0; ks < 2; ++ks) {
    bf16x8 bv = *(const bf16x8*)&w2t[(wave * 16 + la) * 64 + ks * 32 + lb * 8];
    #pragma unroll
    for (int m = 0; m < 3; ++m) {
      bf16x8 av = *(const bf16x8*)&Y1[(m * 16 + la) * 72 + ks * 32 + lb * 8];
      acc2[m] = __builtin_amdgcn_mfma_f32_16x16x32_bf16(av, bv, acc2[m], 0, 0, 0);
    }
  }
  #pragma unroll
  for (int m = 0; m < 3; ++m)
    #pragma unroll
    for (int j = 0; j < 4; ++j)
      Y2[(m * 16 + lb * 4 + j) * 66 + wave * 16 + la] = acc2[m][j];
  __syncthreads();

  #pragma unroll
  for (int i = 0; i < 12; ++i) {
    int e = tid + 256 * i;
    int cc = e / 48, wv = e - cc * 48;
    out[xb + (long)cc * 57600 + wv] = Y2[wv * 66 + cc] + xs[cc * 49 + wv];
  }
}

// ---------------- host launcher ----------------
extern "C" void kernel_launch(void* const* d_in, const int* in_sizes, int n_in,
                              void* d_out, int out_size, void* d_ws, size_t ws_size,
                              hipStream_t stream) {
  (void)in_sizes; (void)n_in; (void)out_size;
  const float* x     = (const float*)d_in[0];
  const float* gamma = (const float*)d_in[1];
  const float* beta  = (const float*)d_in[2];
  const float* w1    = (const float*)d_in[3];
  const float* w2    = (const float*)d_in[4];
  float* out = (float*)d_out;

  const size_t NEED = 237191168UL;
  if (ws_size < NEED) return;
  char* ws = (char*)d_ws;
  short* F     = (short*)(ws);                           // 88,473,600
  short* att   = (short*)(ws + 88473600UL);              // 75,497,472
  short* Qbf   = (short*)(ws + 163971072UL);             // 35,389,440
  short* QbfT  = (short*)(ws + 199360512UL);             // 35,389,440
  float* Sf    = (float*)(ws + 234749952UL);             //  2,359,296
  float* invn  = (float*)(ws + 237109248UL);             //     49,152
  short* w1t   = (short*)(ws + 237158400UL);             //     24,576
  short* w2t   = (short*)(ws + 237182976UL);             //      8,192

  prep_w_k<<<64, 256, 0, stream>>>(w1, w2, w1t, w2t);

  // ================= SF: M=3072, K=1200 (Kp=1280) =================
  permute_sf_k<<<3072, 256, 0, stream>>>(x, Qbf);
  transpose_k<<<dim3(40, 96, 4), 256, 0, stream>>>(Qbf, QbfT, 3072, 1280);
  invnorm_k<<<dim3(3072, 4), 256, 0, stream>>>(Qbf, 3932160L, 1280, 3072, 3072, invn);
  gemm1_tri_k<<<dim3(300, 1, 4), 256, 0, stream>>>(Qbf, invn, att);
  softmax_bf16_k<<<dim3(3072, 4), 256, 0, stream>>>(att, 9437184L, 3072);
  gemm2_k<1><<<dim3(960), 256, 0, stream>>>(att, QbfT, F);

  // ================= AF: M=320 (Mp=384), Kp=11520 =================
  permtr_k<1><<<dim3(360, 12, 4), 256, 0, stream>>>(x, Qbf, QbfT);
  invnorm_k<<<dim3(384, 4), 256, 0, stream>>>(Qbf, 4423680L, 11520, 320, 384, invn);
  hipMemsetAsync(Sf, 0, (size_t)4 * 384 * 384 * 4, stream);
  gemm_s_k<<<dim3(3, 3, 32), 256, 0, stream>>>(Qbf, 4423680L, 11520, 180, 23, 8, Sf, 147456L, 384);
  softmax_k<<<dim3(320, 4), 256, 0, stream>>>(Sf, 147456L, invn, 320, 384, att, 147456L);
  gemm2_k<2><<<dim3(900), 256, 0, stream>>>(att, QbfT, F);

  // ================= SA: M=240 (Mp=256), Kp=15360 =================
  permtr_k<2><<<dim3(480, 8, 4), 256, 0, stream>>>(x, Qbf, QbfT);
  invnorm_k<<<dim3(256, 4), 256, 0, stream>>>(Qbf, 3932160L, 15360, 240, 256, invn);
  hipMemsetAsync(Sf, 0, (size_t)4 * 256 * 256 * 4, stream);
  gemm_s_k<<<dim3(2, 2, 64), 256, 0, stream>>>(Qbf, 3932160L, 15360, 240, 15, 16, Sf, 65536L, 256);
  softmax_k<<<dim3(240, 4), 256, 0, stream>>>(Sf, 65536L, invn, 240, 256, att, 65536L);
  gemm2_k<3><<<dim3(960), 256, 0, stream>>>(att, QbfT, F);

  // ================= LN + MLP + residual =================
  ln_mlp_mfma_k<<<dim3(25, 48, 4), 256, 0, stream>>>(F, x, gamma, beta, w1t, w2t, out);
}

// Round 5
// 568.782 us; speedup vs baseline: 2.9160x; 1.1052x over previous
//
#include <hip/hip_runtime.h>
#include <stdint.h>

typedef __attribute__((ext_vector_type(8))) short bf16x8;
typedef __attribute__((ext_vector_type(4))) float f32x4;

__device__ __forceinline__ float b2f(short s) {
  union { unsigned u; float f; } a; a.u = ((unsigned)(unsigned short)s) << 16; return a.f;
}
__device__ __forceinline__ short f2b(float f) {
  union { float f; unsigned u; } a; a.f = f;
  unsigned r = a.u + 0x7fffu + ((a.u >> 16) & 1u);
  return (short)(r >> 16);
}
__device__ __forceinline__ void gload16(const void* g, void* l) {
  __builtin_amdgcn_global_load_lds((__attribute__((address_space(1))) void*)g,
                                   (__attribute__((address_space(3))) void*)l, 16, 0, 0);
}

// LDS XOR swizzle (T2, rule-21 form): linear LDS dest, inverse-swizzled global src col,
// swizzled ds_read col. col in shorts within a 64-short (128B) row; involution.
#define SWZ(row, col) ((col) ^ (((row) & 7) << 3))

// ---------------- permute kernels ----------------

// SF: m=(c,h) M=3072, k=(w,u,v) K=1200 Kp=1280.
__global__ __launch_bounds__(256) void permute_sf_k(const float* __restrict__ x, short* __restrict__ Q) {
  __shared__ float buf[4][1200];
  int wave = threadIdx.x >> 6, lane = threadIdx.x & 63;
  int gr = blockIdx.x * 4 + wave;
  int b = gr / 3072, m = gr - b * 3072;
  int c = m / 48, hh = m - c * 48;
  const float* xb = x + (long)(b * 64 + c) * 57600 + hh * 48;
  for (int uv = 0; uv < 25; ++uv)
    if (lane < 48) buf[wave][uv * 48 + lane] = xb[uv * 2304 + lane];
  __syncthreads();
  short* Qr = Q + (long)gr * 1280;
  for (int k = lane; k < 1280; k += 64) {
    float v = 0.f;
    if (k < 1200) { int wv = k / 25, uv = k - wv * 25; v = buf[wave][uv * 48 + wv]; }
    Qr[k] = f2b(v);
  }
}

// fused permute + transpose for af/sa
template<int BR>
__global__ __launch_bounds__(256) void permtr_k(const float* __restrict__ x,
                                                short* __restrict__ Q, short* __restrict__ QT) {
  constexpr int M  = (BR == 1) ? 320 : 240;
  constexpr int Mp = (BR == 1) ? 384 : 256;
  constexpr int Kp = (BR == 1) ? 11520 : 15360;
  __shared__ short t[32][33];
  int b = blockIdx.z;
  int k0 = blockIdx.x * 32, m0 = blockIdx.y * 32;
  int tx = threadIdx.x & 31, ty = threadIdx.x >> 5;
  const float* xb = x + (long)b * 3686400;
  #pragma unroll
  for (int i = 0; i < 32; i += 8) {
    int m = m0 + ty + i, k = k0 + tx;
    float v = 0.f;
    if (m < M) {
      int q1 = k / 240, r2 = k - q1 * 240;
      int v5 = r2 / 48, wv = r2 - v5 * 48;
      int a1 = m / 5, u = m - a1 * 5;
      long xi;
      if (BR == 1) xi = ((long)a1 * 25 + u * 5 + v5) * 2304 + q1 * 48 + wv;
      else         xi = ((long)q1 * 25 + u * 5 + v5) * 2304 + a1 * 48 + wv;
      v = xb[xi];
    }
    t[ty + i][tx] = f2b(v);
  }
  __syncthreads();
  long Qb = (long)b * Mp * Kp;
  #pragma unroll
  for (int i = 0; i < 32; i += 8)
    Q[Qb + (long)(m0 + ty + i) * Kp + k0 + tx] = t[ty + i][tx];
  #pragma unroll
  for (int i = 0; i < 32; i += 8)
    QT[Qb + (long)(k0 + ty + i) * Mp + m0 + tx] = t[tx][ty + i];
}

// ---------------- bf16 2D transpose (sf only) ----------------
__global__ __launch_bounds__(256) void transpose_k(const short* __restrict__ in, short* __restrict__ out,
                                                   int R, int C) {
  __shared__ short t[32][33];
  long base = (long)blockIdx.z * R * C;
  int c0 = blockIdx.x * 32, r0 = blockIdx.y * 32;
  int tx = threadIdx.x & 31, ty = threadIdx.x >> 5;
  #pragma unroll
  for (int i = 0; i < 32; i += 8)
    t[ty + i][tx] = in[base + (long)(r0 + ty + i) * C + c0 + tx];
  __syncthreads();
  #pragma unroll
  for (int i = 0; i < 32; i += 8)
    out[base + (long)(c0 + ty + i) * R + r0 + tx] = t[tx][ty + i];
}

// ---------------- row inv-norms ----------------
__global__ __launch_bounds__(256) void invnorm_k(const short* __restrict__ Q, long sQ, int Kp,
                                                 int Mvalid, int Mp, float* __restrict__ inv) {
  __shared__ float red[256];
  int m = blockIdx.x, b = blockIdx.y, tid = threadIdx.x;
  float acc = 0.f;
  if (m < Mvalid) {
    const short* row = Q + (long)b * sQ + (long)m * Kp;
    for (int k = tid * 8; k < Kp; k += 2048) {
      bf16x8 v = *(const bf16x8*)&row[k];
      #pragma unroll
      for (int j = 0; j < 8; ++j) { float f = b2f(v[j]); acc += f * f; }
    }
  }
  red[tid] = acc; __syncthreads();
  #pragma unroll
  for (int s2 = 128; s2 > 0; s2 >>= 1) {
    if (tid < s2) red[tid] += red[tid + s2];
    __syncthreads();
  }
  if (tid == 0)
    inv[(long)b * Mp + m] = (m < Mvalid) ? 1.0f / fmaxf(sqrtf(red[0]), 1e-12f) : 1.0f;
}

// ---------------- sf GEMM1: triangular, 2-phase dbuf + counted vmcnt ----------------
// grid (300, 1, 4); tile 128x128; Q (3072 x 1280), KST=20
__global__ __launch_bounds__(256) void gemm1_tri_k(const short* __restrict__ Q,
                                                   const float* __restrict__ invn,
                                                   short* __restrict__ att) {
  __shared__ short sm[32768];      // dbuf: [buf*16384] As 8192 | Bs 8192; epilogue reuses
  int tid = threadIdx.x, wave = tid >> 6, lane = tid & 63;
  int la = lane & 15, lb = lane >> 4;
  int bat = blockIdx.z;
  int bx = blockIdx.x, yt = 0, rem = bx;
  while (rem >= 24 - yt) { rem -= 24 - yt; ++yt; }
  int xt = yt + rem;
  const short* Qb = Q + (long)bat * 3932160L;
  const float* inv = invn + (long)bat * 3072;
  int row0 = yt * 128, col0 = xt * 128;
  f32x4 acc[4][4] = {};
  int wr = wave >> 1, wc = wave & 1;
  int rloc = tid >> 3, cbase = (tid & 7) * 8;

  #define TRI_STAGE(KT, BUF) { \
    int k0 = (KT) * 64; \
    short* Asb = sm + (BUF) * 16384; \
    short* Bsb = Asb + 8192; \
    _Pragma("unroll") \
    for (int p = 0; p < 4; ++p) { \
      int row = p * 32 + rloc; \
      int sc = SWZ(row, cbase); \
      gload16(Qb + (long)(row0 + row) * 1280 + k0 + sc, (void*)(Asb + p * 2048 + tid * 8)); \
      gload16(Qb + (long)(col0 + row) * 1280 + k0 + sc, (void*)(Bsb + p * 2048 + tid * 8)); \
    } }
  #define TRI_COMP(BUF) { \
    const short* Asb = sm + (BUF) * 16384; \
    const short* Bsb = Asb + 8192; \
    _Pragma("unroll") \
    for (int kk = 0; kk < 64; kk += 32) { \
      bf16x8 av[4], bv[4]; \
      _Pragma("unroll") \
      for (int m = 0; m < 4; ++m) \
        av[m] = *(const bf16x8*)&Asb[(wr * 64 + m * 16 + la) * 64 + SWZ(la, kk + lb * 8)]; \
      _Pragma("unroll") \
      for (int nn = 0; nn < 4; ++nn) \
        bv[nn] = *(const bf16x8*)&Bsb[(wc * 64 + nn * 16 + la) * 64 + SWZ(la, kk + lb * 8)]; \
      _Pragma("unroll") \
      for (int m = 0; m < 4; ++m) \
        _Pragma("unroll") \
        for (int nn = 0; nn < 4; ++nn) \
          acc[m][nn] = __builtin_amdgcn_mfma_f32_16x16x32_bf16(av[m], bv[nn], acc[m][nn], 0, 0, 0); \
    } }

  TRI_STAGE(0, 0)
  for (int kt = 0; kt < 19; ++kt) {
    TRI_STAGE(kt + 1, (kt + 1) & 1)
    asm volatile("s_waitcnt vmcnt(8)" ::: "memory");
    __builtin_amdgcn_s_barrier();
    TRI_COMP(kt & 1)
    asm volatile("" ::: "memory");
    __builtin_amdgcn_s_barrier();
  }
  asm volatile("s_waitcnt vmcnt(0)" ::: "memory");
  __builtin_amdgcn_s_barrier();
  TRI_COMP(1)
  asm volatile("" ::: "memory");
  __builtin_amdgcn_s_barrier();

  short* staged = sm;
  #pragma unroll
  for (int m = 0; m < 4; ++m) {
    #pragma unroll
    for (int nn = 0; nn < 4; ++nn) {
      int cl = wc * 64 + nn * 16 + la;
      float ic = inv[col0 + cl];
      #pragma unroll
      for (int j = 0; j < 4; ++j) {
        int rl = wr * 64 + m * 16 + lb * 4 + j;
        staged[rl * 136 + cl] = f2b(acc[m][nn][j] * inv[row0 + rl] * ic);
      }
    }
  }
  __syncthreads();
  short* attb = att + (long)bat * 9437184L;
  {
    int r = tid >> 1, half = tid & 1;
    short* dst = attb + (long)(row0 + r) * 3072 + col0 + half * 64;
    const short* src = &staged[r * 136 + half * 64];
    #pragma unroll
    for (int q = 0; q < 8; ++q)
      *(bf16x8*)&dst[q * 8] = *(const bf16x8*)&src[q * 8];
  }
  if (xt != yt) {
    int c = tid >> 1, half = tid & 1;
    short* dst = attb + (long)(col0 + c) * 3072 + row0 + half * 64;
    #pragma unroll
    for (int q = 0; q < 8; ++q) {
      bf16x8 o;
      #pragma unroll
      for (int jj = 0; jj < 8; ++jj)
        o[jj] = staged[(half * 64 + q * 8 + jj) * 136 + c];
      *(bf16x8*)&dst[q * 8] = o;
    }
  }
}

// ---------------- af/sa GEMM1: raw f32 S, split-K atomics, 2-phase dbuf ----------------
__global__ __launch_bounds__(256) void gemm_s_k(
    const short* __restrict__ A, long sA, int lda,
    int ktotal, int ksper, int SK,
    float* __restrict__ Sf, long sS, int ldc)
{
  __shared__ short sm[32768];
  int tid = threadIdx.x;
  int wave = tid >> 6, lane = tid & 63;
  int la = lane & 15, lb = lane >> 4;
  int bz = blockIdx.z;
  int bat = bz / SK, kc = bz - bat * SK;
  int row0 = blockIdx.y * 128, col0 = blockIdx.x * 128;
  const short* Ab = A + (long)bat * sA;
  int kb = kc * ksper, ke = min(ktotal, kb + ksper);
  int L = ke - kb;
  f32x4 acc[4][4] = {};
  int wr = wave >> 1, wc = wave & 1;
  int rloc = tid >> 3, cbase = (tid & 7) * 8;

  #define GS_STAGE(KT, BUF) { \
    int k0 = (KT) * 64; \
    short* Asb = sm + (BUF) * 16384; \
    short* Bsb = Asb + 8192; \
    _Pragma("unroll") \
    for (int p = 0; p < 4; ++p) { \
      int row = p * 32 + rloc; \
      int sc = SWZ(row, cbase); \
      gload16(Ab + (long)(row0 + row) * lda + k0 + sc, (void*)(Asb + p * 2048 + tid * 8)); \
      gload16(Ab + (long)(col0 + row) * lda + k0 + sc, (void*)(Bsb + p * 2048 + tid * 8)); \
    } }
  #define GS_COMP(BUF) { \
    const short* Asb = sm + (BUF) * 16384; \
    const short* Bsb = Asb + 8192; \
    _Pragma("unroll") \
    for (int kk = 0; kk < 64; kk += 32) { \
      bf16x8 av[4], bv[4]; \
      _Pragma("unroll") \
      for (int m = 0; m < 4; ++m) \
        av[m] = *(const bf16x8*)&Asb[(wr * 64 + m * 16 + la) * 64 + SWZ(la, kk + lb * 8)]; \
      _Pragma("unroll") \
      for (int nn = 0; nn < 4; ++nn) \
        bv[nn] = *(const bf16x8*)&Bsb[(wc * 64 + nn * 16 + la) * 64 + SWZ(la, kk + lb * 8)]; \
      _Pragma("unroll") \
      for (int m = 0; m < 4; ++m) \
        _Pragma("unroll") \
        for (int nn = 0; nn < 4; ++nn) \
          acc[m][nn] = __builtin_amdgcn_mfma_f32_16x16x32_bf16(av[m], bv[nn], acc[m][nn], 0, 0, 0); \
    } }

  GS_STAGE(kb, 0)
  for (int t = 0; t < L - 1; ++t) {
    GS_STAGE(kb + t + 1, (t + 1) & 1)
    asm volatile("s_waitcnt vmcnt(8)" ::: "memory");
    __builtin_amdgcn_s_barrier();
    GS_COMP(t & 1)
    asm volatile("" ::: "memory");
    __builtin_amdgcn_s_barrier();
  }
  asm volatile("s_waitcnt vmcnt(0)" ::: "memory");
  __builtin_amdgcn_s_barrier();
  GS_COMP((L - 1) & 1)

  float* Sb = Sf + (long)bat * sS;
  #pragma unroll
  for (int m = 0; m < 4; ++m) {
    int gr0 = row0 + wr * 64 + m * 16 + lb * 4;
    #pragma unroll
    for (int nn = 0; nn < 4; ++nn) {
      int gc = col0 + wc * 64 + nn * 16 + la;
      #pragma unroll
      for (int j = 0; j < 4; ++j)
        atomicAdd(&Sb[(long)(gr0 + j) * ldc + gc], acc[m][nn][j]);
    }
  }
}

// ---------------- softmax over f32 raw dots (af/sa) ----------------
__global__ __launch_bounds__(256) void softmax_k(const float* __restrict__ Sf, long sS,
                                                 const float* __restrict__ inv,
                                                 int Mvalid, int Mp,
                                                 short* __restrict__ att, long sAtt) {
  __shared__ float srow[3072];
  __shared__ float red[256];
  int row = blockIdx.x, b = blockIdx.y, tid = threadIdx.x;
  const float* Sr = Sf + (long)b * sS + (long)row * Mp;
  const float* invb = inv + (long)b * Mp;
  float inv_i = invb[row];
  for (int j = tid; j < Mvalid; j += 256) srow[j] = Sr[j] * inv_i * invb[j];
  __syncthreads();
  float mx = -1e30f;
  for (int j = tid; j < Mvalid; j += 256) mx = fmaxf(mx, srow[j]);
  red[tid] = mx; __syncthreads();
  #pragma unroll
  for (int s2 = 128; s2 > 0; s2 >>= 1) {
    if (tid < s2) red[tid] = fmaxf(red[tid], red[tid + s2]);
    __syncthreads();
  }
  mx = red[0]; __syncthreads();
  float sum = 0.f;
  for (int j = tid; j < Mvalid; j += 256) {
    float e = __expf(srow[j] - mx);
    srow[j] = e; sum += e;
  }
  red[tid] = sum; __syncthreads();
  #pragma unroll
  for (int s2 = 128; s2 > 0; s2 >>= 1) {
    if (tid < s2) red[tid] += red[tid + s2];
    __syncthreads();
  }
  float rden = 1.0f / red[0];
  short* ar = att + (long)b * sAtt + (long)row * Mp;
  for (int j = tid; j < Mp; j += 256)
    ar[j] = (j < Mvalid) ? f2b(srow[j] * rden) : (short)0;
}

// ---------------- in-place softmax over bf16 scaled S (sf) ----------------
__global__ __launch_bounds__(256) void softmax_bf16_k(short* __restrict__ att, long sAtt, int M) {
  __shared__ float srow[3072];
  __shared__ float red[256];
  int row = blockIdx.x, b = blockIdx.y, tid = threadIdx.x;
  short* ar = att + (long)b * sAtt + (long)row * M;
  float mx = -1e30f;
  for (int j = tid * 8; j < M; j += 2048) {
    bf16x8 v = *(const bf16x8*)&ar[j];
    #pragma unroll
    for (int jj = 0; jj < 8; ++jj) { float f = b2f(v[jj]); srow[j + jj] = f; mx = fmaxf(mx, f); }
  }
  red[tid] = mx; __syncthreads();
  #pragma unroll
  for (int s2 = 128; s2 > 0; s2 >>= 1) {
    if (tid < s2) red[tid] = fmaxf(red[tid], red[tid + s2]);
    __syncthreads();
  }
  mx = red[0]; __syncthreads();
  float sum = 0.f;
  for (int j = tid; j < M; j += 256) {
    float e = __expf(srow[j] - mx);
    srow[j] = e; sum += e;
  }
  red[tid] = sum; __syncthreads();
  #pragma unroll
  for (int s2 = 128; s2 > 0; s2 >>= 1) {
    if (tid < s2) red[tid] += red[tid + s2];
    __syncthreads();
  }
  float rden = 1.0f / red[0];
  for (int j = tid * 8; j < M; j += 2048) {
    bf16x8 o;
    #pragma unroll
    for (int jj = 0; jj < 8; ++jj) o[jj] = f2b(srow[j + jj] * rden);
    *(bf16x8*)&ar[j] = o;
  }
}

// ---------------- sf GEMM2: 128x128 tile (yt-pair), 2-phase dbuf + counted vmcnt ----------------
// A = att (3072x3072), B = QbfT (1280x3072), KST=48, grid(960)
__global__ __launch_bounds__(256) void gemm2sf_k(const short* __restrict__ A,
                                                 const short* __restrict__ B,
                                                 short* __restrict__ F) {
  __shared__ short sm[32768];
  int tid = threadIdx.x, wave = tid >> 6, lane = tid & 63;
  int la = lane & 15, lb = lane >> 4;
  int wr = wave >> 1, wc = wave & 1;
  int wk;
  { int xcd = blockIdx.x & 7, j = blockIdx.x >> 3; wk = xcd * 120 + j; }  // 960 % 8 == 0
  int yt = wk % 24, rem = wk / 24;
  int xt = rem % 10, bat = rem / 10;
  const short* Ab = A + (long)bat * 9437184L;
  const short* Bb = B + (long)bat * 3932160L;
  int rloc = tid >> 3, cbase = (tid & 7) * 8;
  f32x4 acc[4][4] = {};

  // A rows gathered: rowg = (row&63)*48 + yt*2 + (row>>6)  (c fastest, hh = yt*2 + sub)
  #define G2_STAGE(KT, BUF) { \
    int k0 = (KT) * 64; \
    short* Asb = sm + (BUF) * 16384; \
    short* Bsb = Asb + 8192; \
    _Pragma("unroll") \
    for (int p = 0; p < 4; ++p) { \
      int row = p * 32 + rloc; \
      int sc = SWZ(row, cbase); \
      int rga = (row & 63) * 48 + yt * 2 + (row >> 6); \
      gload16(Ab + (long)rga * 3072 + k0 + sc, (void*)(Asb + p * 2048 + tid * 8)); \
      int rgb = xt * 128 + row; \
      gload16(Bb + (long)rgb * 3072 + k0 + sc, (void*)(Bsb + p * 2048 + tid * 8)); \
    } }
  #define G2_COMP(BUF) { \
    const short* Asb = sm + (BUF) * 16384; \
    const short* Bsb = Asb + 8192; \
    _Pragma("unroll") \
    for (int kk = 0; kk < 64; kk += 32) { \
      bf16x8 av[4], bv[4]; \
      _Pragma("unroll") \
      for (int m = 0; m < 4; ++m) \
        av[m] = *(const bf16x8*)&Asb[(wr * 64 + m * 16 + la) * 64 + SWZ(la, kk + lb * 8)]; \
      _Pragma("unroll") \
      for (int nn = 0; nn < 4; ++nn) \
        bv[nn] = *(const bf16x8*)&Bsb[(wc * 64 + nn * 16 + la) * 64 + SWZ(la, kk + lb * 8)]; \
      _Pragma("unroll") \
      for (int m = 0; m < 4; ++m) \
        _Pragma("unroll") \
        for (int nn = 0; nn < 4; ++nn) \
          acc[m][nn] = __builtin_amdgcn_mfma_f32_16x16x32_bf16(av[m], bv[nn], acc[m][nn], 0, 0, 0); \
    } }

  G2_STAGE(0, 0)
  for (int kt = 0; kt < 47; ++kt) {
    G2_STAGE(kt + 1, (kt + 1) & 1)
    asm volatile("s_waitcnt vmcnt(8)" ::: "memory");
    __builtin_amdgcn_s_barrier();
    G2_COMP(kt & 1)
    asm volatile("" ::: "memory");
    __builtin_amdgcn_s_barrier();
  }
  asm volatile("s_waitcnt vmcnt(0)" ::: "memory");
  __builtin_amdgcn_s_barrier();
  G2_COMP(1)
  asm volatile("" ::: "memory");
  __builtin_amdgcn_s_barrier();

  // stage C tile: chunk = cc*2 + sub (sub = local row>>6), 64 c's per chunk, pitch 72
  short* staged = sm;
  #pragma unroll
  for (int m = 0; m < 4; ++m) {
    #pragma unroll
    for (int nn = 0; nn < 4; ++nn) {
      int cc = wc * 64 + nn * 16 + la;
      short4 o;
      o.x = f2b(acc[m][nn][0]); o.y = f2b(acc[m][nn][1]);
      o.z = f2b(acc[m][nn][2]); o.w = f2b(acc[m][nn][3]);
      *(short4*)&staged[(cc * 2 + wr) * 72 + m * 16 + lb * 4] = o;
    }
  }
  __syncthreads();
  #pragma unroll
  for (int rd = 0; rd < 8; ++rd) {
    int chunk = rd * 32 + (tid >> 3);
    int part = tid & 7;
    bf16x8 v = *(const bf16x8*)&staged[chunk * 72 + part * 8];
    int cc = chunk >> 1, sub = chunk & 1;
    int gc = xt * 128 + cc;
    if (gc < 1200) {
      int hh = yt * 2 + sub;
      int wv = gc / 25, nidx = gc - wv * 25;
      long base = (((long)(bat * 48 + hh) * 48 + wv) * 25 + nidx) * 192 + part * 8;
      *(bf16x8*)&F[base] = v;
    }
  }
}

// ---------------- GEMM2 af/sa (1-phase, proven) ----------------
template<int BR>
__global__ __launch_bounds__(256) void gemm2_k(const short* __restrict__ A,
                                               const short* __restrict__ B,
                                               short* __restrict__ F) {
  constexpr int NX  = (BR == 2) ? 45 : 60;
  constexpr int NY  = (BR == 2) ? 5 : 4;
  constexpr int NWG = NX * NY * 4;
  constexpr int LDA = (BR == 2) ? 384 : 256;
  constexpr long SA = (BR == 2) ? 147456L : 65536L;
  constexpr long SB = (BR == 2) ? 4423680L : 3932160L;
  constexpr int KST = (BR == 2) ? 6 : 4;

  __shared__ short sm[20480];
  short* As = sm;
  short* Bs = sm + 4096;
  int tid = threadIdx.x, wave = tid >> 6, lane = tid & 63;
  int la = lane & 15, lb = lane >> 4;

  int wk;
  { constexpr int q = NWG / 8, r = NWG % 8;
    int xcd = blockIdx.x & 7, j = blockIdx.x >> 3;
    wk = (xcd < r) ? xcd * (q + 1) + j : r * (q + 1) + (xcd - r) * q + j; }
  int yt = wk % NY, rem = wk / NY;
  int xt = rem % NX, bat = rem / NX;

  const short* Ab = A + (long)bat * SA;
  const short* Bb = B + (long)bat * SB;
  f32x4 acc[4][4] = {};
  int rloc = tid >> 3, cbase = (tid & 7) * 8;

  for (int kt = 0; kt < KST; ++kt) {
    int k0 = kt * 64;
    #pragma unroll
    for (int p = 0; p < 2; ++p) {
      int r = p * 32 + rloc;
      int sc = SWZ(r, cbase);
      int e = p * 2048 + tid * 8;
      int rowg = (BR == 2) ? (r * 5 + yt) : (yt * 64 + r);
      gload16(Ab + (long)rowg * LDA + k0 + sc, (void*)(As + e));
    }
    #pragma unroll
    for (int p = 0; p < 8; ++p) {
      int rb = p * 32 + rloc;
      int sc = SWZ(rb, cbase);
      int e = p * 2048 + tid * 8;
      int rowg;
      if (BR == 3) { int c = rb & 63, g = rb >> 6; rowg = c * 240 + xt * 4 + g; }
      else rowg = xt * 256 + rb;
      gload16(Bb + (long)rowg * LDA + k0 + sc, (void*)(Bs + e));
    }
    __syncthreads();
    #pragma unroll
    for (int kk = 0; kk < 64; kk += 32) {
      bf16x8 av[4], bv[4];
      #pragma unroll
      for (int m = 0; m < 4; ++m)
        av[m] = *(const bf16x8*)&As[(m * 16 + la) * 64 + SWZ(la, kk + lb * 8)];
      #pragma unroll
      for (int nn = 0; nn < 4; ++nn)
        bv[nn] = *(const bf16x8*)&Bs[(wave * 64 + nn * 16 + la) * 64 + SWZ(la, kk + lb * 8)];
      #pragma unroll
      for (int m = 0; m < 4; ++m)
        #pragma unroll
        for (int nn = 0; nn < 4; ++nn)
          acc[m][nn] = __builtin_amdgcn_mfma_f32_16x16x32_bf16(av[m], bv[nn], acc[m][nn], 0, 0, 0);
    }
    __syncthreads();
  }

  short* staged = sm;
  #pragma unroll
  for (int m = 0; m < 4; ++m) {
    #pragma unroll
    for (int nn = 0; nn < 4; ++nn) {
      if (BR == 3) {
        #pragma unroll
        for (int j = 0; j < 4; ++j)
          staged[((m * 16 + lb * 4 + j) * 4 + wave) * 72 + nn * 16 + la] = f2b(acc[m][nn][j]);
      } else {
        short4 o;
        o.x = f2b(acc[m][nn][0]); o.y = f2b(acc[m][nn][1]);
        o.z = f2b(acc[m][nn][2]); o.w = f2b(acc[m][nn][3]);
        *(short4*)&staged[(wave * 64 + nn * 16 + la) * 72 + m * 16 + lb * 4] = o;
      }
    }
  }
  __syncthreads();

  #pragma unroll
  for (int rd = 0; rd < 8; ++rd) {
    int chunk = rd * 32 + (tid >> 3);
    int part = tid & 7;
    bf16x8 v = *(const bf16x8*)&staged[chunk * 72 + part * 8];
    long base; bool ok = true;
    if (BR == 2) {
      int gc = xt * 256 + chunk;
      int hh = gc / 240, r2 = gc - hh * 240, v5 = r2 / 48, wv = r2 - v5 * 48;
      base = (((long)(bat * 48 + hh) * 48 + wv) * 25 + yt * 5 + v5) * 192 + 64 + part * 8;
    } else {
      int r = chunk >> 2, g = chunk & 3;
      int gr = yt * 64 + r; ok = (gr < 240);
      int hh = gr / 5, u = gr - hh * 5;
      int r2 = xt * 4 + g, v5 = r2 / 48, wv = r2 - v5 * 48;
      base = (((long)(bat * 48 + hh) * 48 + wv) * 25 + u * 5 + v5) * 192 + 128 + part * 8;
    }
    if (ok) *(bf16x8*)&F[base] = v;
  }
}

// ---------------- weight prep ----------------
__global__ __launch_bounds__(256) void prep_w_k(const float* __restrict__ w1, const float* __restrict__ w2,
                                                short* __restrict__ w1t, short* __restrict__ w2t) {
  int idx = blockIdx.x * 256 + threadIdx.x;
  if (idx < 12288) {
    int i = idx / 64, j = idx - i * 64;
    w1t[j * 192 + i] = f2b(w1[idx]);
  } else if (idx < 16384) {
    int k = idx - 12288;
    int i = k / 64, j = k - i * 64;
    w2t[j * 64 + i] = f2b(w2[k]);
  }
}

// ---------------- fused (+x) LayerNorm + MFMA MLP + residual ----------------
__global__ __launch_bounds__(256) void ln_mlp_mfma_k(
    const short* __restrict__ F, const float* __restrict__ x,
    const float* __restrict__ gamma, const float* __restrict__ beta,
    const short* __restrict__ w1t, const short* __restrict__ w2t,
    float* __restrict__ out)
{
  int n = blockIdx.x, hh = blockIdx.y, b = blockIdx.z;
  __shared__ short A1[48 * 200];
  __shared__ short Y1[48 * 72];
  __shared__ float Y2[48 * 66];
  __shared__ float xs[64 * 49];
  int tid = threadIdx.x, wave = tid >> 6, lane = tid & 63;
  int la = lane & 15, lb = lane >> 4;
  long Fb0 = ((long)(b * 48 + hh) * 1200 + n) * 192;
  long xb = (long)b * 3686400 + (long)n * 2304 + hh * 48;

  {
    int ch = tid >> 2, qq = tid & 3;
    const float* xr = x + xb + (long)ch * 57600 + qq * 12;
    #pragma unroll
    for (int i = 0; i < 12; ++i) xs[ch * 49 + qq * 12 + i] = xr[i];
  }
  __syncthreads();

  float g0 = gamma[lane], g1 = gamma[lane + 64], g2 = gamma[lane + 128];
  float bt0 = beta[lane], bt1 = beta[lane + 64], bt2 = beta[lane + 128];
  for (int r = wave; r < 48; r += 4) {
    const short* Fr = F + Fb0 + (long)r * 4800;
    float xv = xs[lane * 49 + r];
    float v0 = b2f(Fr[lane]) + xv, v1 = b2f(Fr[lane + 64]) + xv, v2 = b2f(Fr[lane + 128]) + xv;
    float s = v0 + v1 + v2;
    #pragma unroll
    for (int o = 32; o >= 1; o >>= 1) s += __shfl_xor(s, o, 64);
    float mu = s * (1.f / 192.f);
    float d0 = v0 - mu, d1 = v1 - mu, d2 = v2 - mu;
    float q = d0 * d0 + d1 * d1 + d2 * d2;
    #pragma unroll
    for (int o = 32; o >= 1; o >>= 1) q += __shfl_xor(q, o, 64);
    float rs = rsqrtf(q * (1.f / 192.f) + 1e-5f);
    A1[r * 200 + lane]       = f2b(d0 * rs * g0 + bt0);
    A1[r * 200 + lane + 64]  = f2b(d1 * rs * g1 + bt1);
    A1[r * 200 + lane + 128] = f2b(d2 * rs * g2 + bt2);
  }
  __syncthreads();

  f32x4 acc1[3] = {};
  #pragma unroll
  for (int ks = 0; ks < 6; ++ks) {
    bf16x8 bv = *(const bf16x8*)&w1t[(wave * 16 + la) * 192 + ks * 32 + lb * 8];
    #pragma unroll
    for (int m = 0; m < 3; ++m) {
      bf16x8 av = *(const bf16x8*)&A1[(m * 16 + la) * 200 + ks * 32 + lb * 8];
      acc1[m] = __builtin_amdgcn_mfma_f32_16x16x32_bf16(av, bv, acc1[m], 0, 0, 0);
    }
  }
  #pragma unroll
  for (int m = 0; m < 3; ++m)
    #pragma unroll
    for (int j = 0; j < 4; ++j)
      Y1[(m * 16 + lb * 4 + j) * 72 + wave * 16 + la] = f2b(fmaxf(acc1[m][j], 0.f));
  __syncthreads();

  f32x4 acc2[3] = {};
  #pragma unroll
  for (int ks = 0; ks < 2; ++ks) {
    bf16x8 bv = *(const bf16x8*)&w2t[(wave * 16 + la) * 64 + ks * 32 + lb * 8];
    #pragma unroll
    for (int m = 0; m < 3; ++m) {
      bf16x8 av = *(const bf16x8*)&Y1[(m * 16 + la) * 72 + ks * 32 + lb * 8];
      acc2[m] = __builtin_amdgcn_mfma_f32_16x16x32_bf16(av, bv, acc2[m], 0, 0, 0);
    }
  }
  #pragma unroll
  for (int m = 0; m < 3; ++m)
    #pragma unroll
    for (int j = 0; j < 4; ++j)
      Y2[(m * 16 + lb * 4 + j) * 66 + wave * 16 + la] = acc2[m][j];
  __syncthreads();

  #pragma unroll
  for (int i = 0; i < 12; ++i) {
    int e = tid + 256 * i;
    int cc = e / 48, wv = e - cc * 48;
    out[xb + (long)cc * 57600 + wv] = Y2[wv * 66 + cc] + xs[cc * 49 + wv];
  }
}

// ---------------- host launcher ----------------
extern "C" void kernel_launch(void* const* d_in, const int* in_sizes, int n_in,
                              void* d_out, int out_size, void* d_ws, size_t ws_size,
                              hipStream_t stream) {
  (void)in_sizes; (void)n_in; (void)out_size;
  const float* x     = (const float*)d_in[0];
  const float* gamma = (const float*)d_in[1];
  const float* beta  = (const float*)d_in[2];
  const float* w1    = (const float*)d_in[3];
  const float* w2    = (const float*)d_in[4];
  float* out = (float*)d_out;

  const size_t NEED = 237191168UL;
  if (ws_size < NEED) return;
  char* ws = (char*)d_ws;
  short* F     = (short*)(ws);                           // 88,473,600
  short* att   = (short*)(ws + 88473600UL);              // 75,497,472
  short* Qbf   = (short*)(ws + 163971072UL);             // 35,389,440
  short* QbfT  = (short*)(ws + 199360512UL);             // 35,389,440
  float* Sf    = (float*)(ws + 234749952UL);             //  2,359,296
  float* invn  = (float*)(ws + 237109248UL);             //     49,152
  short* w1t   = (short*)(ws + 237158400UL);             //     24,576
  short* w2t   = (short*)(ws + 237182976UL);             //      8,192

  prep_w_k<<<64, 256, 0, stream>>>(w1, w2, w1t, w2t);

  // ================= SF: M=3072, K=1200 (Kp=1280) =================
  permute_sf_k<<<3072, 256, 0, stream>>>(x, Qbf);
  transpose_k<<<dim3(40, 96, 4), 256, 0, stream>>>(Qbf, QbfT, 3072, 1280);
  invnorm_k<<<dim3(3072, 4), 256, 0, stream>>>(Qbf, 3932160L, 1280, 3072, 3072, invn);
  gemm1_tri_k<<<dim3(300, 1, 4), 256, 0, stream>>>(Qbf, invn, att);
  softmax_bf16_k<<<dim3(3072, 4), 256, 0, stream>>>(att, 9437184L, 3072);
  gemm2sf_k<<<dim3(960), 256, 0, stream>>>(att, QbfT, F);

  // ================= AF: M=320 (Mp=384), Kp=11520 =================
  permtr_k<1><<<dim3(360, 12, 4), 256, 0, stream>>>(x, Qbf, QbfT);
  invnorm_k<<<dim3(384, 4), 256, 0, stream>>>(Qbf, 4423680L, 11520, 320, 384, invn);
  hipMemsetAsync(Sf, 0, (size_t)4 * 384 * 384 * 4, stream);
  gemm_s_k<<<dim3(3, 3, 32), 256, 0, stream>>>(Qbf, 4423680L, 11520, 180, 23, 8, Sf, 147456L, 384);
  softmax_k<<<dim3(320, 4), 256, 0, stream>>>(Sf, 147456L, invn, 320, 384, att, 147456L);
  gemm2_k<2><<<dim3(900), 256, 0, stream>>>(att, QbfT, F);

  // ================= SA: M=240 (Mp=256), Kp=15360 =================
  permtr_k<2><<<dim3(480, 8, 4), 256, 0, stream>>>(x, Qbf, QbfT);
  invnorm_k<<<dim3(256, 4), 256, 0, stream>>>(Qbf, 3932160L, 15360, 240, 256, invn);
  hipMemsetAsync(Sf, 0, (size_t)4 * 256 * 256 * 4, stream);
  gemm_s_k<<<dim3(2, 2, 64), 256, 0, stream>>>(Qbf, 3932160L, 15360, 240, 15, 16, Sf, 65536L, 256);
  softmax_k<<<dim3(240, 4), 256, 0, stream>>>(Sf, 65536L, invn, 240, 256, att, 65536L);
  gemm2_k<3><<<dim3(960), 256, 0, stream>>>(att, QbfT, F);

  // ================= LN + MLP + residual =================
  ln_mlp_mfma_k<<<dim3(25, 48, 4), 256, 0, stream>>>(F, x, gamma, beta, w1t, w2t, out);
}

// Round 6
// 517.385 us; speedup vs baseline: 3.2057x; 1.0993x over previous
//
#include <hip/hip_runtime.h>
#include <stdint.h>

typedef __attribute__((ext_vector_type(8))) short bf16x8;
typedef __attribute__((ext_vector_type(4))) float f32x4;

__device__ __forceinline__ float b2f(short s) {
  union { unsigned u; float f; } a; a.u = ((unsigned)(unsigned short)s) << 16; return a.f;
}
__device__ __forceinline__ short f2b(float f) {
  union { float f; unsigned u; } a; a.f = f;
  unsigned r = a.u + 0x7fffu + ((a.u >> 16) & 1u);
  return (short)(r >> 16);
}
__device__ __forceinline__ void gload16(const void* g, void* l) {
  __builtin_amdgcn_global_load_lds((__attribute__((address_space(1))) void*)g,
                                   (__attribute__((address_space(3))) void*)l, 16, 0, 0);
}

// LDS XOR swizzle (T2, rule-21 form): linear LDS dest, inverse-swizzled global src col,
// swizzled ds_read col. col in shorts within a 64-short (128B) row; involution.
#define SWZ(row, col) ((col) ^ (((row) & 7) << 3))

// ---------------- permute kernels ----------------

// SF: m=(c,h) M=3072, k=(w,u,v) K=1200 Kp=1280.
__global__ __launch_bounds__(256) void permute_sf_k(const float* __restrict__ x, short* __restrict__ Q) {
  __shared__ float buf[4][1200];
  int wave = threadIdx.x >> 6, lane = threadIdx.x & 63;
  int gr = blockIdx.x * 4 + wave;
  int b = gr / 3072, m = gr - b * 3072;
  int c = m / 48, hh = m - c * 48;
  const float* xb = x + (long)(b * 64 + c) * 57600 + hh * 48;
  for (int uv = 0; uv < 25; ++uv)
    if (lane < 48) buf[wave][uv * 48 + lane] = xb[uv * 2304 + lane];
  __syncthreads();
  short* Qr = Q + (long)gr * 1280;
  for (int k = lane; k < 1280; k += 64) {
    float v = 0.f;
    if (k < 1200) { int wv = k / 25, uv = k - wv * 25; v = buf[wave][uv * 48 + wv]; }
    Qr[k] = f2b(v);
  }
}

// fused permute + transpose for af/sa
template<int BR>
__global__ __launch_bounds__(256) void permtr_k(const float* __restrict__ x,
                                                short* __restrict__ Q, short* __restrict__ QT) {
  constexpr int M  = (BR == 1) ? 320 : 240;
  constexpr int Mp = (BR == 1) ? 384 : 256;
  constexpr int Kp = (BR == 1) ? 11520 : 15360;
  __shared__ short t[32][33];
  int b = blockIdx.z;
  int k0 = blockIdx.x * 32, m0 = blockIdx.y * 32;
  int tx = threadIdx.x & 31, ty = threadIdx.x >> 5;
  const float* xb = x + (long)b * 3686400;
  #pragma unroll
  for (int i = 0; i < 32; i += 8) {
    int m = m0 + ty + i, k = k0 + tx;
    float v = 0.f;
    if (m < M) {
      int q1 = k / 240, r2 = k - q1 * 240;
      int v5 = r2 / 48, wv = r2 - v5 * 48;
      int a1 = m / 5, u = m - a1 * 5;
      long xi;
      if (BR == 1) xi = ((long)a1 * 25 + u * 5 + v5) * 2304 + q1 * 48 + wv;
      else         xi = ((long)q1 * 25 + u * 5 + v5) * 2304 + a1 * 48 + wv;
      v = xb[xi];
    }
    t[ty + i][tx] = f2b(v);
  }
  __syncthreads();
  long Qb = (long)b * Mp * Kp;
  #pragma unroll
  for (int i = 0; i < 32; i += 8)
    Q[Qb + (long)(m0 + ty + i) * Kp + k0 + tx] = t[ty + i][tx];
  #pragma unroll
  for (int i = 0; i < 32; i += 8)
    QT[Qb + (long)(k0 + ty + i) * Mp + m0 + tx] = t[tx][ty + i];
}

// ---------------- bf16 2D transpose (sf only) ----------------
__global__ __launch_bounds__(256) void transpose_k(const short* __restrict__ in, short* __restrict__ out,
                                                   int R, int C) {
  __shared__ short t[32][33];
  long base = (long)blockIdx.z * R * C;
  int c0 = blockIdx.x * 32, r0 = blockIdx.y * 32;
  int tx = threadIdx.x & 31, ty = threadIdx.x >> 5;
  #pragma unroll
  for (int i = 0; i < 32; i += 8)
    t[ty + i][tx] = in[base + (long)(r0 + ty + i) * C + c0 + tx];
  __syncthreads();
  #pragma unroll
  for (int i = 0; i < 32; i += 8)
    out[base + (long)(c0 + ty + i) * R + r0 + tx] = t[tx][ty + i];
}

// ---------------- row inv-norms ----------------
__global__ __launch_bounds__(256) void invnorm_k(const short* __restrict__ Q, long sQ, int Kp,
                                                 int Mvalid, int Mp, float* __restrict__ inv) {
  __shared__ float red[256];
  int m = blockIdx.x, b = blockIdx.y, tid = threadIdx.x;
  float acc = 0.f;
  if (m < Mvalid) {
    const short* row = Q + (long)b * sQ + (long)m * Kp;
    for (int k = tid * 8; k < Kp; k += 2048) {
      bf16x8 v = *(const bf16x8*)&row[k];
      #pragma unroll
      for (int j = 0; j < 8; ++j) { float f = b2f(v[j]); acc += f * f; }
    }
  }
  red[tid] = acc; __syncthreads();
  #pragma unroll
  for (int s2 = 128; s2 > 0; s2 >>= 1) {
    if (tid < s2) red[tid] += red[tid + s2];
    __syncthreads();
  }
  if (tid == 0)
    inv[(long)b * Mp + m] = (m < Mvalid) ? 1.0f / fmaxf(sqrtf(red[0]), 1e-12f) : 1.0f;
}

// ---------------- sf GEMM1: triangular, 2-phase dbuf; writes P=exp(cos) + rowsums ---------
// grid (300, 1, 4); tile 128x128; Q (3072 x 1280), KST=20
__global__ __launch_bounds__(256) void gemm1_tri_k(const short* __restrict__ Q,
                                                   const float* __restrict__ invn,
                                                   short* __restrict__ att,
                                                   float* __restrict__ rowsum) {
  __shared__ short sm[32768];      // dbuf: [buf*16384] As 8192 | Bs 8192; epilogue reuses
  int tid = threadIdx.x, wave = tid >> 6, lane = tid & 63;
  int la = lane & 15, lb = lane >> 4;
  int bat = blockIdx.z;
  int bx = blockIdx.x, yt = 0, rem = bx;
  while (rem >= 24 - yt) { rem -= 24 - yt; ++yt; }
  int xt = yt + rem;
  const short* Qb = Q + (long)bat * 3932160L;
  const float* inv = invn + (long)bat * 3072;
  int row0 = yt * 128, col0 = xt * 128;
  f32x4 acc[4][4] = {};
  int wr = wave >> 1, wc = wave & 1;
  int rloc = tid >> 3, cbase = (tid & 7) * 8;

  #define TRI_STAGE(KT, BUF) { \
    int k0 = (KT) * 64; \
    short* Asb = sm + (BUF) * 16384; \
    short* Bsb = Asb + 8192; \
    _Pragma("unroll") \
    for (int p = 0; p < 4; ++p) { \
      int row = p * 32 + rloc; \
      int sc = SWZ(row, cbase); \
      gload16(Qb + (long)(row0 + row) * 1280 + k0 + sc, (void*)(Asb + p * 2048 + tid * 8)); \
      gload16(Qb + (long)(col0 + row) * 1280 + k0 + sc, (void*)(Bsb + p * 2048 + tid * 8)); \
    } }
  #define TRI_COMP(BUF) { \
    const short* Asb = sm + (BUF) * 16384; \
    const short* Bsb = Asb + 8192; \
    _Pragma("unroll") \
    for (int kk = 0; kk < 64; kk += 32) { \
      bf16x8 av[4], bv[4]; \
      _Pragma("unroll") \
      for (int m = 0; m < 4; ++m) \
        av[m] = *(const bf16x8*)&Asb[(wr * 64 + m * 16 + la) * 64 + SWZ(la, kk + lb * 8)]; \
      _Pragma("unroll") \
      for (int nn = 0; nn < 4; ++nn) \
        bv[nn] = *(const bf16x8*)&Bsb[(wc * 64 + nn * 16 + la) * 64 + SWZ(la, kk + lb * 8)]; \
      _Pragma("unroll") \
      for (int m = 0; m < 4; ++m) \
        _Pragma("unroll") \
        for (int nn = 0; nn < 4; ++nn) \
          acc[m][nn] = __builtin_amdgcn_mfma_f32_16x16x32_bf16(av[m], bv[nn], acc[m][nn], 0, 0, 0); \
    } }

  TRI_STAGE(0, 0)
  for (int kt = 0; kt < 19; ++kt) {
    TRI_STAGE(kt + 1, (kt + 1) & 1)
    asm volatile("s_waitcnt vmcnt(8)" ::: "memory");
    __builtin_amdgcn_s_barrier();
    TRI_COMP(kt & 1)
    asm volatile("" ::: "memory");
    __builtin_amdgcn_s_barrier();
  }
  asm volatile("s_waitcnt vmcnt(0)" ::: "memory");
  __builtin_amdgcn_s_barrier();
  TRI_COMP(1)
  asm volatile("" ::: "memory");
  __builtin_amdgcn_s_barrier();

  // P = exp(cos) staged bf16 (values in [1/e, e]); rowsums accumulated from staged tile
  short* staged = sm;
  #pragma unroll
  for (int m = 0; m < 4; ++m) {
    #pragma unroll
    for (int nn = 0; nn < 4; ++nn) {
      int cl = wc * 64 + nn * 16 + la;
      float ic = inv[col0 + cl];
      #pragma unroll
      for (int j = 0; j < 4; ++j) {
        int rl = wr * 64 + m * 16 + lb * 4 + j;
        staged[rl * 136 + cl] = f2b(__expf(acc[m][nn][j] * inv[row0 + rl] * ic));
      }
    }
  }
  __syncthreads();
  short* attb = att + (long)bat * 9437184L;
  float* rsb = rowsum + (long)bat * 3072;
  {
    int r = tid >> 1, half = tid & 1;
    short* dst = attb + (long)(row0 + r) * 3072 + col0 + half * 64;
    const short* src = &staged[r * 136 + half * 64];
    float s = 0.f;
    #pragma unroll
    for (int q = 0; q < 8; ++q) {
      bf16x8 v = *(const bf16x8*)&src[q * 8];
      *(bf16x8*)&dst[q * 8] = v;
      #pragma unroll
      for (int jj = 0; jj < 8; ++jj) s += b2f(v[jj]);
    }
    s += __shfl_xor(s, 1, 64);
    if (half == 0) atomicAdd(&rsb[row0 + r], s);
  }
  if (xt != yt) {
    int c = tid >> 1, half = tid & 1;
    short* dst = attb + (long)(col0 + c) * 3072 + row0 + half * 64;
    float s = 0.f;
    #pragma unroll
    for (int q = 0; q < 8; ++q) {
      bf16x8 o;
      #pragma unroll
      for (int jj = 0; jj < 8; ++jj) {
        o[jj] = staged[(half * 64 + q * 8 + jj) * 136 + c];
        s += b2f(o[jj]);
      }
      *(bf16x8*)&dst[q * 8] = o;
    }
    s += __shfl_xor(s, 1, 64);
    if (half == 0) atomicAdd(&rsb[col0 + c], s);
  }
}

// ---------------- af/sa GEMM1: raw f32 S, split-K atomics, 2-phase dbuf ----------------
__global__ __launch_bounds__(256) void gemm_s_k(
    const short* __restrict__ A, long sA, int lda,
    int ktotal, int ksper, int SK,
    float* __restrict__ Sf, long sS, int ldc)
{
  __shared__ short sm[32768];
  int tid = threadIdx.x;
  int wave = tid >> 6, lane = tid & 63;
  int la = lane & 15, lb = lane >> 4;
  int bz = blockIdx.z;
  int bat = bz / SK, kc = bz - bat * SK;
  int row0 = blockIdx.y * 128, col0 = blockIdx.x * 128;
  const short* Ab = A + (long)bat * sA;
  int kb = kc * ksper, ke = min(ktotal, kb + ksper);
  int L = ke - kb;
  f32x4 acc[4][4] = {};
  int wr = wave >> 1, wc = wave & 1;
  int rloc = tid >> 3, cbase = (tid & 7) * 8;

  #define GS_STAGE(KT, BUF) { \
    int k0 = (KT) * 64; \
    short* Asb = sm + (BUF) * 16384; \
    short* Bsb = Asb + 8192; \
    _Pragma("unroll") \
    for (int p = 0; p < 4; ++p) { \
      int row = p * 32 + rloc; \
      int sc = SWZ(row, cbase); \
      gload16(Ab + (long)(row0 + row) * lda + k0 + sc, (void*)(Asb + p * 2048 + tid * 8)); \
      gload16(Ab + (long)(col0 + row) * lda + k0 + sc, (void*)(Bsb + p * 2048 + tid * 8)); \
    } }
  #define GS_COMP(BUF) { \
    const short* Asb = sm + (BUF) * 16384; \
    const short* Bsb = Asb + 8192; \
    _Pragma("unroll") \
    for (int kk = 0; kk < 64; kk += 32) { \
      bf16x8 av[4], bv[4]; \
      _Pragma("unroll") \
      for (int m = 0; m < 4; ++m) \
        av[m] = *(const bf16x8*)&Asb[(wr * 64 + m * 16 + la) * 64 + SWZ(la, kk + lb * 8)]; \
      _Pragma("unroll") \
      for (int nn = 0; nn < 4; ++nn) \
        bv[nn] = *(const bf16x8*)&Bsb[(wc * 64 + nn * 16 + la) * 64 + SWZ(la, kk + lb * 8)]; \
      _Pragma("unroll") \
      for (int m = 0; m < 4; ++m) \
        _Pragma("unroll") \
        for (int nn = 0; nn < 4; ++nn) \
          acc[m][nn] = __builtin_amdgcn_mfma_f32_16x16x32_bf16(av[m], bv[nn], acc[m][nn], 0, 0, 0); \
    } }

  GS_STAGE(kb, 0)
  for (int t = 0; t < L - 1; ++t) {
    GS_STAGE(kb + t + 1, (t + 1) & 1)
    asm volatile("s_waitcnt vmcnt(8)" ::: "memory");
    __builtin_amdgcn_s_barrier();
    GS_COMP(t & 1)
    asm volatile("" ::: "memory");
    __builtin_amdgcn_s_barrier();
  }
  asm volatile("s_waitcnt vmcnt(0)" ::: "memory");
  __builtin_amdgcn_s_barrier();
  GS_COMP((L - 1) & 1)

  float* Sb = Sf + (long)bat * sS;
  #pragma unroll
  for (int m = 0; m < 4; ++m) {
    int gr0 = row0 + wr * 64 + m * 16 + lb * 4;
    #pragma unroll
    for (int nn = 0; nn < 4; ++nn) {
      int gc = col0 + wc * 64 + nn * 16 + la;
      #pragma unroll
      for (int j = 0; j < 4; ++j)
        atomicAdd(&Sb[(long)(gr0 + j) * ldc + gc], acc[m][nn][j]);
    }
  }
}

// ---------------- softmax over f32 raw dots (af/sa); no max pass (cos in [-1,1]) --------
__global__ __launch_bounds__(256) void softmax_k(const float* __restrict__ Sf, long sS,
                                                 const float* __restrict__ inv,
                                                 int Mvalid, int Mp,
                                                 short* __restrict__ att, long sAtt) {
  __shared__ float srow[3072];
  __shared__ float red[256];
  int row = blockIdx.x, b = blockIdx.y, tid = threadIdx.x;
  const float* Sr = Sf + (long)b * sS + (long)row * Mp;
  const float* invb = inv + (long)b * Mp;
  float inv_i = invb[row];
  float sum = 0.f;
  for (int j = tid; j < Mvalid; j += 256) {
    float e = __expf(Sr[j] * inv_i * invb[j]);
    srow[j] = e; sum += e;
  }
  red[tid] = sum; __syncthreads();
  #pragma unroll
  for (int s2 = 128; s2 > 0; s2 >>= 1) {
    if (tid < s2) red[tid] += red[tid + s2];
    __syncthreads();
  }
  float rden = 1.0f / red[0];
  short* ar = att + (long)b * sAtt + (long)row * Mp;
  for (int j = tid; j < Mp; j += 256)
    ar[j] = (j < Mvalid) ? f2b(srow[j] * rden) : (short)0;
}

// ---------------- sf GEMM2: 128x128 tile (yt-pair), 2-phase dbuf; /rowsum in epilogue ----
// A = P (3072x3072), B = QbfT (1280x3072), KST=48, grid(960)
__global__ __launch_bounds__(256) void gemm2sf_k(const short* __restrict__ A,
                                                 const short* __restrict__ B,
                                                 const float* __restrict__ rowsum,
                                                 short* __restrict__ F) {
  __shared__ short sm[32768];
  int tid = threadIdx.x, wave = tid >> 6, lane = tid & 63;
  int la = lane & 15, lb = lane >> 4;
  int wr = wave >> 1, wc = wave & 1;
  int wk;
  { int xcd = blockIdx.x & 7, j = blockIdx.x >> 3; wk = xcd * 120 + j; }  // 960 % 8 == 0
  int yt = wk % 24, rem = wk / 24;
  int xt = rem % 10, bat = rem / 10;
  const short* Ab = A + (long)bat * 9437184L;
  const short* Bb = B + (long)bat * 3932160L;
  int rloc = tid >> 3, cbase = (tid & 7) * 8;
  f32x4 acc[4][4] = {};

  // A rows gathered: rowg = (row&63)*48 + yt*2 + (row>>6)  (c fastest, hh = yt*2 + sub)
  #define G2_STAGE(KT, BUF) { \
    int k0 = (KT) * 64; \
    short* Asb = sm + (BUF) * 16384; \
    short* Bsb = Asb + 8192; \
    _Pragma("unroll") \
    for (int p = 0; p < 4; ++p) { \
      int row = p * 32 + rloc; \
      int sc = SWZ(row, cbase); \
      int rga = (row & 63) * 48 + yt * 2 + (row >> 6); \
      gload16(Ab + (long)rga * 3072 + k0 + sc, (void*)(Asb + p * 2048 + tid * 8)); \
      int rgb = xt * 128 + row; \
      gload16(Bb + (long)rgb * 3072 + k0 + sc, (void*)(Bsb + p * 2048 + tid * 8)); \
    } }
  #define G2_COMP(BUF) { \
    const short* Asb = sm + (BUF) * 16384; \
    const short* Bsb = Asb + 8192; \
    _Pragma("unroll") \
    for (int kk = 0; kk < 64; kk += 32) { \
      bf16x8 av[4], bv[4]; \
      _Pragma("unroll") \
      for (int m = 0; m < 4; ++m) \
        av[m] = *(const bf16x8*)&Asb[(wr * 64 + m * 16 + la) * 64 + SWZ(la, kk + lb * 8)]; \
      _Pragma("unroll") \
      for (int nn = 0; nn < 4; ++nn) \
        bv[nn] = *(const bf16x8*)&Bsb[(wc * 64 + nn * 16 + la) * 64 + SWZ(la, kk + lb * 8)]; \
      _Pragma("unroll") \
      for (int m = 0; m < 4; ++m) \
        _Pragma("unroll") \
        for (int nn = 0; nn < 4; ++nn) \
          acc[m][nn] = __builtin_amdgcn_mfma_f32_16x16x32_bf16(av[m], bv[nn], acc[m][nn], 0, 0, 0); \
    } }

  G2_STAGE(0, 0)
  for (int kt = 0; kt < 47; ++kt) {
    G2_STAGE(kt + 1, (kt + 1) & 1)
    asm volatile("s_waitcnt vmcnt(8)" ::: "memory");
    __builtin_amdgcn_s_barrier();
    G2_COMP(kt & 1)
    asm volatile("" ::: "memory");
    __builtin_amdgcn_s_barrier();
  }
  asm volatile("s_waitcnt vmcnt(0)" ::: "memory");
  __builtin_amdgcn_s_barrier();
  G2_COMP(1)
  asm volatile("" ::: "memory");
  __builtin_amdgcn_s_barrier();

  // per-C-row softmax denominators: attRow = (m*16+lb*4+j)*48 + yt*2 + wr
  const float* rsb = rowsum + (long)bat * 3072;
  float rs[4][4];
  #pragma unroll
  for (int m = 0; m < 4; ++m)
    #pragma unroll
    for (int j = 0; j < 4; ++j)
      rs[m][j] = 1.0f / rsb[(m * 16 + lb * 4 + j) * 48 + yt * 2 + wr];

  // stage C tile: chunk = cc*2 + sub (sub = local row>>6), 64 c's per chunk, pitch 72
  short* staged = sm;
  #pragma unroll
  for (int m = 0; m < 4; ++m) {
    #pragma unroll
    for (int nn = 0; nn < 4; ++nn) {
      int cc = wc * 64 + nn * 16 + la;
      short4 o;
      o.x = f2b(acc[m][nn][0] * rs[m][0]); o.y = f2b(acc[m][nn][1] * rs[m][1]);
      o.z = f2b(acc[m][nn][2] * rs[m][2]); o.w = f2b(acc[m][nn][3] * rs[m][3]);
      *(short4*)&staged[(cc * 2 + wr) * 72 + m * 16 + lb * 4] = o;
    }
  }
  __syncthreads();
  #pragma unroll
  for (int rd = 0; rd < 8; ++rd) {
    int chunk = rd * 32 + (tid >> 3);
    int part = tid & 7;
    bf16x8 v = *(const bf16x8*)&staged[chunk * 72 + part * 8];
    int cc = chunk >> 1, sub = chunk & 1;
    int gc = xt * 128 + cc;
    if (gc < 1200) {
      int hh = yt * 2 + sub;
      int wv = gc / 25, nidx = gc - wv * 25;
      long base = (((long)(bat * 48 + hh) * 48 + wv) * 25 + nidx) * 192 + part * 8;
      *(bf16x8*)&F[base] = v;
    }
  }
}

// ---------------- GEMM2 af/sa (1-phase, proven) ----------------
template<int BR>
__global__ __launch_bounds__(256) void gemm2_k(const short* __restrict__ A,
                                               const short* __restrict__ B,
                                               short* __restrict__ F) {
  constexpr int NX  = (BR == 2) ? 45 : 60;
  constexpr int NY  = (BR == 2) ? 5 : 4;
  constexpr int NWG = NX * NY * 4;
  constexpr int LDA = (BR == 2) ? 384 : 256;
  constexpr long SA = (BR == 2) ? 147456L : 65536L;
  constexpr long SB = (BR == 2) ? 4423680L : 3932160L;
  constexpr int KST = (BR == 2) ? 6 : 4;

  __shared__ short sm[20480];
  short* As = sm;
  short* Bs = sm + 4096;
  int tid = threadIdx.x, wave = tid >> 6, lane = tid & 63;
  int la = lane & 15, lb = lane >> 4;

  int wk;
  { constexpr int q = NWG / 8, r = NWG % 8;
    int xcd = blockIdx.x & 7, j = blockIdx.x >> 3;
    wk = (xcd < r) ? xcd * (q + 1) + j : r * (q + 1) + (xcd - r) * q + j; }
  int yt = wk % NY, rem = wk / NY;
  int xt = rem % NX, bat = rem / NX;

  const short* Ab = A + (long)bat * SA;
  const short* Bb = B + (long)bat * SB;
  f32x4 acc[4][4] = {};
  int rloc = tid >> 3, cbase = (tid & 7) * 8;

  for (int kt = 0; kt < KST; ++kt) {
    int k0 = kt * 64;
    #pragma unroll
    for (int p = 0; p < 2; ++p) {
      int r = p * 32 + rloc;
      int sc = SWZ(r, cbase);
      int e = p * 2048 + tid * 8;
      int rowg = (BR == 2) ? (r * 5 + yt) : (yt * 64 + r);
      gload16(Ab + (long)rowg * LDA + k0 + sc, (void*)(As + e));
    }
    #pragma unroll
    for (int p = 0; p < 8; ++p) {
      int rb = p * 32 + rloc;
      int sc = SWZ(rb, cbase);
      int e = p * 2048 + tid * 8;
      int rowg;
      if (BR == 3) { int c = rb & 63, g = rb >> 6; rowg = c * 240 + xt * 4 + g; }
      else rowg = xt * 256 + rb;
      gload16(Bb + (long)rowg * LDA + k0 + sc, (void*)(Bs + e));
    }
    __syncthreads();
    #pragma unroll
    for (int kk = 0; kk < 64; kk += 32) {
      bf16x8 av[4], bv[4];
      #pragma unroll
      for (int m = 0; m < 4; ++m)
        av[m] = *(const bf16x8*)&As[(m * 16 + la) * 64 + SWZ(la, kk + lb * 8)];
      #pragma unroll
      for (int nn = 0; nn < 4; ++nn)
        bv[nn] = *(const bf16x8*)&Bs[(wave * 64 + nn * 16 + la) * 64 + SWZ(la, kk + lb * 8)];
      #pragma unroll
      for (int m = 0; m < 4; ++m)
        #pragma unroll
        for (int nn = 0; nn < 4; ++nn)
          acc[m][nn] = __builtin_amdgcn_mfma_f32_16x16x32_bf16(av[m], bv[nn], acc[m][nn], 0, 0, 0);
    }
    __syncthreads();
  }

  short* staged = sm;
  #pragma unroll
  for (int m = 0; m < 4; ++m) {
    #pragma unroll
    for (int nn = 0; nn < 4; ++nn) {
      if (BR == 3) {
        #pragma unroll
        for (int j = 0; j < 4; ++j)
          staged[((m * 16 + lb * 4 + j) * 4 + wave) * 72 + nn * 16 + la] = f2b(acc[m][nn][j]);
      } else {
        short4 o;
        o.x = f2b(acc[m][nn][0]); o.y = f2b(acc[m][nn][1]);
        o.z = f2b(acc[m][nn][2]); o.w = f2b(acc[m][nn][3]);
        *(short4*)&staged[(wave * 64 + nn * 16 + la) * 72 + m * 16 + lb * 4] = o;
      }
    }
  }
  __syncthreads();

  #pragma unroll
  for (int rd = 0; rd < 8; ++rd) {
    int chunk = rd * 32 + (tid >> 3);
    int part = tid & 7;
    bf16x8 v = *(const bf16x8*)&staged[chunk * 72 + part * 8];
    long base; bool ok = true;
    if (BR == 2) {
      int gc = xt * 256 + chunk;
      int hh = gc / 240, r2 = gc - hh * 240, v5 = r2 / 48, wv = r2 - v5 * 48;
      base = (((long)(bat * 48 + hh) * 48 + wv) * 25 + yt * 5 + v5) * 192 + 64 + part * 8;
    } else {
      int r = chunk >> 2, g = chunk & 3;
      int gr = yt * 64 + r; ok = (gr < 240);
      int hh = gr / 5, u = gr - hh * 5;
      int r2 = xt * 4 + g, v5 = r2 / 48, wv = r2 - v5 * 48;
      base = (((long)(bat * 48 + hh) * 48 + wv) * 25 + u * 5 + v5) * 192 + 128 + part * 8;
    }
    if (ok) *(bf16x8*)&F[base] = v;
  }
}

// ---------------- weight prep ----------------
__global__ __launch_bounds__(256) void prep_w_k(const float* __restrict__ w1, const float* __restrict__ w2,
                                                short* __restrict__ w1t, short* __restrict__ w2t) {
  int idx = blockIdx.x * 256 + threadIdx.x;
  if (idx < 12288) {
    int i = idx / 64, j = idx - i * 64;
    w1t[j * 192 + i] = f2b(w1[idx]);
  } else if (idx < 16384) {
    int k = idx - 12288;
    int i = k / 64, j = k - i * 64;
    w2t[j * 64 + i] = f2b(w2[k]);
  }
}

// ---------------- fused (+x) LayerNorm + MFMA MLP + residual ----------------
// grid (25, 48, 4); F staged to LDS via coalesced bf16x8 loads; LN row-loop unrolled
__global__ __launch_bounds__(256) void ln_mlp_mfma_k(
    const short* __restrict__ F, const float* __restrict__ x,
    const float* __restrict__ gamma, const float* __restrict__ beta,
    const short* __restrict__ w1t, const short* __restrict__ w2t,
    float* __restrict__ out)
{
  int n = blockIdx.x, hh = blockIdx.y, b = blockIdx.z;
  __shared__ short A1[48 * 200];                 // 19200 B
  __shared__ float xs[64 * 49];                  // 12544 B
  __shared__ __align__(16) char pool[19584];     // Fs (18432) aliases Y1(6912)+Y2(12672)
  short* Fs = (short*)pool;
  short* Y1 = (short*)pool;
  float* Y2 = (float*)(pool + 6912);
  int tid = threadIdx.x, wave = tid >> 6, lane = tid & 63;
  int la = lane & 15, lb = lane >> 4;
  long Fb0 = ((long)(b * 48 + hh) * 1200 + n) * 192;
  long xb = (long)b * 3686400 + (long)n * 2304 + hh * 48;

  // stage F tile (48 x 192 bf16) coalesced: 1152 chunks of 16B
  #pragma unroll
  for (int it = 0; it < 5; ++it) {
    int ci = tid + 256 * it;
    if (ci < 1152) {
      int r = ci / 24, q = ci - r * 24;
      *(bf16x8*)&Fs[r * 192 + q * 8] = *(const bf16x8*)&F[Fb0 + (long)r * 4800 + q * 8];
    }
  }
  { // coalesced x tile: 64 ch x 48 w
    int ch = tid >> 2, qq = tid & 3;
    const float* xr = x + xb + (long)ch * 57600 + qq * 12;
    #pragma unroll
    for (int i = 0; i < 12; ++i) xs[ch * 49 + qq * 12 + i] = xr[i];
  }
  __syncthreads();

  float g0 = gamma[lane], g1 = gamma[lane + 64], g2 = gamma[lane + 128];
  float bt0 = beta[lane], bt1 = beta[lane + 64], bt2 = beta[lane + 128];
  #pragma unroll 4
  for (int rr = 0; rr < 12; ++rr) {
    int r = wave * 12 + rr;
    float xv = xs[lane * 49 + r];
    float v0 = b2f(Fs[r * 192 + lane]) + xv;
    float v1 = b2f(Fs[r * 192 + lane + 64]) + xv;
    float v2 = b2f(Fs[r * 192 + lane + 128]) + xv;
    float s = v0 + v1 + v2;
    #pragma unroll
    for (int o = 32; o >= 1; o >>= 1) s += __shfl_xor(s, o, 64);
    float mu = s * (1.f / 192.f);
    float d0 = v0 - mu, d1 = v1 - mu, d2 = v2 - mu;
    float q = d0 * d0 + d1 * d1 + d2 * d2;
    #pragma unroll
    for (int o = 32; o >= 1; o >>= 1) q += __shfl_xor(q, o, 64);
    float rs = rsqrtf(q * (1.f / 192.f) + 1e-5f);
    A1[r * 200 + lane]       = f2b(d0 * rs * g0 + bt0);
    A1[r * 200 + lane + 64]  = f2b(d1 * rs * g1 + bt1);
    A1[r * 200 + lane + 128] = f2b(d2 * rs * g2 + bt2);
  }
  __syncthreads();

  f32x4 acc1[3] = {};
  #pragma unroll
  for (int ks = 0; ks < 6; ++ks) {
    bf16x8 bv = *(const bf16x8*)&w1t[(wave * 16 + la) * 192 + ks * 32 + lb * 8];
    #pragma unroll
    for (int m = 0; m < 3; ++m) {
      bf16x8 av = *(const bf16x8*)&A1[(m * 16 + la) * 200 + ks * 32 + lb * 8];
      acc1[m] = __builtin_amdgcn_mfma_f32_16x16x32_bf16(av, bv, acc1[m], 0, 0, 0);
    }
  }
  #pragma unroll
  for (int m = 0; m < 3; ++m)
    #pragma unroll
    for (int j = 0; j < 4; ++j)
      Y1[(m * 16 + lb * 4 + j) * 72 + wave * 16 + la] = f2b(fmaxf(acc1[m][j], 0.f));
  __syncthreads();

  f32x4 acc2[3] = {};
  #pragma unroll
  for (int ks = 0; ks < 2; ++ks) {
    bf16x8 bv = *(const bf16x8*)&w2t[(wave * 16 + la) * 64 + ks * 32 + lb * 8];
    #pragma unroll
    for (int m = 0; m < 3; ++m) {
      bf16x8 av = *(const bf16x8*)&Y1[(m * 16 + la) * 72 + ks * 32 + lb * 8];
      acc2[m] = __builtin_amdgcn_mfma_f32_16x16x32_bf16(av, bv, acc2[m], 0, 0, 0);
    }
  }
  #pragma unroll
  for (int m = 0; m < 3; ++m)
    #pragma unroll
    for (int j = 0; j < 4; ++j)
      Y2[(m * 16 + lb * 4 + j) * 66 + wave * 16 + la] = acc2[m][j];
  __syncthreads();

  #pragma unroll
  for (int i = 0; i < 12; ++i) {
    int e = tid + 256 * i;
    int cc = e / 48, wv = e - cc * 48;
    out[xb + (long)cc * 57600 + wv] = Y2[wv * 66 + cc] + xs[cc * 49 + wv];
  }
}

// ---------------- host launcher ----------------
extern "C" void kernel_launch(void* const* d_in, const int* in_sizes, int n_in,
                              void* d_out, int out_size, void* d_ws, size_t ws_size,
                              hipStream_t stream) {
  (void)in_sizes; (void)n_in; (void)out_size;
  const float* x     = (const float*)d_in[0];
  const float* gamma = (const float*)d_in[1];
  const float* beta  = (const float*)d_in[2];
  const float* w1    = (const float*)d_in[3];
  const float* w2    = (const float*)d_in[4];
  float* out = (float*)d_out;

  const size_t NEED = 237191168UL;
  if (ws_size < NEED) return;
  char* ws = (char*)d_ws;
  short* F     = (short*)(ws);                           // 88,473,600
  short* att   = (short*)(ws + 88473600UL);              // 75,497,472
  short* Qbf   = (short*)(ws + 163971072UL);             // 35,389,440
  short* QbfT  = (short*)(ws + 199360512UL);             // 35,389,440
  float* Sf    = (float*)(ws + 234749952UL);             //  2,359,296 (sf: rowsum 49KB)
  float* invn  = (float*)(ws + 237109248UL);             //     49,152
  short* w1t   = (short*)(ws + 237158400UL);             //     24,576
  short* w2t   = (short*)(ws + 237182976UL);             //      8,192

  prep_w_k<<<64, 256, 0, stream>>>(w1, w2, w1t, w2t);

  // ================= SF: M=3072, K=1200 (Kp=1280) =================
  permute_sf_k<<<3072, 256, 0, stream>>>(x, Qbf);
  transpose_k<<<dim3(40, 96, 4), 256, 0, stream>>>(Qbf, QbfT, 3072, 1280);
  invnorm_k<<<dim3(3072, 4), 256, 0, stream>>>(Qbf, 3932160L, 1280, 3072, 3072, invn);
  hipMemsetAsync(Sf, 0, 49152, stream);                  // rowsum zero
  gemm1_tri_k<<<dim3(300, 1, 4), 256, 0, stream>>>(Qbf, invn, att, Sf);
  gemm2sf_k<<<dim3(960), 256, 0, stream>>>(att, QbfT, Sf, F);

  // ================= AF: M=320 (Mp=384), Kp=11520 =================
  permtr_k<1><<<dim3(360, 12, 4), 256, 0, stream>>>(x, Qbf, QbfT);
  invnorm_k<<<dim3(384, 4), 256, 0, stream>>>(Qbf, 4423680L, 11520, 320, 384, invn);
  hipMemsetAsync(Sf, 0, (size_t)4 * 384 * 384 * 4, stream);
  gemm_s_k<<<dim3(3, 3, 32), 256, 0, stream>>>(Qbf, 4423680L, 11520, 180, 23, 8, Sf, 147456L, 384);
  softmax_k<<<dim3(320, 4), 256, 0, stream>>>(Sf, 147456L, invn, 320, 384, att, 147456L);
  gemm2_k<2><<<dim3(900), 256, 0, stream>>>(att, QbfT, F);

  // ================= SA: M=240 (Mp=256), Kp=15360 =================
  permtr_k<2><<<dim3(480, 8, 4), 256, 0, stream>>>(x, Qbf, QbfT);
  invnorm_k<<<dim3(256, 4), 256, 0, stream>>>(Qbf, 3932160L, 15360, 240, 256, invn);
  hipMemsetAsync(Sf, 0, (size_t)4 * 256 * 256 * 4, stream);
  gemm_s_k<<<dim3(2, 2, 64), 256, 0, stream>>>(Qbf, 3932160L, 15360, 240, 15, 16, Sf, 65536L, 256);
  softmax_k<<<dim3(240, 4), 256, 0, stream>>>(Sf, 65536L, invn, 240, 256, att, 65536L);
  gemm2_k<3><<<dim3(960), 256, 0, stream>>>(att, QbfT, F);

  // ================= LN + MLP + residual =================
  ln_mlp_mfma_k<<<dim3(25, 48, 4), 256, 0, stream>>>(F, x, gamma, beta, w1t, w2t, out);
}

// Round 7
// 502.432 us; speedup vs baseline: 3.3011x; 1.0298x over previous
//
#include <hip/hip_runtime.h>
#include <stdint.h>

typedef __attribute__((ext_vector_type(8))) short bf16x8;
typedef __attribute__((ext_vector_type(4))) float f32x4;

__device__ __forceinline__ float b2f(short s) {
  union { unsigned u; float f; } a; a.u = ((unsigned)(unsigned short)s) << 16; return a.f;
}
__device__ __forceinline__ short f2b(float f) {
  union { float f; unsigned u; } a; a.f = f;
  unsigned r = a.u + 0x7fffu + ((a.u >> 16) & 1u);
  return (short)(r >> 16);
}
__device__ __forceinline__ void gload16(const void* g, void* l) {
  __builtin_amdgcn_global_load_lds((__attribute__((address_space(1))) void*)g,
                                   (__attribute__((address_space(3))) void*)l, 16, 0, 0);
}

// LDS XOR swizzle (T2, rule-21 form): linear LDS dest, inverse-swizzled global src col,
// swizzled ds_read col. col in shorts within a 64-short (128B) row; involution.
#define SWZ(row, col) ((col) ^ (((row) & 7) << 3))

// ---------------- permute kernels ----------------

// SF: m=(c,h) M=3072, k=(w,u,v) K=1200 Kp=1280.
__global__ __launch_bounds__(256) void permute_sf_k(const float* __restrict__ x, short* __restrict__ Q) {
  __shared__ float buf[4][1200];
  int wave = threadIdx.x >> 6, lane = threadIdx.x & 63;
  int gr = blockIdx.x * 4 + wave;
  int b = gr / 3072, m = gr - b * 3072;
  int c = m / 48, hh = m - c * 48;
  const float* xb = x + (long)(b * 64 + c) * 57600 + hh * 48;
  for (int uv = 0; uv < 25; ++uv)
    if (lane < 48) buf[wave][uv * 48 + lane] = xb[uv * 2304 + lane];
  __syncthreads();
  short* Qr = Q + (long)gr * 1280;
  for (int k = lane; k < 1280; k += 64) {
    float v = 0.f;
    if (k < 1200) { int wv = k / 25, uv = k - wv * 25; v = buf[wave][uv * 48 + wv]; }
    Qr[k] = f2b(v);
  }
}

// fused permute + transpose for af/sa
template<int BR>
__global__ __launch_bounds__(256) void permtr_k(const float* __restrict__ x,
                                                short* __restrict__ Q, short* __restrict__ QT) {
  constexpr int M  = (BR == 1) ? 320 : 240;
  constexpr int Mp = (BR == 1) ? 384 : 256;
  constexpr int Kp = (BR == 1) ? 11520 : 15360;
  __shared__ short t[32][33];
  int b = blockIdx.z;
  int k0 = blockIdx.x * 32, m0 = blockIdx.y * 32;
  int tx = threadIdx.x & 31, ty = threadIdx.x >> 5;
  const float* xb = x + (long)b * 3686400;
  #pragma unroll
  for (int i = 0; i < 32; i += 8) {
    int m = m0 + ty + i, k = k0 + tx;
    float v = 0.f;
    if (m < M) {
      int q1 = k / 240, r2 = k - q1 * 240;
      int v5 = r2 / 48, wv = r2 - v5 * 48;
      int a1 = m / 5, u = m - a1 * 5;
      long xi;
      if (BR == 1) xi = ((long)a1 * 25 + u * 5 + v5) * 2304 + q1 * 48 + wv;
      else         xi = ((long)q1 * 25 + u * 5 + v5) * 2304 + a1 * 48 + wv;
      v = xb[xi];
    }
    t[ty + i][tx] = f2b(v);
  }
  __syncthreads();
  long Qb = (long)b * Mp * Kp;
  #pragma unroll
  for (int i = 0; i < 32; i += 8)
    Q[Qb + (long)(m0 + ty + i) * Kp + k0 + tx] = t[ty + i][tx];
  #pragma unroll
  for (int i = 0; i < 32; i += 8)
    QT[Qb + (long)(k0 + ty + i) * Mp + m0 + tx] = t[tx][ty + i];
}

// ---------------- bf16 2D transpose (sf only) ----------------
__global__ __launch_bounds__(256) void transpose_k(const short* __restrict__ in, short* __restrict__ out,
                                                   int R, int C) {
  __shared__ short t[32][33];
  long base = (long)blockIdx.z * R * C;
  int c0 = blockIdx.x * 32, r0 = blockIdx.y * 32;
  int tx = threadIdx.x & 31, ty = threadIdx.x >> 5;
  #pragma unroll
  for (int i = 0; i < 32; i += 8)
    t[ty + i][tx] = in[base + (long)(r0 + ty + i) * C + c0 + tx];
  __syncthreads();
  #pragma unroll
  for (int i = 0; i < 32; i += 8)
    out[base + (long)(c0 + ty + i) * R + r0 + tx] = t[tx][ty + i];
}

// ---------------- row inv-norms ----------------
__global__ __launch_bounds__(256) void invnorm_k(const short* __restrict__ Q, long sQ, int Kp,
                                                 int Mvalid, int Mp, float* __restrict__ inv) {
  __shared__ float red[256];
  int m = blockIdx.x, b = blockIdx.y, tid = threadIdx.x;
  float acc = 0.f;
  if (m < Mvalid) {
    const short* row = Q + (long)b * sQ + (long)m * Kp;
    for (int k = tid * 8; k < Kp; k += 2048) {
      bf16x8 v = *(const bf16x8*)&row[k];
      #pragma unroll
      for (int j = 0; j < 8; ++j) { float f = b2f(v[j]); acc += f * f; }
    }
  }
  red[tid] = acc; __syncthreads();
  #pragma unroll
  for (int s2 = 128; s2 > 0; s2 >>= 1) {
    if (tid < s2) red[tid] += red[tid + s2];
    __syncthreads();
  }
  if (tid == 0)
    inv[(long)b * Mp + m] = (m < Mvalid) ? 1.0f / fmaxf(sqrtf(red[0]), 1e-12f) : 1.0f;
}

// ---------------- sf GEMM1: triangular, 2-phase dbuf; writes P=exp(cos) + rowsums ---------
// grid (300, 1, 4); tile 128x128; Q (3072 x 1280), KST=20
__global__ __launch_bounds__(256, 2) void gemm1_tri_k(const short* __restrict__ Q,
                                                      const float* __restrict__ invn,
                                                      short* __restrict__ att,
                                                      float* __restrict__ rowsum) {
  __shared__ short sm[32768];      // dbuf: [buf*16384] As 8192 | Bs 8192; epilogue reuses
  int tid = threadIdx.x, wave = tid >> 6, lane = tid & 63;
  int la = lane & 15, lb = lane >> 4;
  int bat = blockIdx.z;
  int bx = blockIdx.x, yt = 0, rem = bx;
  while (rem >= 24 - yt) { rem -= 24 - yt; ++yt; }
  int xt = yt + rem;
  const short* Qb = Q + (long)bat * 3932160L;
  const float* inv = invn + (long)bat * 3072;
  int row0 = yt * 128, col0 = xt * 128;
  f32x4 acc[4][4] = {};
  int wr = wave >> 1, wc = wave & 1;
  int rloc = tid >> 3, cbase = (tid & 7) * 8;
  int ldsoff = tid * 8;

  // hoisted per-thread staging pointers (induction: +kt*64 shorts per K-step)
  const short *pA[4], *pB[4];
  #pragma unroll
  for (int p = 0; p < 4; ++p) {
    int row = p * 32 + rloc;
    int sc = SWZ(row, cbase);
    pA[p] = Qb + (long)(row0 + row) * 1280 + sc;
    pB[p] = Qb + (long)(col0 + row) * 1280 + sc;
  }

  #define TRI_STAGE(KT, BUF) { \
    short* Asb = sm + (BUF) * 16384; \
    short* Bsb = Asb + 8192; \
    _Pragma("unroll") \
    for (int p = 0; p < 4; ++p) { \
      gload16(pA[p] + (KT) * 64, (void*)(Asb + p * 2048 + ldsoff)); \
      gload16(pB[p] + (KT) * 64, (void*)(Bsb + p * 2048 + ldsoff)); \
    } }
  #define TRI_COMP(BUF) { \
    const short* Asb = sm + (BUF) * 16384; \
    const short* Bsb = Asb + 8192; \
    _Pragma("unroll") \
    for (int kk = 0; kk < 64; kk += 32) { \
      bf16x8 av[4], bv[4]; \
      _Pragma("unroll") \
      for (int m = 0; m < 4; ++m) \
        av[m] = *(const bf16x8*)&Asb[(wr * 64 + m * 16 + la) * 64 + SWZ(la, kk + lb * 8)]; \
      _Pragma("unroll") \
      for (int nn = 0; nn < 4; ++nn) \
        bv[nn] = *(const bf16x8*)&Bsb[(wc * 64 + nn * 16 + la) * 64 + SWZ(la, kk + lb * 8)]; \
      _Pragma("unroll") \
      for (int m = 0; m < 4; ++m) \
        _Pragma("unroll") \
        for (int nn = 0; nn < 4; ++nn) \
          acc[m][nn] = __builtin_amdgcn_mfma_f32_16x16x32_bf16(av[m], bv[nn], acc[m][nn], 0, 0, 0); \
    } }

  TRI_STAGE(0, 0)
  for (int kt = 0; kt < 19; ++kt) {
    TRI_STAGE(kt + 1, (kt + 1) & 1)
    asm volatile("s_waitcnt vmcnt(8)" ::: "memory");
    __builtin_amdgcn_s_barrier();
    TRI_COMP(kt & 1)
    asm volatile("" ::: "memory");
    __builtin_amdgcn_s_barrier();
  }
  asm volatile("s_waitcnt vmcnt(0)" ::: "memory");
  __builtin_amdgcn_s_barrier();
  TRI_COMP(1)
  asm volatile("" ::: "memory");
  __builtin_amdgcn_s_barrier();

  // P = exp(cos) staged bf16 (values in [1/e, e]); rowsums accumulated from staged tile
  short* staged = sm;
  #pragma unroll
  for (int m = 0; m < 4; ++m) {
    #pragma unroll
    for (int nn = 0; nn < 4; ++nn) {
      int cl = wc * 64 + nn * 16 + la;
      float ic = inv[col0 + cl];
      #pragma unroll
      for (int j = 0; j < 4; ++j) {
        int rl = wr * 64 + m * 16 + lb * 4 + j;
        staged[rl * 136 + cl] = f2b(__expf(acc[m][nn][j] * inv[row0 + rl] * ic));
      }
    }
  }
  __syncthreads();
  short* attb = att + (long)bat * 9437184L;
  float* rsb = rowsum + (long)bat * 3072;
  {
    int r = tid >> 1, half = tid & 1;
    short* dst = attb + (long)(row0 + r) * 3072 + col0 + half * 64;
    const short* src = &staged[r * 136 + half * 64];
    float s = 0.f;
    #pragma unroll
    for (int q = 0; q < 8; ++q) {
      bf16x8 v = *(const bf16x8*)&src[q * 8];
      *(bf16x8*)&dst[q * 8] = v;
      #pragma unroll
      for (int jj = 0; jj < 8; ++jj) s += b2f(v[jj]);
    }
    s += __shfl_xor(s, 1, 64);
    if (half == 0) atomicAdd(&rsb[row0 + r], s);
  }
  if (xt != yt) {
    int c = tid >> 1, half = tid & 1;
    short* dst = attb + (long)(col0 + c) * 3072 + row0 + half * 64;
    float s = 0.f;
    #pragma unroll
    for (int q = 0; q < 8; ++q) {
      bf16x8 o;
      #pragma unroll
      for (int jj = 0; jj < 8; ++jj) {
        o[jj] = staged[(half * 64 + q * 8 + jj) * 136 + c];
        s += b2f(o[jj]);
      }
      *(bf16x8*)&dst[q * 8] = o;
    }
    s += __shfl_xor(s, 1, 64);
    if (half == 0) atomicAdd(&rsb[col0 + c], s);
  }
}

// ---------------- af/sa GEMM1: raw f32 S, split-K atomics, 2-phase dbuf ----------------
__global__ __launch_bounds__(256, 2) void gemm_s_k(
    const short* __restrict__ A, long sA, int lda,
    int ktotal, int ksper, int SK,
    float* __restrict__ Sf, long sS, int ldc)
{
  __shared__ short sm[32768];
  int tid = threadIdx.x;
  int wave = tid >> 6, lane = tid & 63;
  int la = lane & 15, lb = lane >> 4;
  int bz = blockIdx.z;
  int bat = bz / SK, kc = bz - bat * SK;
  int row0 = blockIdx.y * 128, col0 = blockIdx.x * 128;
  const short* Ab = A + (long)bat * sA;
  int kb = kc * ksper, ke = min(ktotal, kb + ksper);
  int L = ke - kb;
  f32x4 acc[4][4] = {};
  int wr = wave >> 1, wc = wave & 1;
  int rloc = tid >> 3, cbase = (tid & 7) * 8;
  int ldsoff = tid * 8;

  const short *pA[4], *pB[4];
  #pragma unroll
  for (int p = 0; p < 4; ++p) {
    int row = p * 32 + rloc;
    int sc = SWZ(row, cbase);
    pA[p] = Ab + (long)(row0 + row) * lda + sc;
    pB[p] = Ab + (long)(col0 + row) * lda + sc;
  }

  #define GS_STAGE(KT, BUF) { \
    short* Asb = sm + (BUF) * 16384; \
    short* Bsb = Asb + 8192; \
    _Pragma("unroll") \
    for (int p = 0; p < 4; ++p) { \
      gload16(pA[p] + (KT) * 64, (void*)(Asb + p * 2048 + ldsoff)); \
      gload16(pB[p] + (KT) * 64, (void*)(Bsb + p * 2048 + ldsoff)); \
    } }
  #define GS_COMP(BUF) { \
    const short* Asb = sm + (BUF) * 16384; \
    const short* Bsb = Asb + 8192; \
    _Pragma("unroll") \
    for (int kk = 0; kk < 64; kk += 32) { \
      bf16x8 av[4], bv[4]; \
      _Pragma("unroll") \
      for (int m = 0; m < 4; ++m) \
        av[m] = *(const bf16x8*)&Asb[(wr * 64 + m * 16 + la) * 64 + SWZ(la, kk + lb * 8)]; \
      _Pragma("unroll") \
      for (int nn = 0; nn < 4; ++nn) \
        bv[nn] = *(const bf16x8*)&Bsb[(wc * 64 + nn * 16 + la) * 64 + SWZ(la, kk + lb * 8)]; \
      _Pragma("unroll") \
      for (int m = 0; m < 4; ++m) \
        _Pragma("unroll") \
        for (int nn = 0; nn < 4; ++nn) \
          acc[m][nn] = __builtin_amdgcn_mfma_f32_16x16x32_bf16(av[m], bv[nn], acc[m][nn], 0, 0, 0); \
    } }

  GS_STAGE(kb, 0)
  for (int t = 0; t < L - 1; ++t) {
    GS_STAGE(kb + t + 1, (t + 1) & 1)
    asm volatile("s_waitcnt vmcnt(8)" ::: "memory");
    __builtin_amdgcn_s_barrier();
    GS_COMP(t & 1)
    asm volatile("" ::: "memory");
    __builtin_amdgcn_s_barrier();
  }
  asm volatile("s_waitcnt vmcnt(0)" ::: "memory");
  __builtin_amdgcn_s_barrier();
  GS_COMP((L - 1) & 1)

  float* Sb = Sf + (long)bat * sS;
  #pragma unroll
  for (int m = 0; m < 4; ++m) {
    int gr0 = row0 + wr * 64 + m * 16 + lb * 4;
    #pragma unroll
    for (int nn = 0; nn < 4; ++nn) {
      int gc = col0 + wc * 64 + nn * 16 + la;
      #pragma unroll
      for (int j = 0; j < 4; ++j)
        atomicAdd(&Sb[(long)(gr0 + j) * ldc + gc], acc[m][nn][j]);
    }
  }
}

// ---------------- softmax over f32 raw dots (af/sa); no max pass (cos in [-1,1]) --------
__global__ __launch_bounds__(256) void softmax_k(const float* __restrict__ Sf, long sS,
                                                 const float* __restrict__ inv,
                                                 int Mvalid, int Mp,
                                                 short* __restrict__ att, long sAtt) {
  __shared__ float srow[3072];
  __shared__ float red[256];
  int row = blockIdx.x, b = blockIdx.y, tid = threadIdx.x;
  const float* Sr = Sf + (long)b * sS + (long)row * Mp;
  const float* invb = inv + (long)b * Mp;
  float inv_i = invb[row];
  float sum = 0.f;
  for (int j = tid; j < Mvalid; j += 256) {
    float e = __expf(Sr[j] * inv_i * invb[j]);
    srow[j] = e; sum += e;
  }
  red[tid] = sum; __syncthreads();
  #pragma unroll
  for (int s2 = 128; s2 > 0; s2 >>= 1) {
    if (tid < s2) red[tid] += red[tid + s2];
    __syncthreads();
  }
  float rden = 1.0f / red[0];
  short* ar = att + (long)b * sAtt + (long)row * Mp;
  for (int j = tid; j < Mp; j += 256)
    ar[j] = (j < Mvalid) ? f2b(srow[j] * rden) : (short)0;
}

// ---------------- sf GEMM2: 128x128 tile (yt-pair), 2-phase dbuf; /rowsum in epilogue ----
// A = P (3072x3072), B = QbfT (1280x3072), KST=48, grid(960)
__global__ __launch_bounds__(256, 2) void gemm2sf_k(const short* __restrict__ A,
                                                    const short* __restrict__ B,
                                                    const float* __restrict__ rowsum,
                                                    short* __restrict__ F) {
  __shared__ short sm[32768];
  int tid = threadIdx.x, wave = tid >> 6, lane = tid & 63;
  int la = lane & 15, lb = lane >> 4;
  int wr = wave >> 1, wc = wave & 1;
  int wk;
  { int xcd = blockIdx.x & 7, j = blockIdx.x >> 3; wk = xcd * 120 + j; }  // 960 % 8 == 0
  int yt = wk % 24, rem = wk / 24;
  int xt = rem % 10, bat = rem / 10;
  const short* Ab = A + (long)bat * 9437184L;
  const short* Bb = B + (long)bat * 3932160L;
  int rloc = tid >> 3, cbase = (tid & 7) * 8;
  int ldsoff = tid * 8;
  f32x4 acc[4][4] = {};

  // hoisted per-thread staging pointers; A rows gathered (c fastest, hh = yt*2 + sub)
  const short *pA[4], *pB[4];
  #pragma unroll
  for (int p = 0; p < 4; ++p) {
    int row = p * 32 + rloc;
    int sc = SWZ(row, cbase);
    int rga = (row & 63) * 48 + yt * 2 + (row >> 6);
    pA[p] = Ab + (long)rga * 3072 + sc;
    int rgb = xt * 128 + row;
    pB[p] = Bb + (long)rgb * 3072 + sc;
  }

  #define G2_STAGE(KT, BUF) { \
    short* Asb = sm + (BUF) * 16384; \
    short* Bsb = Asb + 8192; \
    _Pragma("unroll") \
    for (int p = 0; p < 4; ++p) { \
      gload16(pA[p] + (KT) * 64, (void*)(Asb + p * 2048 + ldsoff)); \
      gload16(pB[p] + (KT) * 64, (void*)(Bsb + p * 2048 + ldsoff)); \
    } }
  #define G2_COMP(BUF) { \
    const short* Asb = sm + (BUF) * 16384; \
    const short* Bsb = Asb + 8192; \
    _Pragma("unroll") \
    for (int kk = 0; kk < 64; kk += 32) { \
      bf16x8 av[4], bv[4]; \
      _Pragma("unroll") \
      for (int m = 0; m < 4; ++m) \
        av[m] = *(const bf16x8*)&Asb[(wr * 64 + m * 16 + la) * 64 + SWZ(la, kk + lb * 8)]; \
      _Pragma("unroll") \
      for (int nn = 0; nn < 4; ++nn) \
        bv[nn] = *(const bf16x8*)&Bsb[(wc * 64 + nn * 16 + la) * 64 + SWZ(la, kk + lb * 8)]; \
      _Pragma("unroll") \
      for (int m = 0; m < 4; ++m) \
        _Pragma("unroll") \
        for (int nn = 0; nn < 4; ++nn) \
          acc[m][nn] = __builtin_amdgcn_mfma_f32_16x16x32_bf16(av[m], bv[nn], acc[m][nn], 0, 0, 0); \
    } }

  G2_STAGE(0, 0)
  for (int kt = 0; kt < 47; ++kt) {
    G2_STAGE(kt + 1, (kt + 1) & 1)
    asm volatile("s_waitcnt vmcnt(8)" ::: "memory");
    __builtin_amdgcn_s_barrier();
    G2_COMP(kt & 1)
    asm volatile("" ::: "memory");
    __builtin_amdgcn_s_barrier();
  }
  asm volatile("s_waitcnt vmcnt(0)" ::: "memory");
  __builtin_amdgcn_s_barrier();
  G2_COMP(1)
  asm volatile("" ::: "memory");
  __builtin_amdgcn_s_barrier();

  // per-C-row softmax denominators: attRow = (m*16+lb*4+j)*48 + yt*2 + wr
  const float* rsb = rowsum + (long)bat * 3072;
  float rs[4][4];
  #pragma unroll
  for (int m = 0; m < 4; ++m)
    #pragma unroll
    for (int j = 0; j < 4; ++j)
      rs[m][j] = 1.0f / rsb[(m * 16 + lb * 4 + j) * 48 + yt * 2 + wr];

  // stage C tile: chunk = cc*2 + sub (sub = local row>>6), 64 c's per chunk, pitch 72
  short* staged = sm;
  #pragma unroll
  for (int m = 0; m < 4; ++m) {
    #pragma unroll
    for (int nn = 0; nn < 4; ++nn) {
      int cc = wc * 64 + nn * 16 + la;
      short4 o;
      o.x = f2b(acc[m][nn][0] * rs[m][0]); o.y = f2b(acc[m][nn][1] * rs[m][1]);
      o.z = f2b(acc[m][nn][2] * rs[m][2]); o.w = f2b(acc[m][nn][3] * rs[m][3]);
      *(short4*)&staged[(cc * 2 + wr) * 72 + m * 16 + lb * 4] = o;
    }
  }
  __syncthreads();
  #pragma unroll
  for (int rd = 0; rd < 8; ++rd) {
    int chunk = rd * 32 + (tid >> 3);
    int part = tid & 7;
    bf16x8 v = *(const bf16x8*)&staged[chunk * 72 + part * 8];
    int cc = chunk >> 1, sub = chunk & 1;
    int gc = xt * 128 + cc;
    if (gc < 1200) {
      int hh = yt * 2 + sub;
      int wv = gc / 25, nidx = gc - wv * 25;
      long base = (((long)(bat * 48 + hh) * 48 + wv) * 25 + nidx) * 192 + part * 8;
      *(bf16x8*)&F[base] = v;
    }
  }
}

// ---------------- GEMM2 af/sa (1-phase, proven) ----------------
template<int BR>
__global__ __launch_bounds__(256) void gemm2_k(const short* __restrict__ A,
                                               const short* __restrict__ B,
                                               short* __restrict__ F) {
  constexpr int NX  = (BR == 2) ? 45 : 60;
  constexpr int NY  = (BR == 2) ? 5 : 4;
  constexpr int NWG = NX * NY * 4;
  constexpr int LDA = (BR == 2) ? 384 : 256;
  constexpr long SA = (BR == 2) ? 147456L : 65536L;
  constexpr long SB = (BR == 2) ? 4423680L : 3932160L;
  constexpr int KST = (BR == 2) ? 6 : 4;

  __shared__ short sm[20480];
  short* As = sm;
  short* Bs = sm + 4096;
  int tid = threadIdx.x, wave = tid >> 6, lane = tid & 63;
  int la = lane & 15, lb = lane >> 4;

  int wk;
  { constexpr int q = NWG / 8, r = NWG % 8;
    int xcd = blockIdx.x & 7, j = blockIdx.x >> 3;
    wk = (xcd < r) ? xcd * (q + 1) + j : r * (q + 1) + (xcd - r) * q + j; }
  int yt = wk % NY, rem = wk / NY;
  int xt = rem % NX, bat = rem / NX;

  const short* Ab = A + (long)bat * SA;
  const short* Bb = B + (long)bat * SB;
  f32x4 acc[4][4] = {};
  int rloc = tid >> 3, cbase = (tid & 7) * 8;

  for (int kt = 0; kt < KST; ++kt) {
    int k0 = kt * 64;
    #pragma unroll
    for (int p = 0; p < 2; ++p) {
      int r = p * 32 + rloc;
      int sc = SWZ(r, cbase);
      int e = p * 2048 + tid * 8;
      int rowg = (BR == 2) ? (r * 5 + yt) : (yt * 64 + r);
      gload16(Ab + (long)rowg * LDA + k0 + sc, (void*)(As + e));
    }
    #pragma unroll
    for (int p = 0; p < 8; ++p) {
      int rb = p * 32 + rloc;
      int sc = SWZ(rb, cbase);
      int e = p * 2048 + tid * 8;
      int rowg;
      if (BR == 3) { int c = rb & 63, g = rb >> 6; rowg = c * 240 + xt * 4 + g; }
      else rowg = xt * 256 + rb;
      gload16(Bb + (long)rowg * LDA + k0 + sc, (void*)(Bs + e));
    }
    __syncthreads();
    #pragma unroll
    for (int kk = 0; kk < 64; kk += 32) {
      bf16x8 av[4], bv[4];
      #pragma unroll
      for (int m = 0; m < 4; ++m)
        av[m] = *(const bf16x8*)&As[(m * 16 + la) * 64 + SWZ(la, kk + lb * 8)];
      #pragma unroll
      for (int nn = 0; nn < 4; ++nn)
        bv[nn] = *(const bf16x8*)&Bs[(wave * 64 + nn * 16 + la) * 64 + SWZ(la, kk + lb * 8)];
      #pragma unroll
      for (int m = 0; m < 4; ++m)
        #pragma unroll
        for (int nn = 0; nn < 4; ++nn)
          acc[m][nn] = __builtin_amdgcn_mfma_f32_16x16x32_bf16(av[m], bv[nn], acc[m][nn], 0, 0, 0);
    }
    __syncthreads();
  }

  short* staged = sm;
  #pragma unroll
  for (int m = 0; m < 4; ++m) {
    #pragma unroll
    for (int nn = 0; nn < 4; ++nn) {
      if (BR == 3) {
        #pragma unroll
        for (int j = 0; j < 4; ++j)
          staged[((m * 16 + lb * 4 + j) * 4 + wave) * 72 + nn * 16 + la] = f2b(acc[m][nn][j]);
      } else {
        short4 o;
        o.x = f2b(acc[m][nn][0]); o.y = f2b(acc[m][nn][1]);
        o.z = f2b(acc[m][nn][2]); o.w = f2b(acc[m][nn][3]);
        *(short4*)&staged[(wave * 64 + nn * 16 + la) * 72 + m * 16 + lb * 4] = o;
      }
    }
  }
  __syncthreads();

  #pragma unroll
  for (int rd = 0; rd < 8; ++rd) {
    int chunk = rd * 32 + (tid >> 3);
    int part = tid & 7;
    bf16x8 v = *(const bf16x8*)&staged[chunk * 72 + part * 8];
    long base; bool ok = true;
    if (BR == 2) {
      int gc = xt * 256 + chunk;
      int hh = gc / 240, r2 = gc - hh * 240, v5 = r2 / 48, wv = r2 - v5 * 48;
      base = (((long)(bat * 48 + hh) * 48 + wv) * 25 + yt * 5 + v5) * 192 + 64 + part * 8;
    } else {
      int r = chunk >> 2, g = chunk & 3;
      int gr = yt * 64 + r; ok = (gr < 240);
      int hh = gr / 5, u = gr - hh * 5;
      int r2 = xt * 4 + g, v5 = r2 / 48, wv = r2 - v5 * 48;
      base = (((long)(bat * 48 + hh) * 48 + wv) * 25 + u * 5 + v5) * 192 + 128 + part * 8;
    }
    if (ok) *(bf16x8*)&F[base] = v;
  }
}

// ---------------- weight prep ----------------
__global__ __launch_bounds__(256) void prep_w_k(const float* __restrict__ w1, const float* __restrict__ w2,
                                                short* __restrict__ w1t, short* __restrict__ w2t) {
  int idx = blockIdx.x * 256 + threadIdx.x;
  if (idx < 12288) {
    int i = idx / 64, j = idx - i * 64;
    w1t[j * 192 + i] = f2b(w1[idx]);
  } else if (idx < 16384) {
    int k = idx - 12288;
    int i = k / 64, j = k - i * 64;
    w2t[j * 64 + i] = f2b(w2[k]);
  }
}

// ---------------- fused (+x) LayerNorm + MFMA MLP + residual ----------------
// grid (25, 48, 4); F staged to LDS via coalesced bf16x8 loads; LN row-loop unrolled
__global__ __launch_bounds__(256) void ln_mlp_mfma_k(
    const short* __restrict__ F, const float* __restrict__ x,
    const float* __restrict__ gamma, const float* __restrict__ beta,
    const short* __restrict__ w1t, const short* __restrict__ w2t,
    float* __restrict__ out)
{
  int n = blockIdx.x, hh = blockIdx.y, b = blockIdx.z;
  __shared__ short A1[48 * 200];                 // 19200 B
  __shared__ float xs[64 * 49];                  // 12544 B
  __shared__ __align__(16) char pool[19584];     // Fs (18432) aliases Y1(6912)+Y2(12672)
  short* Fs = (short*)pool;
  short* Y1 = (short*)pool;
  float* Y2 = (float*)(pool + 6912);
  int tid = threadIdx.x, wave = tid >> 6, lane = tid & 63;
  int la = lane & 15, lb = lane >> 4;
  long Fb0 = ((long)(b * 48 + hh) * 1200 + n) * 192;
  long xb = (long)b * 3686400 + (long)n * 2304 + hh * 48;

  // stage F tile (48 x 192 bf16) coalesced: 1152 chunks of 16B
  #pragma unroll
  for (int it = 0; it < 5; ++it) {
    int ci = tid + 256 * it;
    if (ci < 1152) {
      int r = ci / 24, q = ci - r * 24;
      *(bf16x8*)&Fs[r * 192 + q * 8] = *(const bf16x8*)&F[Fb0 + (long)r * 4800 + q * 8];
    }
  }
  { // coalesced x tile: 64 ch x 48 w
    int ch = tid >> 2, qq = tid & 3;
    const float* xr = x + xb + (long)ch * 57600 + qq * 12;
    #pragma unroll
    for (int i = 0; i < 12; ++i) xs[ch * 49 + qq * 12 + i] = xr[i];
  }
  __syncthreads();

  float g0 = gamma[lane], g1 = gamma[lane + 64], g2 = gamma[lane + 128];
  float bt0 = beta[lane], bt1 = beta[lane + 64], bt2 = beta[lane + 128];
  #pragma unroll 4
  for (int rr = 0; rr < 12; ++rr) {
    int r = wave * 12 + rr;
    float xv = xs[lane * 49 + r];
    float v0 = b2f(Fs[r * 192 + lane]) + xv;
    float v1 = b2f(Fs[r * 192 + lane + 64]) + xv;
    float v2 = b2f(Fs[r * 192 + lane + 128]) + xv;
    float s = v0 + v1 + v2;
    #pragma unroll
    for (int o = 32; o >= 1; o >>= 1) s += __shfl_xor(s, o, 64);
    float mu = s * (1.f / 192.f);
    float d0 = v0 - mu, d1 = v1 - mu, d2 = v2 - mu;
    float q = d0 * d0 + d1 * d1 + d2 * d2;
    #pragma unroll
    for (int o = 32; o >= 1; o >>= 1) q += __shfl_xor(q, o, 64);
    float rs = rsqrtf(q * (1.f / 192.f) + 1e-5f);
    A1[r * 200 + lane]       = f2b(d0 * rs * g0 + bt0);
    A1[r * 200 + lane + 64]  = f2b(d1 * rs * g1 + bt1);
    A1[r * 200 + lane + 128] = f2b(d2 * rs * g2 + bt2);
  }
  __syncthreads();

  f32x4 acc1[3] = {};
  #pragma unroll
  for (int ks = 0; ks < 6; ++ks) {
    bf16x8 bv = *(const bf16x8*)&w1t[(wave * 16 + la) * 192 + ks * 32 + lb * 8];
    #pragma unroll
    for (int m = 0; m < 3; ++m) {
      bf16x8 av = *(const bf16x8*)&A1[(m * 16 + la) * 200 + ks * 32 + lb * 8];
      acc1[m] = __builtin_amdgcn_mfma_f32_16x16x32_bf16(av, bv, acc1[m], 0, 0, 0);
    }
  }
  #pragma unroll
  for (int m = 0; m < 3; ++m)
    #pragma unroll
    for (int j = 0; j < 4; ++j)
      Y1[(m * 16 + lb * 4 + j) * 72 + wave * 16 + la] = f2b(fmaxf(acc1[m][j], 0.f));
  __syncthreads();

  f32x4 acc2[3] = {};
  #pragma unroll
  for (int ks = 0; ks < 2; ++ks) {
    bf16x8 bv = *(const bf16x8*)&w2t[(wave * 16 + la) * 64 + ks * 32 + lb * 8];
    #pragma unroll
    for (int m = 0; m < 3; ++m) {
      bf16x8 av = *(const bf16x8*)&Y1[(m * 16 + la) * 72 + ks * 32 + lb * 8];
      acc2[m] = __builtin_amdgcn_mfma_f32_16x16x32_bf16(av, bv, acc2[m], 0, 0, 0);
    }
  }
  #pragma unroll
  for (int m = 0; m < 3; ++m)
    #pragma unroll
    for (int j = 0; j < 4; ++j)
      Y2[(m * 16 + lb * 4 + j) * 66 + wave * 16 + la] = acc2[m][j];
  __syncthreads();

  #pragma unroll
  for (int i = 0; i < 12; ++i) {
    int e = tid + 256 * i;
    int cc = e / 48, wv = e - cc * 48;
    out[xb + (long)cc * 57600 + wv] = Y2[wv * 66 + cc] + xs[cc * 49 + wv];
  }
}

// ---------------- host launcher ----------------
extern "C" void kernel_launch(void* const* d_in, const int* in_sizes, int n_in,
                              void* d_out, int out_size, void* d_ws, size_t ws_size,
                              hipStream_t stream) {
  (void)in_sizes; (void)n_in; (void)out_size;
  const float* x     = (const float*)d_in[0];
  const float* gamma = (const float*)d_in[1];
  const float* beta  = (const float*)d_in[2];
  const float* w1    = (const float*)d_in[3];
  const float* w2    = (const float*)d_in[4];
  float* out = (float*)d_out;

  const size_t NEED = 237191168UL;
  if (ws_size < NEED) return;
  char* ws = (char*)d_ws;
  short* F     = (short*)(ws);                           // 88,473,600
  short* att   = (short*)(ws + 88473600UL);              // 75,497,472
  short* Qbf   = (short*)(ws + 163971072UL);             // 35,389,440
  short* QbfT  = (short*)(ws + 199360512UL);             // 35,389,440
  float* Sf    = (float*)(ws + 234749952UL);             //  2,359,296 (sf: rowsum 49KB)
  float* invn  = (float*)(ws + 237109248UL);             //     49,152
  short* w1t   = (short*)(ws + 237158400UL);             //     24,576
  short* w2t   = (short*)(ws + 237182976UL);             //      8,192

  prep_w_k<<<64, 256, 0, stream>>>(w1, w2, w1t, w2t);

  // ================= SF: M=3072, K=1200 (Kp=1280) =================
  permute_sf_k<<<3072, 256, 0, stream>>>(x, Qbf);
  transpose_k<<<dim3(40, 96, 4), 256, 0, stream>>>(Qbf, QbfT, 3072, 1280);
  invnorm_k<<<dim3(3072, 4), 256, 0, stream>>>(Qbf, 3932160L, 1280, 3072, 3072, invn);
  hipMemsetAsync(Sf, 0, 49152, stream);                  // rowsum zero
  gemm1_tri_k<<<dim3(300, 1, 4), 256, 0, stream>>>(Qbf, invn, att, Sf);
  gemm2sf_k<<<dim3(960), 256, 0, stream>>>(att, QbfT, Sf, F);

  // ================= AF: M=320 (Mp=384), Kp=11520 =================
  permtr_k<1><<<dim3(360, 12, 4), 256, 0, stream>>>(x, Qbf, QbfT);
  invnorm_k<<<dim3(384, 4), 256, 0, stream>>>(Qbf, 4423680L, 11520, 320, 384, invn);
  hipMemsetAsync(Sf, 0, (size_t)4 * 384 * 384 * 4, stream);
  gemm_s_k<<<dim3(3, 3, 32), 256, 0, stream>>>(Qbf, 4423680L, 11520, 180, 23, 8, Sf, 147456L, 384);
  softmax_k<<<dim3(320, 4), 256, 0, stream>>>(Sf, 147456L, invn, 320, 384, att, 147456L);
  gemm2_k<2><<<dim3(900), 256, 0, stream>>>(att, QbfT, F);

  // ================= SA: M=240 (Mp=256), Kp=15360 =================
  permtr_k<2><<<dim3(480, 8, 4), 256, 0, stream>>>(x, Qbf, QbfT);
  invnorm_k<<<dim3(256, 4), 256, 0, stream>>>(Qbf, 3932160L, 15360, 240, 256, invn);
  hipMemsetAsync(Sf, 0, (size_t)4 * 256 * 256 * 4, stream);
  gemm_s_k<<<dim3(2, 2, 64), 256, 0, stream>>>(Qbf, 3932160L, 15360, 240, 15, 16, Sf, 65536L, 256);
  softmax_k<<<dim3(240, 4), 256, 0, stream>>>(Sf, 65536L, invn, 240, 256, att, 65536L);
  gemm2_k<3><<<dim3(960), 256, 0, stream>>>(att, QbfT, F);

  // ================= LN + MLP + residual =================
  ln_mlp_mfma_k<<<dim3(25, 48, 4), 256, 0, stream>>>(F, x, gamma, beta, w1t, w2t, out);
}